// Round 4
// baseline (432.689 us; speedup 1.0000x reference)
//
#include <hip/hip_runtime.h>

// HeteroGNN on MI355X. Inputs/weights/output fp32 (per reference); intermediates bf16.
// Round 12 = Round 11 resubmit (bench infra failed twice; source re-audited, no
// hang/fault hazard found). Prep-pipeline rebuild: non-k_mega time was stable ~205us
// across R8-R10 while k_host churned => cost is the bucket sort (kb2 9.6MB binE
// round-trip + kb3 at 1 block/CU). Replaced by direct CSR build:
//   k_pre  : weights->bf16 | x->bf16 | per-node degree via global atomics
//   k_scan1: block-local inclusive scan of deg -> off, block sums -> bsum
//   k_scan2: add block prefix (reduce bsum in-block), off final, cur = start
//   k_scat : csr[atomicAdd(&cur[dst],1)] = src  (one pass, 1.2M distributed atomics)
// k_mega = R9 exactly (R10's merged gather spilled: WRITE 25->102MB = scratch).
// k_host = R10's (625 blocks, 2-way neighbor split).
//   k_host : h=lrelu([mean(xfb nbrs)|xhb]@WT0_fh^T+b0); hT=h@WT1_l^T        (M=20000)
//   k_mega : h=lrelu([mean(xhb nbrs)|xfb]@WT0_hf^T+b0);
//            g=lrelu(h@WT1_r^T+mean(hT nbrs)+b1); out=g@WTo^T+bout          (M=200000)
// g_host dead in reference -> W1_fh_* unused.

#define N_HOST 20000
#define N_FLOW 200000
#define NEDGE  600000
#define D_IN   64
#define D_H    128
#define D_OUT  32
#define NSEG   (N_FLOW + N_HOST)
#define NEB    586                 // ceil(1200000/2048)
#define NB_SCAN 108                // ceil(220000/2048)

typedef unsigned short u16;
typedef unsigned int   u32;
typedef short bf16x8 __attribute__((ext_vector_type(8)));
typedef float f32x4  __attribute__((ext_vector_type(4)));
typedef float fx2    __attribute__((ext_vector_type(2)));

__device__ __forceinline__ float bfh(u16 h) { return __uint_as_float(((u32)h) << 16); }
__device__ __forceinline__ u16 fbh(float f) {
    u32 u = __float_as_uint(f);
    return (u16)((u + 0x7fffu + ((u >> 16) & 1u)) >> 16);   // RNE
}
__device__ __forceinline__ u32 packbf(float x, float y) {
    return (u32)fbh(x) | ((u32)fbh(y) << 16);
}
__device__ __forceinline__ void acc8(float* a, uint4 u) {
    a[0] += __uint_as_float(u.x << 16);
    a[1] += __uint_as_float(u.x & 0xffff0000u);
    a[2] += __uint_as_float(u.y << 16);
    a[3] += __uint_as_float(u.y & 0xffff0000u);
    a[4] += __uint_as_float(u.z << 16);
    a[5] += __uint_as_float(u.z & 0xffff0000u);
    a[6] += __uint_as_float(u.w << 16);
    a[7] += __uint_as_float(u.w & 0xffff0000u);
}
// packed accumulate (f32x2) for k_host split path
__device__ __forceinline__ void accp(fx2* a, uint4 u) {
    fx2 p;
    p.x = __uint_as_float(u.x << 16); p.y = __uint_as_float(u.x & 0xffff0000u); a[0] += p;
    p.x = __uint_as_float(u.y << 16); p.y = __uint_as_float(u.y & 0xffff0000u); a[1] += p;
    p.x = __uint_as_float(u.z << 16); p.y = __uint_as_float(u.z & 0xffff0000u); a[2] += p;
    p.x = __uint_as_float(u.w << 16); p.y = __uint_as_float(u.w & 0xffff0000u); a[3] += p;
}
__device__ __forceinline__ uint4 packp(const fx2* a, float inv) {
    uint4 o;
    o.x = packbf(a[0].x * inv, a[0].y * inv);
    o.y = packbf(a[1].x * inv, a[1].y * inv);
    o.z = packbf(a[2].x * inv, a[2].y * inv);
    o.w = packbf(a[3].x * inv, a[3].y * inv);
    return o;
}

// gather-mean of 16B chunks; neighbor indices from LDS window (fit) or global fallback.
template <int U>
__device__ __forceinline__ uint4 gmean(const u16* __restrict__ pool, int rs, int coff,
                                       const int* __restrict__ gcsr,
                                       const int* __restrict__ lcsr, int st0, bool fit,
                                       int st, int en) {
    float a[8] = {0.f, 0.f, 0.f, 0.f, 0.f, 0.f, 0.f, 0.f};
    for (int e = st; e < en; e += U) {
        int n[U];
#pragma unroll
        for (int j = 0; j < U; j++)
            n[j] = (e + j < en) ? (fit ? lcsr[e + j - st0] : gcsr[e + j]) : -1;
        uint4 u[U];
#pragma unroll
        for (int j = 0; j < U; j++)
            u[j] = (n[j] >= 0) ? *(const uint4*)(pool + n[j] * rs + coff)
                               : make_uint4(0u, 0u, 0u, 0u);
#pragma unroll
        for (int j = 0; j < U; j++) acc8(a, u[j]);
    }
    float inv = (en > st) ? 1.f / (float)(en - st) : 0.f;
    uint4 o;
    o.x = packbf(a[0] * inv, a[1] * inv);
    o.y = packbf(a[2] * inv, a[3] * inv);
    o.z = packbf(a[4] * inv, a[5] * inv);
    o.w = packbf(a[6] * inv, a[7] * inv);
    return o;
}

// ---------------- k_pre: weights transpose | x->bf16 | degree count ----------------
__global__ void k_pre(const float* __restrict__ W0_hf_l, const float* __restrict__ W0_hf_r,
                      const float* __restrict__ W0_fh_l, const float* __restrict__ W0_fh_r,
                      const float* __restrict__ W1_l, const float* __restrict__ W1_r,
                      const float* __restrict__ Wout,
                      u16* __restrict__ WT0_hf, u16* __restrict__ WT0_fh,
                      u16* __restrict__ WT1_l, u16* __restrict__ WT1_r,
                      u16* __restrict__ WTo,
                      const float* __restrict__ xf, const float* __restrict__ xh,
                      u16* __restrict__ xfb, u16* __restrict__ xhb,
                      const int* __restrict__ dst_hf, const int* __restrict__ dst_fh,
                      int* __restrict__ deg) {
    int b = blockIdx.x, t = threadIdx.x;
    if (b < 34) {
        u16 tmp[8];
        if (b < 32) {
            int e = (b & 7) * 2048 + t * 8;
            int n = e >> 7, k0 = e & 127;
            if (b < 8) {
#pragma unroll
                for (int j = 0; j < 8; j++) {
                    int k = k0 + j;
                    tmp[j] = fbh(k < 64 ? W0_hf_l[k * D_H + n] : W0_hf_r[(k - 64) * D_H + n]);
                }
                *(uint4*)(WT0_hf + n * 128 + k0) = *(uint4*)tmp;
            } else if (b < 16) {
#pragma unroll
                for (int j = 0; j < 8; j++) {
                    int k = k0 + j;
                    tmp[j] = fbh(k < 64 ? W0_fh_l[k * D_H + n] : W0_fh_r[(k - 64) * D_H + n]);
                }
                *(uint4*)(WT0_fh + n * 128 + k0) = *(uint4*)tmp;
            } else if (b < 24) {
#pragma unroll
                for (int j = 0; j < 8; j++) tmp[j] = fbh(W1_l[(k0 + j) * D_H + n]);
                *(uint4*)(WT1_l + n * 128 + k0) = *(uint4*)tmp;
            } else {
#pragma unroll
                for (int j = 0; j < 8; j++) tmp[j] = fbh(W1_r[(k0 + j) * D_H + n]);
                *(uint4*)(WT1_r + n * 128 + k0) = *(uint4*)tmp;
            }
        } else {
            int e = (b - 32) * 2048 + t * 8;
            int n = e >> 7, k0 = e & 127;
#pragma unroll
            for (int j = 0; j < 8; j++) tmp[j] = fbh(Wout[(k0 + j) * D_OUT + n]);
            *(uint4*)(WTo + n * 128 + k0) = *(uint4*)tmp;
        }
    } else if (b < 34 + 6875) {
        int q = (b - 34) * 256 + t;       // 8 floats per thread
        const int TF = (N_FLOW * D_IN) / 8;
        const int TT = TF + (N_HOST * D_IN) / 8;
        if (q >= TT) return;
        const float* src; u16* dst; int base;
        if (q < TF) { src = xf; dst = xfb; base = q * 8; }
        else        { src = xh; dst = xhb; base = (q - TF) * 8; }
        float4 f0 = *(const float4*)(src + base);
        float4 f1 = *(const float4*)(src + base + 4);
        uint4 o;
        o.x = packbf(f0.x, f0.y); o.y = packbf(f0.z, f0.w);
        o.z = packbf(f1.x, f1.y); o.w = packbf(f1.z, f1.w);
        *(uint4*)(dst + base) = o;
    } else {
        int base = (b - 34 - 6875) * 2048;
#pragma unroll
        for (int i = 0; i < 8; i++) {
            int e = base + t + i * 256;
            if (e < 2 * NEDGE) {
                int node = (e < NEDGE) ? dst_hf[e] : (N_FLOW + dst_fh[e - NEDGE]);
                atomicAdd(&deg[node], 1);
            }
        }
    }
}

// ------------- k_scan1: block-local inclusive scan of deg -> off, sums -> bsum -------------
__global__ __launch_bounds__(512) void k_scan1(const int* __restrict__ deg,
                                               int* __restrict__ off,
                                               int* __restrict__ bsum) {
    __shared__ int ts[512];
    int b = blockIdx.x, t = threadIdx.x;
    int base = b * 2048 + t * 4;
    int4 d = make_int4(0, 0, 0, 0);
    if (base + 3 < NSEG) d = *(const int4*)(deg + base);
    else if (base < NSEG) {
        d.x = deg[base];
        if (base + 1 < NSEG) d.y = deg[base + 1];
        if (base + 2 < NSEG) d.z = deg[base + 2];
    }
    int l1 = d.x + d.y, l2 = l1 + d.z, l3 = l2 + d.w;
    ts[t] = l3;
    __syncthreads();
    for (int s = 1; s < 512; s <<= 1) {
        int v = (t >= s) ? ts[t - s] : 0;
        __syncthreads();
        ts[t] += v;
        __syncthreads();
    }
    int add = ts[t] - l3;   // exclusive prefix of this thread within block
    if (base + 3 < NSEG) {
        *(int4*)(off + base) = make_int4(add + d.x, add + l1, add + l2, add + l3);
    } else if (base < NSEG) {
        off[base] = add + d.x;
        if (base + 1 < NSEG) off[base + 1] = add + l1;
        if (base + 2 < NSEG) off[base + 2] = add + l2;
    }
    if (t == 511) bsum[b] = ts[511];
}

// ------- k_scan2: add block prefix (in-block reduce of bsum), write final off + cur -------
__global__ __launch_bounds__(512) void k_scan2(const int* __restrict__ deg,
                                               int* __restrict__ off,
                                               const int* __restrict__ bsum,
                                               int* __restrict__ cur) {
    __shared__ int red[512];
    int b = blockIdx.x, t = threadIdx.x;
    red[t] = (t < b) ? bsum[t] : 0;    // b <= 107 < 512
    __syncthreads();
    for (int s = 256; s > 0; s >>= 1) {
        if (t < s) red[t] += red[t + s];
        __syncthreads();
    }
    int add = red[0];
    int base = b * 2048 + t * 4;
    if (base >= NSEG) return;
    if (base + 3 < NSEG) {
        int4 o = *(const int4*)(off + base);
        int4 d = *(const int4*)(deg + base);
        o.x += add; o.y += add; o.z += add; o.w += add;
        *(int4*)(off + base) = o;
        *(int4*)(cur + base) = make_int4(o.x - d.x, o.y - d.y, o.z - d.z, o.w - d.w);
    } else {
#pragma unroll
        for (int j = 0; j < 4; j++) {
            if (base + j < NSEG) {
                int o = off[base + j] + add;
                off[base + j] = o;
                cur[base + j] = o - deg[base + j];
            }
        }
    }
}

// ---------------- k_scat: one-pass CSR scatter ----------------
__global__ __launch_bounds__(512) void k_scat(const int* __restrict__ src_hf,
                                              const int* __restrict__ dst_hf,
                                              const int* __restrict__ src_fh,
                                              const int* __restrict__ dst_fh,
                                              int* __restrict__ cur,
                                              int* __restrict__ csr) {
    int e = blockIdx.x * 2048 + threadIdx.x * 4;
    if (e >= 2 * NEDGE) return;
    // NEDGE % 4 == 0 and e % 4 == 0 -> a thread's 4 slots never straddle the boundary
    int4 s4, d4; int nb;
    if (e < NEDGE) {
        s4 = *(const int4*)(src_hf + e);
        d4 = *(const int4*)(dst_hf + e);
        nb = 0;
    } else {
        s4 = *(const int4*)(src_fh + e - NEDGE);
        d4 = *(const int4*)(dst_fh + e - NEDGE);
        nb = N_FLOW;
    }
    int p0 = atomicAdd(&cur[d4.x + nb], 1);
    int p1 = atomicAdd(&cur[d4.y + nb], 1);
    int p2 = atomicAdd(&cur[d4.z + nb], 1);
    int p3 = atomicAdd(&cur[d4.w + nb], 1);
    csr[p0] = s4.x; csr[p1] = s4.y; csr[p2] = s4.z; csr[p3] = s4.w;
}

// ------- k_host: G2+G3 fused, 32-row tiles, 2-way neighbor split (M=20000=625*32) -------
__global__ __launch_bounds__(512, 4) void k_host(
    const u16* __restrict__ xfb, const u16* __restrict__ xhb,
    const int* __restrict__ off, const int* __restrict__ csr,
    const u16* __restrict__ WT0, const float* __restrict__ b0,
    const u16* __restrict__ WT1l, u16* __restrict__ hT) {
    __shared__ __align__(16) u16 sA[32 * 136];
    __shared__ __align__(16) float sP[256 * 8];
    __shared__ int sOff[40];
    __shared__ int sCsr[2048];
    const int t = threadIdx.x;
    const int m0 = blockIdx.x * 32;
    if (t < 33) sOff[t] = off[N_FLOW + m0 - 1 + t];
    // direct half: xhb row, k in [64,128) — 256 chunks
    if (t < 256) {
        int r = t >> 3, c = t & 7;
        uint4 v = *(const uint4*)(xhb + (m0 + r) * 64 + c * 8);
        *(uint4*)(&sA[r * 136 + 64 + c * 8]) = v;
    }
    __syncthreads();
    int st0 = sOff[0];
    int win = sOff[32] - st0;
    bool fit = (win <= 2048);
    if (fit) for (int e = t; e < win; e += 512) sCsr[e] = csr[st0 + e];
    __syncthreads();
    // gather half: mean(xfb nbrs), k in [0,64) — 32r x 8c x 2 splits, U=8 per split
    const int r = t >> 4, s8 = (t >> 3) & 1, c = t & 7;
    const int st = sOff[r], en = sOff[r + 1];
    fx2 a[4] = {};
    for (int e = st + s8; e < en; e += 16) {
        int n[8];
#pragma unroll
        for (int j = 0; j < 8; j++) {
            int ee = e + 2 * j;
            n[j] = (ee < en) ? (fit ? sCsr[ee - st0] : csr[ee]) : -1;
        }
        uint4 u[8];
#pragma unroll
        for (int j = 0; j < 8; j++)
            u[j] = (n[j] >= 0) ? *(const uint4*)(xfb + n[j] * 64 + c * 8)
                               : make_uint4(0u, 0u, 0u, 0u);
#pragma unroll
        for (int j = 0; j < 8; j++) accp(a, u[j]);
    }
    if (s8) {
        float4* p = (float4*)(&sP[(r * 8 + c) * 8]);
        p[0] = make_float4(a[0].x, a[0].y, a[1].x, a[1].y);
        p[1] = make_float4(a[2].x, a[2].y, a[3].x, a[3].y);
    }
    __syncthreads();
    if (!s8) {
        const float4* p = (const float4*)(&sP[(r * 8 + c) * 8]);
        float4 v0 = p[0], v1 = p[1];
        a[0].x += v0.x; a[0].y += v0.y; a[1].x += v0.z; a[1].y += v0.w;
        a[2].x += v1.x; a[2].y += v1.y; a[3].x += v1.z; a[3].y += v1.w;
        float inv = (en > st) ? 1.f / (float)(en - st) : 0.f;
        *(uint4*)(&sA[r * 136 + c * 8]) = packp(a, inv);
    }
    __syncthreads();
    // MFMA: 8 waves = (wr in {0,1}) x (wc in 0..3, 32 cols each)
    const int w = t >> 6, wr = w >> 2, wc = w & 3;
    const int ln = t & 63, l15 = ln & 15, quad = ln >> 4;
    const u16* pA = sA + (wr * 16 + l15) * 136 + quad * 8;
    const u16* pB0 = WT0 + wc * 4096 + l15 * 128 + quad * 8;
    f32x4 acc[2];
    acc[0] = (f32x4){0.f, 0.f, 0.f, 0.f};
    acc[1] = (f32x4){0.f, 0.f, 0.f, 0.f};
#pragma unroll
    for (int s = 0; s < 4; s++) {
        bf16x8 av = *(const bf16x8*)(pA + s * 32);
#pragma unroll
        for (int tt = 0; tt < 2; tt++) {
            bf16x8 b = *(const bf16x8*)(pB0 + tt * 2048 + s * 32);
            acc[tt] = __builtin_amdgcn_mfma_f32_16x16x32_bf16(av, b, acc[tt], 0, 0, 0);
        }
    }
    __syncthreads();   // all phase-A reads done before h overwrites sA
#pragma unroll
    for (int tt = 0; tt < 2; tt++) {
        int col = wc * 32 + tt * 16 + l15;
        float bv = b0[col];
#pragma unroll
        for (int i = 0; i < 4; i++) {
            int rl = wr * 16 + quad * 4 + i;
            float v = acc[tt][i] + bv;
            v = v > 0.f ? v : 0.01f * v;
            sA[rl * 136 + col] = fbh(v);
        }
    }
    __syncthreads();   // h complete before phase B reads
    const u16* pB1 = WT1l + wc * 4096 + l15 * 128 + quad * 8;
    f32x4 accB[2];
    accB[0] = (f32x4){0.f, 0.f, 0.f, 0.f};
    accB[1] = (f32x4){0.f, 0.f, 0.f, 0.f};
#pragma unroll
    for (int s = 0; s < 4; s++) {
        bf16x8 av = *(const bf16x8*)(pA + s * 32);
#pragma unroll
        for (int tt = 0; tt < 2; tt++) {
            bf16x8 b = *(const bf16x8*)(pB1 + tt * 2048 + s * 32);
            accB[tt] = __builtin_amdgcn_mfma_f32_16x16x32_bf16(av, b, accB[tt], 0, 0, 0);
        }
    }
#pragma unroll
    for (int tt = 0; tt < 2; tt++) {
        int col = wc * 32 + tt * 16 + l15;
#pragma unroll
        for (int i = 0; i < 4; i++) {
            int row = m0 + wr * 16 + quad * 4 + i;
            hT[row * D_H + col] = fbh(accB[tt][i]);
        }
    }
}

// ---------------- k_mega: G1+G4 fused (M=200000, no tail) — R9 version ----------------
__global__ __launch_bounds__(512, 8) void k_mega(
    const u16* __restrict__ xfb, const u16* __restrict__ xhb,
    const int* __restrict__ off, const int* __restrict__ csr,
    const u16* __restrict__ hT,
    const u16* __restrict__ WT0, const float* __restrict__ b0,
    const u16* __restrict__ WT1r, const float* __restrict__ b1,
    const u16* __restrict__ WTo, const float* __restrict__ bout,
    float* __restrict__ OUT) {
    __shared__ __align__(16) u16 sA[64 * 136];    // A0 tile -> h band
    __shared__ __align__(16) u16 sAg[64 * 136];   // gathered mean(hT) tile -> g band
    __shared__ int sOff[72];
    __shared__ int sCsr[1024];
    const int t = threadIdx.x;
    const int m0 = blockIdx.x * 64;
    if (t < 65) {
        int idx = m0 - 1 + t;
        sOff[t] = (idx < 0) ? 0 : off[idx];
    }
    // direct half: xfb row, k in [64,128)
    {
        int r = t >> 3, c = t & 7;
        uint4 v = *(const uint4*)(xfb + (m0 + r) * 64 + c * 8);
        *(uint4*)(&sA[r * 136 + 64 + c * 8]) = v;
    }
    __syncthreads();
    int st0 = sOff[0];
    int win = sOff[64] - st0;
    bool fit = (win <= 1024);
    if (fit) for (int e = t; e < win; e += 512) sCsr[e] = csr[st0 + e];
    __syncthreads();
    // A0 gather half: mean(xhb nbrs), k in [0,64) — 512 tasks
    {
        int r = t >> 3, c = t & 7;
        uint4 o = gmean<4>(xhb, 64, c * 8, csr, sCsr, st0, fit, sOff[r], sOff[r + 1]);
        *(uint4*)(&sA[r * 136 + c * 8]) = o;
    }
    // agg tile: mean(hT nbrs), 128d — 1024 tasks, 2/thread
#pragma unroll
    for (int i = 0; i < 2; i++) {
        int q = t + i * 512;
        int r = q >> 4, c = q & 15;
        uint4 o = gmean<4>(hT, 128, c * 8, csr, sCsr, st0, fit, sOff[r], sOff[r + 1]);
        *(uint4*)(&sAg[r * 136 + c * 8]) = o;
    }
    __syncthreads();
    const int w = t >> 6, wr = w >> 1, wc = w & 1;   // wave = (row-band, col-half)
    const int ln = t & 63, l15 = ln & 15, quad = ln >> 4;
    const u16* pA = sA + (wr * 16 + l15) * 136 + quad * 8;
    const u16* pB0 = WT0 + wc * 8192 + l15 * 128 + quad * 8;
    f32x4 acc[4];
#pragma unroll
    for (int tt = 0; tt < 4; tt++) acc[tt] = (f32x4){0.f, 0.f, 0.f, 0.f};
#pragma unroll
    for (int s = 0; s < 4; s++) {
        bf16x8 av = *(const bf16x8*)(pA + s * 32);
#pragma unroll
        for (int tt = 0; tt < 4; tt++) {
            bf16x8 b = *(const bf16x8*)(pB0 + tt * 2048 + s * 32);
            acc[tt] = __builtin_amdgcn_mfma_f32_16x16x32_bf16(av, b, acc[tt], 0, 0, 0);
        }
    }
    __syncthreads();   // all phase-A reads of sA done before h overwrites it
    // epilogue1: h = lrelu(acc + b0) -> sA band (cols wc*64 ..)
#pragma unroll
    for (int tt = 0; tt < 4; tt++) {
        int col = wc * 64 + tt * 16 + l15;
        float bv = b0[col];
#pragma unroll
        for (int i = 0; i < 4; i++) {
            int rl = wr * 16 + quad * 4 + i;
            float v = acc[tt][i] + bv;
            v = v > 0.f ? v : 0.01f * v;
            sA[rl * 136 + col] = fbh(v);
        }
    }
    __syncthreads();   // h complete before phase B reads full rows
    // phase B: h @ WT1r^T
    const u16* pB1 = WT1r + wc * 8192 + l15 * 128 + quad * 8;
    f32x4 accB[4];
#pragma unroll
    for (int tt = 0; tt < 4; tt++) accB[tt] = (f32x4){0.f, 0.f, 0.f, 0.f};
#pragma unroll
    for (int s = 0; s < 4; s++) {
        bf16x8 av = *(const bf16x8*)(pA + s * 32);
#pragma unroll
        for (int tt = 0; tt < 4; tt++) {
            bf16x8 b = *(const bf16x8*)(pB1 + tt * 2048 + s * 32);
            accB[tt] = __builtin_amdgcn_mfma_f32_16x16x32_bf16(av, b, accB[tt], 0, 0, 0);
        }
    }
    // epilogue2: g = lrelu(accB + agg + b1) -> in-place over sAg
#pragma unroll
    for (int tt = 0; tt < 4; tt++) {
        int col = wc * 64 + tt * 16 + l15;
        float bv = b1[col];
#pragma unroll
        for (int i = 0; i < 4; i++) {
            int rl = wr * 16 + quad * 4 + i;
            float v = accB[tt][i] + bfh(sAg[rl * 136 + col]) + bv;
            v = v > 0.f ? v : 0.01f * v;
            sAg[rl * 136 + col] = fbh(v);
        }
    }
    __syncthreads();   // g complete before phase C reads full rows
    // phase C: out = g @ WTo^T + bout  (each wave: 16-row band x 16-col tile wc)
    const u16* pG = sAg + (wr * 16 + l15) * 136 + quad * 8;
    const u16* pBo = WTo + wc * 2048 + l15 * 128 + quad * 8;
    f32x4 acc2 = (f32x4){0.f, 0.f, 0.f, 0.f};
#pragma unroll
    for (int s = 0; s < 4; s++) {
        bf16x8 g = *(const bf16x8*)(pG + s * 32);
        bf16x8 b = *(const bf16x8*)(pBo + s * 32);
        acc2 = __builtin_amdgcn_mfma_f32_16x16x32_bf16(g, b, acc2, 0, 0, 0);
    }
    {
        int col = wc * 16 + l15;
        float bv = bout[col];
#pragma unroll
        for (int i = 0; i < 4; i++) {
            int row = m0 + wr * 16 + quad * 4 + i;
            OUT[row * D_OUT + col] = acc2[i] + bv;
        }
    }
}

extern "C" void kernel_launch(void* const* d_in, const int* in_sizes, int n_in,
                              void* d_out, int out_size, void* d_ws, size_t ws_size,
                              hipStream_t stream) {
    const float* x_host  = (const float*)d_in[0];
    const float* x_flow  = (const float*)d_in[1];
    const int* src_hf  = (const int*)d_in[2];
    const int* dst_hf  = (const int*)d_in[3];
    const int* src_fh  = (const int*)d_in[4];
    const int* dst_fh  = (const int*)d_in[5];
    const float* W0_hf_l = (const float*)d_in[6];
    const float* W0_hf_r = (const float*)d_in[7];
    const float* b0_hf   = (const float*)d_in[8];
    const float* W0_fh_l = (const float*)d_in[9];
    const float* W0_fh_r = (const float*)d_in[10];
    const float* b0_fh   = (const float*)d_in[11];
    const float* W1_hf_l = (const float*)d_in[12];
    const float* W1_hf_r = (const float*)d_in[13];
    const float* b1_hf   = (const float*)d_in[14];
    const float* W_out   = (const float*)d_in[18];
    const float* b_out   = (const float*)d_in[19];
    float* out = (float*)d_out;

    // workspace layout (bytes), all disjoint, total ~48.7 MB
    char* ws = (char*)d_ws;
    int*  off    = (int*)(ws + 0);             //   880,000
    int*  csr    = (int*)(ws + 880000);        // 4,800,000
    u16*  hT     = (u16*)(ws + 5680000);       //  5,120,000
    u16*  xfb    = (u16*)(ws + 10800000);      // 25,600,000
    u16*  xhb    = (u16*)(ws + 36400000);      //  2,560,000
    int*  deg    = (int*)(ws + 38960000);      //    880,000
    int*  cur    = (int*)(ws + 39840000);      //    880,000
    int*  bsum   = (int*)(ws + 40720000);      //        512
    u16*  WT0_hf = (u16*)(ws + 48562560);      //  32,768
    u16*  WT0_fh = (u16*)(ws + 48595328);      //  32,768
    u16*  WT1_l  = (u16*)(ws + 48628096);      //  32,768
    u16*  WT1_r  = (u16*)(ws + 48660864);      //  32,768
    u16*  WTo    = (u16*)(ws + 48693632);      //   8,192

    hipMemsetAsync(deg, 0, 880000, stream);
    k_pre<<<34 + 6875 + NEB, 256, 0, stream>>>(
        W0_hf_l, W0_hf_r, W0_fh_l, W0_fh_r, W1_hf_l, W1_hf_r, W_out,
        WT0_hf, WT0_fh, WT1_l, WT1_r, WTo,
        x_flow, x_host, xfb, xhb, dst_hf, dst_fh, deg);
    k_scan1<<<NB_SCAN, 512, 0, stream>>>(deg, off, bsum);
    k_scan2<<<NB_SCAN, 512, 0, stream>>>(deg, off, bsum, cur);
    k_scat<<<NEB, 512, 0, stream>>>(src_hf, dst_hf, src_fh, dst_fh, cur, csr);
    k_host<<<625, 512, 0, stream>>>(xfb, xhb, off, csr, WT0_fh, b0_fh, WT1_l, hT);
    k_mega<<<3125, 512, 0, stream>>>(xfb, xhb, off, csr, hT, WT0_hf, b0_hf,
                                     WT1_r, b1_hf, WTo, b_out, out);
}

// Round 5
// 414.448 us; speedup vs baseline: 1.0440x; 1.0440x over previous
//
#include <hip/hip_runtime.h>

// HeteroGNN on MI355X. Inputs/weights/output fp32 (per reference); intermediates bf16.
// Round 13: hybrid prep + k_mega VALU cut.
//  - R12 post-mortem: scan-prep was ~93us SLOWER than bucket prep; culprit = k_scat's
//    1.2M random 4B csr writes (64B-line RMW amplification across 8 XCD L2s). kb2's
//    bucketed binE earns write locality. KEEP kb2; replace only kb3 (275 blocks =
//    1.07/CU) with scan1/scan2 (parallel, from R12) + streaming binE->csr scatter
//    whose writes land inside each bucket's ~12-30KB csr region.
//  - k_mega: R12 counters showed VALUBusy*dur == hand-counted unpack VALU (~40us
//    floor). acc8 (16 VALU/chunk) -> accp (12 VALU/chunk, v_pk_add_f32, same math).
//  - deg/cur/bsum alias the hT region (dead until k_host runs). ws <= 48.7MB.
//   k_pre  : weights->bf16 | x->bf16 | bucket histogram + per-node degree
//   kb2    : bin scatter (in-block 275-prefix)
//   k_scan1/k_scan2: hierarchical scan of deg -> off (segment ENDs), cur = starts
//   k_scatE: csr[atomicAdd(&cur[dst],1)] = src, streaming binE (bucket-local writes)
//   k_host : h=lrelu([mean(xfb nbrs)|xhb]@WT0_fh^T+b0); hT=h@WT1_l^T        (M=20000)
//   k_mega : h=lrelu([mean(xhb nbrs)|xfb]@WT0_hf^T+b0);
//            g=lrelu(h@WT1_r^T+mean(hT nbrs)+b1); out=g@WTo^T+bout          (M=200000)
// g_host dead in reference -> W1_fh_* unused.

#define N_HOST 20000
#define N_FLOW 200000
#define NEDGE  600000
#define D_IN   64
#define D_H    128
#define D_OUT  32
#define NSEG   (N_FLOW + N_HOST)
#define NBKT_F 196
#define NBKT_H 79
#define NBKT   (NBKT_F + NBKT_H)   // 275
#define NEB    586                 // ceil(1200000/2048)
#define NB_SCAN 108                // ceil(220000/2048)

typedef unsigned short u16;
typedef unsigned int   u32;
typedef short bf16x8 __attribute__((ext_vector_type(8)));
typedef float f32x4  __attribute__((ext_vector_type(4)));
typedef float fx2    __attribute__((ext_vector_type(2)));

__device__ __forceinline__ float bfh(u16 h) { return __uint_as_float(((u32)h) << 16); }
__device__ __forceinline__ u16 fbh(float f) {
    u32 u = __float_as_uint(f);
    return (u16)((u + 0x7fffu + ((u >> 16) & 1u)) >> 16);   // RNE
}
__device__ __forceinline__ u32 packbf(float x, float y) {
    return (u32)fbh(x) | ((u32)fbh(y) << 16);
}
// packed bf16 unpack+accumulate: 8 unpacks + 4 v_pk_add_f32 (vs 16 VALU for scalar)
__device__ __forceinline__ void accp(fx2* a, uint4 u) {
    fx2 p;
    p.x = __uint_as_float(u.x << 16); p.y = __uint_as_float(u.x & 0xffff0000u); a[0] += p;
    p.x = __uint_as_float(u.y << 16); p.y = __uint_as_float(u.y & 0xffff0000u); a[1] += p;
    p.x = __uint_as_float(u.z << 16); p.y = __uint_as_float(u.z & 0xffff0000u); a[2] += p;
    p.x = __uint_as_float(u.w << 16); p.y = __uint_as_float(u.w & 0xffff0000u); a[3] += p;
}
__device__ __forceinline__ uint4 packp(const fx2* a, float inv) {
    uint4 o;
    o.x = packbf(a[0].x * inv, a[0].y * inv);
    o.y = packbf(a[1].x * inv, a[1].y * inv);
    o.z = packbf(a[2].x * inv, a[2].y * inv);
    o.w = packbf(a[3].x * inv, a[3].y * inv);
    return o;
}

// gather-mean of 16B chunks; neighbor indices from LDS window (fit) or global fallback.
template <int U>
__device__ __forceinline__ uint4 gmean(const u16* __restrict__ pool, int rs, int coff,
                                       const int* __restrict__ gcsr,
                                       const int* __restrict__ lcsr, int st0, bool fit,
                                       int st, int en) {
    fx2 a[4] = {};
    for (int e = st; e < en; e += U) {
        int n[U];
#pragma unroll
        for (int j = 0; j < U; j++)
            n[j] = (e + j < en) ? (fit ? lcsr[e + j - st0] : gcsr[e + j]) : -1;
        uint4 u[U];
#pragma unroll
        for (int j = 0; j < U; j++)
            u[j] = (n[j] >= 0) ? *(const uint4*)(pool + n[j] * rs + coff)
                               : make_uint4(0u, 0u, 0u, 0u);
#pragma unroll
        for (int j = 0; j < U; j++) accp(a, u[j]);
    }
    float inv = (en > st) ? 1.f / (float)(en - st) : 0.f;
    return packp(a, inv);
}

// ------- k_pre: weights transpose | x->bf16 | bucket histogram + degree count -------
__global__ void k_pre(const float* __restrict__ W0_hf_l, const float* __restrict__ W0_hf_r,
                      const float* __restrict__ W0_fh_l, const float* __restrict__ W0_fh_r,
                      const float* __restrict__ W1_l, const float* __restrict__ W1_r,
                      const float* __restrict__ Wout,
                      u16* __restrict__ WT0_hf, u16* __restrict__ WT0_fh,
                      u16* __restrict__ WT1_l, u16* __restrict__ WT1_r,
                      u16* __restrict__ WTo,
                      const float* __restrict__ xf, const float* __restrict__ xh,
                      u16* __restrict__ xfb, u16* __restrict__ xhb,
                      const int* __restrict__ dst_hf, const int* __restrict__ dst_fh,
                      int* __restrict__ bcnt, int* __restrict__ deg) {
    int b = blockIdx.x, t = threadIdx.x;
    if (b < 34) {
        u16 tmp[8];
        if (b < 32) {
            int e = (b & 7) * 2048 + t * 8;
            int n = e >> 7, k0 = e & 127;
            if (b < 8) {
#pragma unroll
                for (int j = 0; j < 8; j++) {
                    int k = k0 + j;
                    tmp[j] = fbh(k < 64 ? W0_hf_l[k * D_H + n] : W0_hf_r[(k - 64) * D_H + n]);
                }
                *(uint4*)(WT0_hf + n * 128 + k0) = *(uint4*)tmp;
            } else if (b < 16) {
#pragma unroll
                for (int j = 0; j < 8; j++) {
                    int k = k0 + j;
                    tmp[j] = fbh(k < 64 ? W0_fh_l[k * D_H + n] : W0_fh_r[(k - 64) * D_H + n]);
                }
                *(uint4*)(WT0_fh + n * 128 + k0) = *(uint4*)tmp;
            } else if (b < 24) {
#pragma unroll
                for (int j = 0; j < 8; j++) tmp[j] = fbh(W1_l[(k0 + j) * D_H + n]);
                *(uint4*)(WT1_l + n * 128 + k0) = *(uint4*)tmp;
            } else {
#pragma unroll
                for (int j = 0; j < 8; j++) tmp[j] = fbh(W1_r[(k0 + j) * D_H + n]);
                *(uint4*)(WT1_r + n * 128 + k0) = *(uint4*)tmp;
            }
        } else {
            int e = (b - 32) * 2048 + t * 8;
            int n = e >> 7, k0 = e & 127;
#pragma unroll
            for (int j = 0; j < 8; j++) tmp[j] = fbh(Wout[(k0 + j) * D_OUT + n]);
            *(uint4*)(WTo + n * 128 + k0) = *(uint4*)tmp;
        }
    } else if (b < 34 + 6875) {
        int q = (b - 34) * 256 + t;       // 8 floats per thread
        const int TF = (N_FLOW * D_IN) / 8;
        const int TT = TF + (N_HOST * D_IN) / 8;
        if (q >= TT) return;
        const float* src; u16* dst; int base;
        if (q < TF) { src = xf; dst = xfb; base = q * 8; }
        else        { src = xh; dst = xhb; base = (q - TF) * 8; }
        float4 f0 = *(const float4*)(src + base);
        float4 f1 = *(const float4*)(src + base + 4);
        uint4 o;
        o.x = packbf(f0.x, f0.y); o.y = packbf(f0.z, f0.w);
        o.z = packbf(f1.x, f1.y); o.w = packbf(f1.z, f1.w);
        *(uint4*)(dst + base) = o;
    } else {
        __shared__ int h[NBKT];
        for (int j = t; j < NBKT; j += 256) h[j] = 0;
        __syncthreads();
        int base = (b - 34 - 6875) * 2048;
#pragma unroll
        for (int i = 0; i < 8; i++) {
            int e = base + t + i * 256;
            if (e < 2 * NEDGE) {
                int node, bkt;
                if (e < NEDGE) { node = dst_hf[e]; bkt = node >> 10; }
                else { node = N_FLOW + dst_fh[e - NEDGE]; bkt = NBKT_F + ((node - N_FLOW) >> 8); }
                atomicAdd(&h[bkt], 1);
                atomicAdd(&deg[node], 1);
            }
        }
        __syncthreads();
        for (int j = t; j < NBKT; j += 256)
            if (h[j]) atomicAdd(&bcnt[j], h[j]);
    }
}

// ---------------- kb2: bin scatter (in-block prefix of bcnt) ----------------
__global__ void kb2(const int* __restrict__ src_hf, const int* __restrict__ dst_hf,
                    const int* __restrict__ src_fh, const int* __restrict__ dst_fh,
                    const int* __restrict__ bcnt, int* __restrict__ bcur,
                    int2* __restrict__ binE) {
    __shared__ int sp[512];    // becomes exclusive bucket base
    __shared__ int lh[NBKT];
    __shared__ int lb[NBKT];
    int t = threadIdx.x;
    int o1 = (t < NBKT) ? bcnt[t] : 0;
    int o2 = (t + 256 < NBKT) ? bcnt[t + 256] : 0;
    sp[t] = o1; sp[t + 256] = o2;
    for (int j = t; j < NBKT; j += 256) lh[j] = 0;
    __syncthreads();
    for (int d = 1; d < 512; d <<= 1) {
        int a0 = (t >= d) ? sp[t - d] : 0;
        int a1 = sp[t + 256 - d];
        __syncthreads();
        sp[t] += a0; sp[t + 256] += a1;
        __syncthreads();
    }
    sp[t] -= o1; sp[t + 256] -= o2;   // exclusive
    __syncthreads();
    int base = blockIdx.x * 2048;
    int mybkt[8], myrank[8], mysrc[8], mydst[8];
#pragma unroll
    for (int i = 0; i < 8; i++) {
        int e = base + t + i * 256;
        mybkt[i] = -1;
        if (e < 2 * NEDGE) {
            int s, d;
            if (e < NEDGE) { s = src_hf[e]; d = dst_hf[e]; }
            else           { s = src_fh[e - NEDGE]; d = dst_fh[e - NEDGE] + N_FLOW; }
            int bkt = (d < N_FLOW) ? (d >> 10) : (NBKT_F + ((d - N_FLOW) >> 8));
            mybkt[i] = bkt; mysrc[i] = s; mydst[i] = d;
            myrank[i] = atomicAdd(&lh[bkt], 1);
        }
    }
    __syncthreads();
    for (int j = t; j < NBKT; j += 256)
        lb[j] = lh[j] ? atomicAdd(&bcur[j], lh[j]) : 0;
    __syncthreads();
#pragma unroll
    for (int i = 0; i < 8; i++) {
        if (mybkt[i] >= 0) {
            int pos = sp[mybkt[i]] + lb[mybkt[i]] + myrank[i];
            binE[pos] = make_int2(mysrc[i], mydst[i]);
        }
    }
}

// ------------- k_scan1: block-local inclusive scan of deg -> off, sums -> bsum -------------
__global__ __launch_bounds__(512) void k_scan1(const int* __restrict__ deg,
                                               int* __restrict__ off,
                                               int* __restrict__ bsum) {
    __shared__ int ts[512];
    int b = blockIdx.x, t = threadIdx.x;
    int base = b * 2048 + t * 4;
    int4 d = make_int4(0, 0, 0, 0);
    if (base + 3 < NSEG) d = *(const int4*)(deg + base);
    else if (base < NSEG) {
        d.x = deg[base];
        if (base + 1 < NSEG) d.y = deg[base + 1];
        if (base + 2 < NSEG) d.z = deg[base + 2];
    }
    int l1 = d.x + d.y, l2 = l1 + d.z, l3 = l2 + d.w;
    ts[t] = l3;
    __syncthreads();
    for (int s = 1; s < 512; s <<= 1) {
        int v = (t >= s) ? ts[t - s] : 0;
        __syncthreads();
        ts[t] += v;
        __syncthreads();
    }
    int add = ts[t] - l3;   // exclusive prefix of this thread within block
    if (base + 3 < NSEG) {
        *(int4*)(off + base) = make_int4(add + d.x, add + l1, add + l2, add + l3);
    } else if (base < NSEG) {
        off[base] = add + d.x;
        if (base + 1 < NSEG) off[base + 1] = add + l1;
        if (base + 2 < NSEG) off[base + 2] = add + l2;
    }
    if (t == 511) bsum[b] = ts[511];
}

// ------- k_scan2: add block prefix (in-block reduce of bsum), write final off + cur -------
__global__ __launch_bounds__(512) void k_scan2(const int* __restrict__ deg,
                                               int* __restrict__ off,
                                               const int* __restrict__ bsum,
                                               int* __restrict__ cur) {
    __shared__ int red[512];
    int b = blockIdx.x, t = threadIdx.x;
    red[t] = (t < b) ? bsum[t] : 0;    // b <= 107 < 512
    __syncthreads();
    for (int s = 256; s > 0; s >>= 1) {
        if (t < s) red[t] += red[t + s];
        __syncthreads();
    }
    int add = red[0];
    int base = b * 2048 + t * 4;
    if (base >= NSEG) return;
    if (base + 3 < NSEG) {
        int4 o = *(const int4*)(off + base);
        int4 d = *(const int4*)(deg + base);
        o.x += add; o.y += add; o.z += add; o.w += add;
        *(int4*)(off + base) = o;
        *(int4*)(cur + base) = make_int4(o.x - d.x, o.y - d.y, o.z - d.z, o.w - d.w);
    } else {
#pragma unroll
        for (int j = 0; j < 4; j++) {
            if (base + j < NSEG) {
                int o = off[base + j] + add;
                off[base + j] = o;
                cur[base + j] = o - deg[base + j];
            }
        }
    }
}

// ---- k_scatE: streaming binE -> csr scatter (writes land in dst's bucket region) ----
__global__ __launch_bounds__(512) void k_scatE(const int2* __restrict__ binE,
                                               int* __restrict__ cur,
                                               int* __restrict__ csr) {
    int e = blockIdx.x * 2048 + threadIdx.x * 4;
#pragma unroll
    for (int j = 0; j < 4; j++) {
        if (e + j < 2 * NEDGE) {
            int2 p = binE[e + j];
            int pos = atomicAdd(&cur[p.y], 1);
            csr[pos] = p.x;
        }
    }
}

// ------- k_host: G2+G3 fused, 32-row tiles, 2-way neighbor split (M=20000=625*32) -------
__global__ __launch_bounds__(512, 4) void k_host(
    const u16* __restrict__ xfb, const u16* __restrict__ xhb,
    const int* __restrict__ off, const int* __restrict__ csr,
    const u16* __restrict__ WT0, const float* __restrict__ b0,
    const u16* __restrict__ WT1l, u16* __restrict__ hT) {
    __shared__ __align__(16) u16 sA[32 * 136];
    __shared__ __align__(16) float sP[256 * 8];
    __shared__ int sOff[40];
    __shared__ int sCsr[2048];
    const int t = threadIdx.x;
    const int m0 = blockIdx.x * 32;
    if (t < 33) sOff[t] = off[N_FLOW + m0 - 1 + t];
    // direct half: xhb row, k in [64,128) — 256 chunks
    if (t < 256) {
        int r = t >> 3, c = t & 7;
        uint4 v = *(const uint4*)(xhb + (m0 + r) * 64 + c * 8);
        *(uint4*)(&sA[r * 136 + 64 + c * 8]) = v;
    }
    __syncthreads();
    int st0 = sOff[0];
    int win = sOff[32] - st0;
    bool fit = (win <= 2048);
    if (fit) for (int e = t; e < win; e += 512) sCsr[e] = csr[st0 + e];
    __syncthreads();
    // gather half: mean(xfb nbrs), k in [0,64) — 32r x 8c x 2 splits, U=8 per split
    const int r = t >> 4, s8 = (t >> 3) & 1, c = t & 7;
    const int st = sOff[r], en = sOff[r + 1];
    fx2 a[4] = {};
    for (int e = st + s8; e < en; e += 16) {
        int n[8];
#pragma unroll
        for (int j = 0; j < 8; j++) {
            int ee = e + 2 * j;
            n[j] = (ee < en) ? (fit ? sCsr[ee - st0] : csr[ee]) : -1;
        }
        uint4 u[8];
#pragma unroll
        for (int j = 0; j < 8; j++)
            u[j] = (n[j] >= 0) ? *(const uint4*)(xfb + n[j] * 64 + c * 8)
                               : make_uint4(0u, 0u, 0u, 0u);
#pragma unroll
        for (int j = 0; j < 8; j++) accp(a, u[j]);
    }
    if (s8) {
        float4* p = (float4*)(&sP[(r * 8 + c) * 8]);
        p[0] = make_float4(a[0].x, a[0].y, a[1].x, a[1].y);
        p[1] = make_float4(a[2].x, a[2].y, a[3].x, a[3].y);
    }
    __syncthreads();
    if (!s8) {
        const float4* p = (const float4*)(&sP[(r * 8 + c) * 8]);
        float4 v0 = p[0], v1 = p[1];
        a[0].x += v0.x; a[0].y += v0.y; a[1].x += v0.z; a[1].y += v0.w;
        a[2].x += v1.x; a[2].y += v1.y; a[3].x += v1.z; a[3].y += v1.w;
        float inv = (en > st) ? 1.f / (float)(en - st) : 0.f;
        *(uint4*)(&sA[r * 136 + c * 8]) = packp(a, inv);
    }
    __syncthreads();
    // MFMA: 8 waves = (wr in {0,1}) x (wc in 0..3, 32 cols each)
    const int w = t >> 6, wr = w >> 2, wc = w & 3;
    const int ln = t & 63, l15 = ln & 15, quad = ln >> 4;
    const u16* pA = sA + (wr * 16 + l15) * 136 + quad * 8;
    const u16* pB0 = WT0 + wc * 4096 + l15 * 128 + quad * 8;
    f32x4 acc[2];
    acc[0] = (f32x4){0.f, 0.f, 0.f, 0.f};
    acc[1] = (f32x4){0.f, 0.f, 0.f, 0.f};
#pragma unroll
    for (int s = 0; s < 4; s++) {
        bf16x8 av = *(const bf16x8*)(pA + s * 32);
#pragma unroll
        for (int tt = 0; tt < 2; tt++) {
            bf16x8 b = *(const bf16x8*)(pB0 + tt * 2048 + s * 32);
            acc[tt] = __builtin_amdgcn_mfma_f32_16x16x32_bf16(av, b, acc[tt], 0, 0, 0);
        }
    }
    __syncthreads();   // all phase-A reads done before h overwrites sA
#pragma unroll
    for (int tt = 0; tt < 2; tt++) {
        int col = wc * 32 + tt * 16 + l15;
        float bv = b0[col];
#pragma unroll
        for (int i = 0; i < 4; i++) {
            int rl = wr * 16 + quad * 4 + i;
            float v = acc[tt][i] + bv;
            v = v > 0.f ? v : 0.01f * v;
            sA[rl * 136 + col] = fbh(v);
        }
    }
    __syncthreads();   // h complete before phase B reads
    const u16* pB1 = WT1l + wc * 4096 + l15 * 128 + quad * 8;
    f32x4 accB[2];
    accB[0] = (f32x4){0.f, 0.f, 0.f, 0.f};
    accB[1] = (f32x4){0.f, 0.f, 0.f, 0.f};
#pragma unroll
    for (int s = 0; s < 4; s++) {
        bf16x8 av = *(const bf16x8*)(pA + s * 32);
#pragma unroll
        for (int tt = 0; tt < 2; tt++) {
            bf16x8 b = *(const bf16x8*)(pB1 + tt * 2048 + s * 32);
            accB[tt] = __builtin_amdgcn_mfma_f32_16x16x32_bf16(av, b, accB[tt], 0, 0, 0);
        }
    }
#pragma unroll
    for (int tt = 0; tt < 2; tt++) {
        int col = wc * 32 + tt * 16 + l15;
#pragma unroll
        for (int i = 0; i < 4; i++) {
            int row = m0 + wr * 16 + quad * 4 + i;
            hT[row * D_H + col] = fbh(accB[tt][i]);
        }
    }
}

// ---------------- k_mega: G1+G4 fused (M=200000, no tail) — R9 + accp ----------------
__global__ __launch_bounds__(512, 8) void k_mega(
    const u16* __restrict__ xfb, const u16* __restrict__ xhb,
    const int* __restrict__ off, const int* __restrict__ csr,
    const u16* __restrict__ hT,
    const u16* __restrict__ WT0, const float* __restrict__ b0,
    const u16* __restrict__ WT1r, const float* __restrict__ b1,
    const u16* __restrict__ WTo, const float* __restrict__ bout,
    float* __restrict__ OUT) {
    __shared__ __align__(16) u16 sA[64 * 136];    // A0 tile -> h band
    __shared__ __align__(16) u16 sAg[64 * 136];   // gathered mean(hT) tile -> g band
    __shared__ int sOff[72];
    __shared__ int sCsr[1024];
    const int t = threadIdx.x;
    const int m0 = blockIdx.x * 64;
    if (t < 65) {
        int idx = m0 - 1 + t;
        sOff[t] = (idx < 0) ? 0 : off[idx];
    }
    // direct half: xfb row, k in [64,128)
    {
        int r = t >> 3, c = t & 7;
        uint4 v = *(const uint4*)(xfb + (m0 + r) * 64 + c * 8);
        *(uint4*)(&sA[r * 136 + 64 + c * 8]) = v;
    }
    __syncthreads();
    int st0 = sOff[0];
    int win = sOff[64] - st0;
    bool fit = (win <= 1024);
    if (fit) for (int e = t; e < win; e += 512) sCsr[e] = csr[st0 + e];
    __syncthreads();
    // A0 gather half: mean(xhb nbrs), k in [0,64) — 512 tasks
    {
        int r = t >> 3, c = t & 7;
        uint4 o = gmean<4>(xhb, 64, c * 8, csr, sCsr, st0, fit, sOff[r], sOff[r + 1]);
        *(uint4*)(&sA[r * 136 + c * 8]) = o;
    }
    // agg tile: mean(hT nbrs), 128d — 1024 tasks, 2/thread
#pragma unroll
    for (int i = 0; i < 2; i++) {
        int q = t + i * 512;
        int r = q >> 4, c = q & 15;
        uint4 o = gmean<4>(hT, 128, c * 8, csr, sCsr, st0, fit, sOff[r], sOff[r + 1]);
        *(uint4*)(&sAg[r * 136 + c * 8]) = o;
    }
    __syncthreads();
    const int w = t >> 6, wr = w >> 1, wc = w & 1;   // wave = (row-band, col-half)
    const int ln = t & 63, l15 = ln & 15, quad = ln >> 4;
    const u16* pA = sA + (wr * 16 + l15) * 136 + quad * 8;
    const u16* pB0 = WT0 + wc * 8192 + l15 * 128 + quad * 8;
    f32x4 acc[4];
#pragma unroll
    for (int tt = 0; tt < 4; tt++) acc[tt] = (f32x4){0.f, 0.f, 0.f, 0.f};
#pragma unroll
    for (int s = 0; s < 4; s++) {
        bf16x8 av = *(const bf16x8*)(pA + s * 32);
#pragma unroll
        for (int tt = 0; tt < 4; tt++) {
            bf16x8 b = *(const bf16x8*)(pB0 + tt * 2048 + s * 32);
            acc[tt] = __builtin_amdgcn_mfma_f32_16x16x32_bf16(av, b, acc[tt], 0, 0, 0);
        }
    }
    __syncthreads();   // all phase-A reads of sA done before h overwrites it
    // epilogue1: h = lrelu(acc + b0) -> sA band (cols wc*64 ..)
#pragma unroll
    for (int tt = 0; tt < 4; tt++) {
        int col = wc * 64 + tt * 16 + l15;
        float bv = b0[col];
#pragma unroll
        for (int i = 0; i < 4; i++) {
            int rl = wr * 16 + quad * 4 + i;
            float v = acc[tt][i] + bv;
            v = v > 0.f ? v : 0.01f * v;
            sA[rl * 136 + col] = fbh(v);
        }
    }
    __syncthreads();   // h complete before phase B reads full rows
    // phase B: h @ WT1r^T
    const u16* pB1 = WT1r + wc * 8192 + l15 * 128 + quad * 8;
    f32x4 accB[4];
#pragma unroll
    for (int tt = 0; tt < 4; tt++) accB[tt] = (f32x4){0.f, 0.f, 0.f, 0.f};
#pragma unroll
    for (int s = 0; s < 4; s++) {
        bf16x8 av = *(const bf16x8*)(pA + s * 32);
#pragma unroll
        for (int tt = 0; tt < 4; tt++) {
            bf16x8 b = *(const bf16x8*)(pB1 + tt * 2048 + s * 32);
            accB[tt] = __builtin_amdgcn_mfma_f32_16x16x32_bf16(av, b, accB[tt], 0, 0, 0);
        }
    }
    // epilogue2: g = lrelu(accB + agg + b1) -> in-place over sAg
#pragma unroll
    for (int tt = 0; tt < 4; tt++) {
        int col = wc * 64 + tt * 16 + l15;
        float bv = b1[col];
#pragma unroll
        for (int i = 0; i < 4; i++) {
            int rl = wr * 16 + quad * 4 + i;
            float v = accB[tt][i] + bfh(sAg[rl * 136 + col]) + bv;
            v = v > 0.f ? v : 0.01f * v;
            sAg[rl * 136 + col] = fbh(v);
        }
    }
    __syncthreads();   // g complete before phase C reads full rows
    // phase C: out = g @ WTo^T + bout  (each wave: 16-row band x 16-col tile wc)
    const u16* pG = sAg + (wr * 16 + l15) * 136 + quad * 8;
    const u16* pBo = WTo + wc * 2048 + l15 * 128 + quad * 8;
    f32x4 acc2 = (f32x4){0.f, 0.f, 0.f, 0.f};
#pragma unroll
    for (int s = 0; s < 4; s++) {
        bf16x8 g = *(const bf16x8*)(pG + s * 32);
        bf16x8 b = *(const bf16x8*)(pBo + s * 32);
        acc2 = __builtin_amdgcn_mfma_f32_16x16x32_bf16(g, b, acc2, 0, 0, 0);
    }
    {
        int col = wc * 16 + l15;
        float bv = bout[col];
#pragma unroll
        for (int i = 0; i < 4; i++) {
            int row = m0 + wr * 16 + quad * 4 + i;
            OUT[row * D_OUT + col] = acc2[i] + bv;
        }
    }
}

extern "C" void kernel_launch(void* const* d_in, const int* in_sizes, int n_in,
                              void* d_out, int out_size, void* d_ws, size_t ws_size,
                              hipStream_t stream) {
    const float* x_host  = (const float*)d_in[0];
    const float* x_flow  = (const float*)d_in[1];
    const int* src_hf  = (const int*)d_in[2];
    const int* dst_hf  = (const int*)d_in[3];
    const int* src_fh  = (const int*)d_in[4];
    const int* dst_fh  = (const int*)d_in[5];
    const float* W0_hf_l = (const float*)d_in[6];
    const float* W0_hf_r = (const float*)d_in[7];
    const float* b0_hf   = (const float*)d_in[8];
    const float* W0_fh_l = (const float*)d_in[9];
    const float* W0_fh_r = (const float*)d_in[10];
    const float* b0_fh   = (const float*)d_in[11];
    const float* W1_hf_l = (const float*)d_in[12];
    const float* W1_hf_r = (const float*)d_in[13];
    const float* b1_hf   = (const float*)d_in[14];
    const float* W_out   = (const float*)d_in[18];
    const float* b_out   = (const float*)d_in[19];
    float* out = (float*)d_out;

    // workspace layout (bytes), all disjoint unless noted, total <= 48.7 MB
    char* ws = (char*)d_ws;
    int*  off    = (int*)(ws + 0);             //   880,000
    int*  csr    = (int*)(ws + 880000);        // 4,800,000
    u16*  hT     = (u16*)(ws + 5680000);       // 5,120,000  (written by k_host)
    int*  deg    = (int*)(ws + 5680000);       //   880,000  } alias hT region:
    int*  cur    = (int*)(ws + 6560000);       //   880,000  } dead before k_host
    int*  bsum   = (int*)(ws + 7440000);       //       512  } runs
    u16*  xfb    = (u16*)(ws + 10800000);      // 25,600,000
    u16*  xhb    = (u16*)(ws + 36400000);      //  2,560,000
    int2* binE   = (int2*)(ws + 38960000);     //  9,600,000
    int*  bcnt   = (int*)(ws + 48560000);      //  1,280
    int*  bcur   = (int*)(ws + 48561280);      //  1,280
    u16*  WT0_hf = (u16*)(ws + 48562560);      //  32,768
    u16*  WT0_fh = (u16*)(ws + 48595328);      //  32,768
    u16*  WT1_l  = (u16*)(ws + 48628096);      //  32,768
    u16*  WT1_r  = (u16*)(ws + 48660864);      //  32,768
    u16*  WTo    = (u16*)(ws + 48693632);      //   8,192

    hipMemsetAsync(bcnt, 0, 2560, stream);     // bcnt + bcur
    hipMemsetAsync(deg, 0, 880000, stream);
    k_pre<<<34 + 6875 + NEB, 256, 0, stream>>>(
        W0_hf_l, W0_hf_r, W0_fh_l, W0_fh_r, W1_hf_l, W1_hf_r, W_out,
        WT0_hf, WT0_fh, WT1_l, WT1_r, WTo,
        x_flow, x_host, xfb, xhb, dst_hf, dst_fh, bcnt, deg);
    kb2<<<NEB, 256, 0, stream>>>(src_hf, dst_hf, src_fh, dst_fh, bcnt, bcur, binE);
    k_scan1<<<NB_SCAN, 512, 0, stream>>>(deg, off, bsum);
    k_scan2<<<NB_SCAN, 512, 0, stream>>>(deg, off, bsum, cur);
    k_scatE<<<NEB, 512, 0, stream>>>(binE, cur, csr);
    k_host<<<625, 512, 0, stream>>>(xfb, xhb, off, csr, WT0_fh, b0_fh, WT1_l, hT);
    k_mega<<<3125, 512, 0, stream>>>(xfb, xhb, off, csr, hT, WT0_hf, b0_hf,
                                     WT1_r, b1_hf, WTo, b_out, out);
}

// Round 6
// 389.012 us; speedup vs baseline: 1.1123x; 1.0654x over previous
//
#include <hip/hip_runtime.h>

// HeteroGNN on MI355X. Inputs/weights/output fp32 (per reference); intermediates bf16.
// Round 14: REVERT to R9 config (best measured: 344.2us) + instrumentation split.
//  - R10-R13 post-mortems: every prep-rebuild regressed (R10 merged gather: VGPR spill,
//    WRITE 25->102MB; R12 scan+random-scatter: +93us, 64B-line RMW amplification;
//    R13 hybrid: +70us, the 1.2M random per-node deg atomics in k_pre). The R9 bucket
//    pipeline (k_pre hist / kb2 binE / kb3 CSR) stands as best measured.
//  - Unknown: WHICH of {k_pre,kb2,kb3,k_host} owns the ~207us non-mega time. The top-5
//    counter view only shows the largest kernel (k_mega). So: k_mega is split into 4
//    offset launches (~34us each) => any prep kernel >=35us surfaces in top-5 WITH its
//    counters. Cost ~2-6us launch/tail overhead, buys per-kernel visibility.
//  - gmean uses packed f32x2 accumulate (R13-measured neutral, VGPR 28->24).
//   k_pre  : weights->bf16 WT[n][k] | x->bf16 pools | bucket histogram
//   kb2    : bin scatter (in-block 275-prefix)  kb3: per-bucket CSR build
//   k_host : h=lrelu([mean(xfb nbrs)|xhb]@WT0_fh^T+b0); hT=h@WT1_l^T        (M=20000)
//   k_mega : h=lrelu([mean(xhb nbrs)|xfb]@WT0_hf^T+b0);
//            g=lrelu(h@WT1_r^T+mean(hT nbrs)+b1); out=g@WTo^T+bout          (M=200000)
// g_host dead in reference -> W1_fh_* unused.

#define N_HOST 20000
#define N_FLOW 200000
#define NEDGE  600000
#define D_IN   64
#define D_H    128
#define D_OUT  32
#define NSEG   (N_FLOW + N_HOST)
#define NBKT_F 196
#define NBKT_H 79
#define NBKT   (NBKT_F + NBKT_H)   // 275
#define NEB    586                 // ceil(1200000/2048)

typedef unsigned short u16;
typedef unsigned int   u32;
typedef short bf16x8 __attribute__((ext_vector_type(8)));
typedef float f32x4  __attribute__((ext_vector_type(4)));
typedef float fx2    __attribute__((ext_vector_type(2)));

__device__ __forceinline__ float bfh(u16 h) { return __uint_as_float(((u32)h) << 16); }
__device__ __forceinline__ u16 fbh(float f) {
    u32 u = __float_as_uint(f);
    return (u16)((u + 0x7fffu + ((u >> 16) & 1u)) >> 16);   // RNE
}
__device__ __forceinline__ u32 packbf(float x, float y) {
    return (u32)fbh(x) | ((u32)fbh(y) << 16);
}
// packed bf16 unpack+accumulate (v_pk_add_f32)
__device__ __forceinline__ void accp(fx2* a, uint4 u) {
    fx2 p;
    p.x = __uint_as_float(u.x << 16); p.y = __uint_as_float(u.x & 0xffff0000u); a[0] += p;
    p.x = __uint_as_float(u.y << 16); p.y = __uint_as_float(u.y & 0xffff0000u); a[1] += p;
    p.x = __uint_as_float(u.z << 16); p.y = __uint_as_float(u.z & 0xffff0000u); a[2] += p;
    p.x = __uint_as_float(u.w << 16); p.y = __uint_as_float(u.w & 0xffff0000u); a[3] += p;
}
__device__ __forceinline__ uint4 packp(const fx2* a, float inv) {
    uint4 o;
    o.x = packbf(a[0].x * inv, a[0].y * inv);
    o.y = packbf(a[1].x * inv, a[1].y * inv);
    o.z = packbf(a[2].x * inv, a[2].y * inv);
    o.w = packbf(a[3].x * inv, a[3].y * inv);
    return o;
}

// gather-mean of 16B chunks; neighbor indices from LDS window (fit) or global fallback.
template <int U>
__device__ __forceinline__ uint4 gmean(const u16* __restrict__ pool, int rs, int coff,
                                       const int* __restrict__ gcsr,
                                       const int* __restrict__ lcsr, int st0, bool fit,
                                       int st, int en) {
    fx2 a[4] = {};
    for (int e = st; e < en; e += U) {
        int n[U];
#pragma unroll
        for (int j = 0; j < U; j++)
            n[j] = (e + j < en) ? (fit ? lcsr[e + j - st0] : gcsr[e + j]) : -1;
        uint4 u[U];
#pragma unroll
        for (int j = 0; j < U; j++)
            u[j] = (n[j] >= 0) ? *(const uint4*)(pool + n[j] * rs + coff)
                               : make_uint4(0u, 0u, 0u, 0u);
#pragma unroll
        for (int j = 0; j < U; j++) accp(a, u[j]);
    }
    float inv = (en > st) ? 1.f / (float)(en - st) : 0.f;
    return packp(a, inv);
}

// ---------------- k_pre: weights transpose | x->bf16 | bucket histogram ----------------
__global__ void k_pre(const float* __restrict__ W0_hf_l, const float* __restrict__ W0_hf_r,
                      const float* __restrict__ W0_fh_l, const float* __restrict__ W0_fh_r,
                      const float* __restrict__ W1_l, const float* __restrict__ W1_r,
                      const float* __restrict__ Wout,
                      u16* __restrict__ WT0_hf, u16* __restrict__ WT0_fh,
                      u16* __restrict__ WT1_l, u16* __restrict__ WT1_r,
                      u16* __restrict__ WTo,
                      const float* __restrict__ xf, const float* __restrict__ xh,
                      u16* __restrict__ xfb, u16* __restrict__ xhb,
                      const int* __restrict__ dst_hf, const int* __restrict__ dst_fh,
                      int* __restrict__ bcnt) {
    int b = blockIdx.x, t = threadIdx.x;
    if (b < 34) {
        u16 tmp[8];
        if (b < 32) {
            int e = (b & 7) * 2048 + t * 8;
            int n = e >> 7, k0 = e & 127;
            if (b < 8) {
#pragma unroll
                for (int j = 0; j < 8; j++) {
                    int k = k0 + j;
                    tmp[j] = fbh(k < 64 ? W0_hf_l[k * D_H + n] : W0_hf_r[(k - 64) * D_H + n]);
                }
                *(uint4*)(WT0_hf + n * 128 + k0) = *(uint4*)tmp;
            } else if (b < 16) {
#pragma unroll
                for (int j = 0; j < 8; j++) {
                    int k = k0 + j;
                    tmp[j] = fbh(k < 64 ? W0_fh_l[k * D_H + n] : W0_fh_r[(k - 64) * D_H + n]);
                }
                *(uint4*)(WT0_fh + n * 128 + k0) = *(uint4*)tmp;
            } else if (b < 24) {
#pragma unroll
                for (int j = 0; j < 8; j++) tmp[j] = fbh(W1_l[(k0 + j) * D_H + n]);
                *(uint4*)(WT1_l + n * 128 + k0) = *(uint4*)tmp;
            } else {
#pragma unroll
                for (int j = 0; j < 8; j++) tmp[j] = fbh(W1_r[(k0 + j) * D_H + n]);
                *(uint4*)(WT1_r + n * 128 + k0) = *(uint4*)tmp;
            }
        } else {
            int e = (b - 32) * 2048 + t * 8;
            int n = e >> 7, k0 = e & 127;
#pragma unroll
            for (int j = 0; j < 8; j++) tmp[j] = fbh(Wout[(k0 + j) * D_OUT + n]);
            *(uint4*)(WTo + n * 128 + k0) = *(uint4*)tmp;
        }
    } else if (b < 34 + 6875) {
        int q = (b - 34) * 256 + t;       // 8 floats per thread
        const int TF = (N_FLOW * D_IN) / 8;
        const int TT = TF + (N_HOST * D_IN) / 8;
        if (q >= TT) return;
        const float* src; u16* dst; int base;
        if (q < TF) { src = xf; dst = xfb; base = q * 8; }
        else        { src = xh; dst = xhb; base = (q - TF) * 8; }
        float4 f0 = *(const float4*)(src + base);
        float4 f1 = *(const float4*)(src + base + 4);
        uint4 o;
        o.x = packbf(f0.x, f0.y); o.y = packbf(f0.z, f0.w);
        o.z = packbf(f1.x, f1.y); o.w = packbf(f1.z, f1.w);
        *(uint4*)(dst + base) = o;
    } else {
        __shared__ int h[NBKT];
        for (int j = t; j < NBKT; j += 256) h[j] = 0;
        __syncthreads();
        int base = (b - 34 - 6875) * 2048;
#pragma unroll
        for (int i = 0; i < 8; i++) {
            int e = base + t + i * 256;
            if (e < 2 * NEDGE) {
                int bkt = (e < NEDGE) ? (dst_hf[e] >> 10)
                                      : (NBKT_F + (dst_fh[e - NEDGE] >> 8));
                atomicAdd(&h[bkt], 1);
            }
        }
        __syncthreads();
        for (int j = t; j < NBKT; j += 256)
            if (h[j]) atomicAdd(&bcnt[j], h[j]);
    }
}

// ---------------- kb2: bin scatter (in-block prefix of bcnt) ----------------
__global__ void kb2(const int* __restrict__ src_hf, const int* __restrict__ dst_hf,
                    const int* __restrict__ src_fh, const int* __restrict__ dst_fh,
                    const int* __restrict__ bcnt, int* __restrict__ bcur,
                    int2* __restrict__ binE) {
    __shared__ int sp[512];    // becomes exclusive bucket base
    __shared__ int lh[NBKT];
    __shared__ int lb[NBKT];
    int t = threadIdx.x;
    int o1 = (t < NBKT) ? bcnt[t] : 0;
    int o2 = (t + 256 < NBKT) ? bcnt[t + 256] : 0;
    sp[t] = o1; sp[t + 256] = o2;
    for (int j = t; j < NBKT; j += 256) lh[j] = 0;
    __syncthreads();
    for (int d = 1; d < 512; d <<= 1) {
        int a0 = (t >= d) ? sp[t - d] : 0;
        int a1 = sp[t + 256 - d];
        __syncthreads();
        sp[t] += a0; sp[t + 256] += a1;
        __syncthreads();
    }
    sp[t] -= o1; sp[t + 256] -= o2;   // exclusive
    __syncthreads();
    int base = blockIdx.x * 2048;
    int mybkt[8], myrank[8], mysrc[8], mydst[8];
#pragma unroll
    for (int i = 0; i < 8; i++) {
        int e = base + t + i * 256;
        mybkt[i] = -1;
        if (e < 2 * NEDGE) {
            int s, d;
            if (e < NEDGE) { s = src_hf[e]; d = dst_hf[e]; }
            else           { s = src_fh[e - NEDGE]; d = dst_fh[e - NEDGE] + N_FLOW; }
            int bkt = (d < N_FLOW) ? (d >> 10) : (NBKT_F + ((d - N_FLOW) >> 8));
            mybkt[i] = bkt; mysrc[i] = s; mydst[i] = d;
            myrank[i] = atomicAdd(&lh[bkt], 1);
        }
    }
    __syncthreads();
    for (int j = t; j < NBKT; j += 256)
        lb[j] = lh[j] ? atomicAdd(&bcur[j], lh[j]) : 0;
    __syncthreads();
#pragma unroll
    for (int i = 0; i < 8; i++) {
        if (mybkt[i] >= 0) {
            int pos = sp[mybkt[i]] + lb[mybkt[i]] + myrank[i];
            binE[pos] = make_int2(mysrc[i], mydst[i]);
        }
    }
}

// ---------------- kb3: per-bucket CSR (in-block prefix of bcnt) ----------------
__global__ __launch_bounds__(256) void kb3(const int2* __restrict__ binE,
                                           const int* __restrict__ bcnt,
                                           int* __restrict__ off, int* __restrict__ csr) {
    __shared__ int sp[512];
    __shared__ int deg[1024];
    __shared__ int ts[256];
    int b = blockIdx.x, t = threadIdx.x;
    sp[t] = (t < NBKT) ? bcnt[t] : 0;
    sp[t + 256] = (t + 256 < NBKT) ? bcnt[t + 256] : 0;
    __syncthreads();
    for (int d = 1; d < 512; d <<= 1) {
        int a0 = (t >= d) ? sp[t - d] : 0;
        int a1 = sp[t + 256 - d];
        __syncthreads();
        sp[t] += a0; sp[t + 256] += a1;
        __syncthreads();
    }
    int e0 = (b == 0) ? 0 : sp[b - 1];
    int e1 = sp[b];
    int nbase, ncnt;
    if (b < NBKT_F) { nbase = b << 10; ncnt = min(1024, N_FLOW - nbase); }
    else { nbase = N_FLOW + ((b - NBKT_F) << 8); ncnt = min(256, NSEG - nbase); }
    for (int i = t; i < 1024; i += 256) deg[i] = 0;
    __syncthreads();
    for (int e = e0 + t; e < e1; e += 256) {
        int2 p = binE[e];
        atomicAdd(&deg[p.y - nbase], 1);
    }
    __syncthreads();
    int loc[4]; int s = 0;
#pragma unroll
    for (int j = 0; j < 4; j++) { loc[j] = s; s += deg[t * 4 + j]; }
    ts[t] = s;
    __syncthreads();
    for (int d = 1; d < 256; d <<= 1) {
        int x = (t >= d) ? ts[t - d] : 0;
        __syncthreads();
        ts[t] += x;
        __syncthreads();
    }
    int base2 = e0 + ts[t] - s;
    int dsave[4];
#pragma unroll
    for (int j = 0; j < 4; j++) dsave[j] = deg[t * 4 + j];
    __syncthreads();
#pragma unroll
    for (int j = 0; j < 4; j++) {
        int idx = t * 4 + j;
        int st = base2 + loc[j];
        deg[idx] = st;
        if (idx < ncnt) off[nbase + idx] = st + dsave[j];   // segment END
    }
    __syncthreads();
    for (int e = e0 + t; e < e1; e += 256) {
        int2 p = binE[e];
        int r = atomicAdd(&deg[p.y - nbase], 1);
        csr[r] = p.x;
    }
}

// ---------------- k_host: G2+G3 fused (M=20000), 512 thr, col-split waves ----------------
__global__ __launch_bounds__(512, 4) void k_host(
    const u16* __restrict__ xfb, const u16* __restrict__ xhb,
    const int* __restrict__ off, const int* __restrict__ csr,
    const u16* __restrict__ WT0, const float* __restrict__ b0,
    const u16* __restrict__ WT1l, u16* __restrict__ hT, int M) {
    __shared__ __align__(16) u16 sA[64 * 136];
    __shared__ int sOff[72];
    __shared__ int sCsr[2560];
    const int t = threadIdx.x;
    const int m0 = blockIdx.x * 64;
    if (t < 65) {
        int idx = N_FLOW + m0 - 1 + t;
        sOff[t] = off[min(idx, NSEG - 1)];
    }
    // direct half: xhb row, k in [64,128)  — 512 chunks, 1/thread
    {
        int r = t >> 3, c = t & 7;
        int row = m0 + r;
        uint4 v = make_uint4(0u, 0u, 0u, 0u);
        if (row < M) v = *(const uint4*)(xhb + row * 64 + c * 8);
        *(uint4*)(&sA[r * 136 + 64 + c * 8]) = v;
    }
    __syncthreads();
    int st0 = sOff[0];
    int win = sOff[64] - st0;
    bool fit = (win <= 2560);
    if (fit) for (int e = t; e < win; e += 512) sCsr[e] = csr[st0 + e];
    __syncthreads();
    // gather half: mean(xfb nbrs), k in [0,64) — deg~30, batch 8 loads/round
    {
        int r = t >> 3, c = t & 7;
        int row = m0 + r;
        uint4 o = make_uint4(0u, 0u, 0u, 0u);
        if (row < M) o = gmean<8>(xfb, 64, c * 8, csr, sCsr, st0, fit, sOff[r], sOff[r + 1]);
        *(uint4*)(&sA[r * 136 + c * 8]) = o;
    }
    __syncthreads();
    const int w = t >> 6, wr = w >> 1, wc = w & 1;
    const int ln = t & 63, l15 = ln & 15, quad = ln >> 4;
    const u16* pA = sA + (wr * 16 + l15) * 136 + quad * 8;
    const u16* pB0 = WT0 + wc * 8192 + l15 * 128 + quad * 8;
    f32x4 acc[4];
#pragma unroll
    for (int tt = 0; tt < 4; tt++) acc[tt] = (f32x4){0.f, 0.f, 0.f, 0.f};
#pragma unroll
    for (int s = 0; s < 4; s++) {
        bf16x8 a = *(const bf16x8*)(pA + s * 32);
#pragma unroll
        for (int tt = 0; tt < 4; tt++) {
            bf16x8 b = *(const bf16x8*)(pB0 + tt * 2048 + s * 32);
            acc[tt] = __builtin_amdgcn_mfma_f32_16x16x32_bf16(a, b, acc[tt], 0, 0, 0);
        }
    }
    __syncthreads();   // all phase-A reads of sA done before h overwrites it
#pragma unroll
    for (int tt = 0; tt < 4; tt++) {
        int col = wc * 64 + tt * 16 + l15;
        float bv = b0[col];
#pragma unroll
        for (int i = 0; i < 4; i++) {
            int rl = wr * 16 + quad * 4 + i;
            float v = acc[tt][i] + bv;
            v = v > 0.f ? v : 0.01f * v;
            sA[rl * 136 + col] = fbh(v);
        }
    }
    __syncthreads();   // h complete (both col-half waves) before phase B reads
    const u16* pB1 = WT1l + wc * 8192 + l15 * 128 + quad * 8;
    f32x4 accB[4];
#pragma unroll
    for (int tt = 0; tt < 4; tt++) accB[tt] = (f32x4){0.f, 0.f, 0.f, 0.f};
#pragma unroll
    for (int s = 0; s < 4; s++) {
        bf16x8 a = *(const bf16x8*)(pA + s * 32);
#pragma unroll
        for (int tt = 0; tt < 4; tt++) {
            bf16x8 b = *(const bf16x8*)(pB1 + tt * 2048 + s * 32);
            accB[tt] = __builtin_amdgcn_mfma_f32_16x16x32_bf16(a, b, accB[tt], 0, 0, 0);
        }
    }
#pragma unroll
    for (int tt = 0; tt < 4; tt++) {
        int col = wc * 64 + tt * 16 + l15;
#pragma unroll
        for (int i = 0; i < 4; i++) {
            int row = m0 + wr * 16 + quad * 4 + i;
            if (row < M) hT[row * D_H + col] = fbh(accB[tt][i]);
        }
    }
}

// ---------- k_mega: G1+G4 fused, 512 thr — launched in 4 offset slices ----------
__global__ __launch_bounds__(512, 8) void k_mega(
    const u16* __restrict__ xfb, const u16* __restrict__ xhb,
    const int* __restrict__ off, const int* __restrict__ csr,
    const u16* __restrict__ hT,
    const u16* __restrict__ WT0, const float* __restrict__ b0,
    const u16* __restrict__ WT1r, const float* __restrict__ b1,
    const u16* __restrict__ WTo, const float* __restrict__ bout,
    float* __restrict__ OUT, int moff) {
    __shared__ __align__(16) u16 sA[64 * 136];    // A0 tile -> h band
    __shared__ __align__(16) u16 sAg[64 * 136];   // gathered mean(hT) tile -> g band
    __shared__ int sOff[72];
    __shared__ int sCsr[1024];
    const int t = threadIdx.x;
    const int m0 = (blockIdx.x + moff) * 64;
    if (t < 65) {
        int idx = m0 - 1 + t;
        sOff[t] = (idx < 0) ? 0 : off[idx];
    }
    // direct half: xfb row, k in [64,128) — 512 chunks, 1/thread
    {
        int r = t >> 3, c = t & 7;
        uint4 v = *(const uint4*)(xfb + (m0 + r) * 64 + c * 8);
        *(uint4*)(&sA[r * 136 + 64 + c * 8]) = v;
    }
    __syncthreads();
    int st0 = sOff[0];
    int win = sOff[64] - st0;
    bool fit = (win <= 1024);
    if (fit) for (int e = t; e < win; e += 512) sCsr[e] = csr[st0 + e];
    __syncthreads();
    // A0 gather half: mean(xhb nbrs), k in [0,64) — 512 tasks
    {
        int r = t >> 3, c = t & 7;
        uint4 o = gmean<4>(xhb, 64, c * 8, csr, sCsr, st0, fit, sOff[r], sOff[r + 1]);
        *(uint4*)(&sA[r * 136 + c * 8]) = o;
    }
    // agg tile: mean(hT nbrs), 128d — 1024 tasks, 2/thread
#pragma unroll
    for (int i = 0; i < 2; i++) {
        int q = t + i * 512;
        int r = q >> 4, c = q & 15;
        uint4 o = gmean<4>(hT, 128, c * 8, csr, sCsr, st0, fit, sOff[r], sOff[r + 1]);
        *(uint4*)(&sAg[r * 136 + c * 8]) = o;
    }
    __syncthreads();
    const int w = t >> 6, wr = w >> 1, wc = w & 1;   // wave = (row-band, col-half)
    const int ln = t & 63, l15 = ln & 15, quad = ln >> 4;
    const u16* pA = sA + (wr * 16 + l15) * 136 + quad * 8;
    const u16* pB0 = WT0 + wc * 8192 + l15 * 128 + quad * 8;
    f32x4 acc[4];
#pragma unroll
    for (int tt = 0; tt < 4; tt++) acc[tt] = (f32x4){0.f, 0.f, 0.f, 0.f};
#pragma unroll
    for (int s = 0; s < 4; s++) {
        bf16x8 av = *(const bf16x8*)(pA + s * 32);
#pragma unroll
        for (int tt = 0; tt < 4; tt++) {
            bf16x8 b = *(const bf16x8*)(pB0 + tt * 2048 + s * 32);
            acc[tt] = __builtin_amdgcn_mfma_f32_16x16x32_bf16(av, b, acc[tt], 0, 0, 0);
        }
    }
    __syncthreads();   // all phase-A reads of sA done before h overwrites it
    // epilogue1: h = lrelu(acc + b0) -> sA band (cols wc*64 ..)
#pragma unroll
    for (int tt = 0; tt < 4; tt++) {
        int col = wc * 64 + tt * 16 + l15;
        float bv = b0[col];
#pragma unroll
        for (int i = 0; i < 4; i++) {
            int rl = wr * 16 + quad * 4 + i;
            float v = acc[tt][i] + bv;
            v = v > 0.f ? v : 0.01f * v;
            sA[rl * 136 + col] = fbh(v);
        }
    }
    __syncthreads();   // h complete before phase B reads full rows
    // phase B: h @ WT1r^T
    const u16* pB1 = WT1r + wc * 8192 + l15 * 128 + quad * 8;
    f32x4 accB[4];
#pragma unroll
    for (int tt = 0; tt < 4; tt++) accB[tt] = (f32x4){0.f, 0.f, 0.f, 0.f};
#pragma unroll
    for (int s = 0; s < 4; s++) {
        bf16x8 av = *(const bf16x8*)(pA + s * 32);
#pragma unroll
        for (int tt = 0; tt < 4; tt++) {
            bf16x8 b = *(const bf16x8*)(pB1 + tt * 2048 + s * 32);
            accB[tt] = __builtin_amdgcn_mfma_f32_16x16x32_bf16(av, b, accB[tt], 0, 0, 0);
        }
    }
    // epilogue2: g = lrelu(accB + agg + b1) -> in-place over sAg
#pragma unroll
    for (int tt = 0; tt < 4; tt++) {
        int col = wc * 64 + tt * 16 + l15;
        float bv = b1[col];
#pragma unroll
        for (int i = 0; i < 4; i++) {
            int rl = wr * 16 + quad * 4 + i;
            float v = accB[tt][i] + bfh(sAg[rl * 136 + col]) + bv;
            v = v > 0.f ? v : 0.01f * v;
            sAg[rl * 136 + col] = fbh(v);
        }
    }
    __syncthreads();   // g complete before phase C reads full rows
    // phase C: out = g @ WTo^T + bout  (each wave: 16-row band x 16-col tile wc)
    const u16* pG = sAg + (wr * 16 + l15) * 136 + quad * 8;
    const u16* pBo = WTo + wc * 2048 + l15 * 128 + quad * 8;
    f32x4 acc2 = (f32x4){0.f, 0.f, 0.f, 0.f};
#pragma unroll
    for (int s = 0; s < 4; s++) {
        bf16x8 g = *(const bf16x8*)(pG + s * 32);
        bf16x8 b = *(const bf16x8*)(pBo + s * 32);
        acc2 = __builtin_amdgcn_mfma_f32_16x16x32_bf16(g, b, acc2, 0, 0, 0);
    }
    {
        int col = wc * 16 + l15;
        float bv = bout[col];
#pragma unroll
        for (int i = 0; i < 4; i++) {
            int row = m0 + wr * 16 + quad * 4 + i;
            OUT[row * D_OUT + col] = acc2[i] + bv;
        }
    }
}

extern "C" void kernel_launch(void* const* d_in, const int* in_sizes, int n_in,
                              void* d_out, int out_size, void* d_ws, size_t ws_size,
                              hipStream_t stream) {
    const float* x_host  = (const float*)d_in[0];
    const float* x_flow  = (const float*)d_in[1];
    const int* src_hf  = (const int*)d_in[2];
    const int* dst_hf  = (const int*)d_in[3];
    const int* src_fh  = (const int*)d_in[4];
    const int* dst_fh  = (const int*)d_in[5];
    const float* W0_hf_l = (const float*)d_in[6];
    const float* W0_hf_r = (const float*)d_in[7];
    const float* b0_hf   = (const float*)d_in[8];
    const float* W0_fh_l = (const float*)d_in[9];
    const float* W0_fh_r = (const float*)d_in[10];
    const float* b0_fh   = (const float*)d_in[11];
    const float* W1_hf_l = (const float*)d_in[12];
    const float* W1_hf_r = (const float*)d_in[13];
    const float* b1_hf   = (const float*)d_in[14];
    const float* W_out   = (const float*)d_in[18];
    const float* b_out   = (const float*)d_in[19];
    float* out = (float*)d_out;

    // workspace layout (bytes), all disjoint, total ~48.7 MB
    char* ws = (char*)d_ws;
    int*  off    = (int*)(ws + 0);             //   880,000
    int*  csr    = (int*)(ws + 880000);        // 4,800,000
    u16*  hT     = (u16*)(ws + 5680000);       //  5,120,000
    u16*  xfb    = (u16*)(ws + 10800000);      // 25,600,000
    u16*  xhb    = (u16*)(ws + 36400000);      //  2,560,000
    int2* binE   = (int2*)(ws + 38960000);     //  9,600,000
    int*  bcnt   = (int*)(ws + 48560000);      //  1,280
    int*  bcur   = (int*)(ws + 48561280);      //  1,280
    u16*  WT0_hf = (u16*)(ws + 48562560);      //  32,768
    u16*  WT0_fh = (u16*)(ws + 48595328);      //  32,768
    u16*  WT1_l  = (u16*)(ws + 48628096);      //  32,768
    u16*  WT1_r  = (u16*)(ws + 48660864);      //  32,768
    u16*  WTo    = (u16*)(ws + 48693632);      //   8,192

    hipMemsetAsync(bcnt, 0, 2560, stream);     // bcnt + bcur
    k_pre<<<34 + 6875 + NEB, 256, 0, stream>>>(
        W0_hf_l, W0_hf_r, W0_fh_l, W0_fh_r, W1_hf_l, W1_hf_r, W_out,
        WT0_hf, WT0_fh, WT1_l, WT1_r, WTo,
        x_flow, x_host, xfb, xhb, dst_hf, dst_fh, bcnt);
    kb2<<<NEB, 256, 0, stream>>>(src_hf, dst_hf, src_fh, dst_fh, bcnt, bcur, binE);
    kb3<<<NBKT, 256, 0, stream>>>(binE, bcnt, off, csr);
    k_host<<<313, 512, 0, stream>>>(xfb, xhb, off, csr, WT0_fh, b0_fh, WT1_l, hT, N_HOST);
    // k_mega split into 4 offset slices (782+782+782+779 = 3125) purely so that prep
    // kernels >=~35us surface in the top-5 counter dump with their own counters.
    k_mega<<<782, 512, 0, stream>>>(xfb, xhb, off, csr, hT, WT0_hf, b0_hf,
                                    WT1_r, b1_hf, WTo, b_out, out, 0);
    k_mega<<<782, 512, 0, stream>>>(xfb, xhb, off, csr, hT, WT0_hf, b0_hf,
                                    WT1_r, b1_hf, WTo, b_out, out, 782);
    k_mega<<<782, 512, 0, stream>>>(xfb, xhb, off, csr, hT, WT0_hf, b0_hf,
                                    WT1_r, b1_hf, WTo, b_out, out, 1564);
    k_mega<<<779, 512, 0, stream>>>(xfb, xhb, off, csr, hT, WT0_hf, b0_hf,
                                    WT1_r, b1_hf, WTo, b_out, out, 2346);
}

// Round 7
// 369.434 us; speedup vs baseline: 1.1712x; 1.0530x over previous
//
#include <hip/hip_runtime.h>

// HeteroGNN on MI355X. Inputs/weights/output fp32 (per reference); intermediates bf16.
// Round 15: kb3 parallelism rebuild + 2-slice instrumentation.
//  - R14: 4-way k_mega split cost 48us (782 blocks < 1024 cant fill 4/CU + 4 tails).
//    Info: NO prep kernel > ~46us; ~203us spread over k_pre/kb2/kb3/k_host.
//  - k_mega now 2 slices (1563+1562, both >1024 so machine stays full; ~5-10us cost)
//    => top-5 = 2 mega halves + the 3 LARGEST prep kernels with counters.
//  - kb3 rebuilt 275 -> 1100 blocks (4x sub-split of every bucket; sub-block scans
//    parent binE window, filters to its node sub-range, 'below' count gives csr base;
//    output layout bit-identical). Was 1.07 blocks/CU with 79 host buckets scanning
//    ~7600 edges each; now 4.3/CU. +29MB redundant binE reads (~5us BW) for 4x par.
//   k_pre  : weights->bf16 WT[n][k] | x->bf16 pools | bucket histogram
//   kb2    : bin scatter (in-block 275-prefix)  kb3: per-sub-bucket CSR build
//   k_host : h=lrelu([mean(xfb nbrs)|xhb]@WT0_fh^T+b0); hT=h@WT1_l^T        (M=20000)
//   k_mega : h=lrelu([mean(xhb nbrs)|xfb]@WT0_hf^T+b0);
//            g=lrelu(h@WT1_r^T+mean(hT nbrs)+b1); out=g@WTo^T+bout          (M=200000)
// g_host dead in reference -> W1_fh_* unused.

#define N_HOST 20000
#define N_FLOW 200000
#define NEDGE  600000
#define D_IN   64
#define D_H    128
#define D_OUT  32
#define NSEG   (N_FLOW + N_HOST)
#define NBKT_F 196
#define NBKT_H 79
#define NBKT   (NBKT_F + NBKT_H)   // 275
#define NEB    586                 // ceil(1200000/2048)
#define KB3_NF 784                 // 196*4 flow sub-blocks (256 nodes each)
#define KB3_NH 316                 // 79*4 host sub-blocks (64 nodes each)

typedef unsigned short u16;
typedef unsigned int   u32;
typedef short bf16x8 __attribute__((ext_vector_type(8)));
typedef float f32x4  __attribute__((ext_vector_type(4)));
typedef float fx2    __attribute__((ext_vector_type(2)));

__device__ __forceinline__ float bfh(u16 h) { return __uint_as_float(((u32)h) << 16); }
__device__ __forceinline__ u16 fbh(float f) {
    u32 u = __float_as_uint(f);
    return (u16)((u + 0x7fffu + ((u >> 16) & 1u)) >> 16);   // RNE
}
__device__ __forceinline__ u32 packbf(float x, float y) {
    return (u32)fbh(x) | ((u32)fbh(y) << 16);
}
// packed bf16 unpack+accumulate (v_pk_add_f32)
__device__ __forceinline__ void accp(fx2* a, uint4 u) {
    fx2 p;
    p.x = __uint_as_float(u.x << 16); p.y = __uint_as_float(u.x & 0xffff0000u); a[0] += p;
    p.x = __uint_as_float(u.y << 16); p.y = __uint_as_float(u.y & 0xffff0000u); a[1] += p;
    p.x = __uint_as_float(u.z << 16); p.y = __uint_as_float(u.z & 0xffff0000u); a[2] += p;
    p.x = __uint_as_float(u.w << 16); p.y = __uint_as_float(u.w & 0xffff0000u); a[3] += p;
}
__device__ __forceinline__ uint4 packp(const fx2* a, float inv) {
    uint4 o;
    o.x = packbf(a[0].x * inv, a[0].y * inv);
    o.y = packbf(a[1].x * inv, a[1].y * inv);
    o.z = packbf(a[2].x * inv, a[2].y * inv);
    o.w = packbf(a[3].x * inv, a[3].y * inv);
    return o;
}

// gather-mean of 16B chunks; neighbor indices from LDS window (fit) or global fallback.
template <int U>
__device__ __forceinline__ uint4 gmean(const u16* __restrict__ pool, int rs, int coff,
                                       const int* __restrict__ gcsr,
                                       const int* __restrict__ lcsr, int st0, bool fit,
                                       int st, int en) {
    fx2 a[4] = {};
    for (int e = st; e < en; e += U) {
        int n[U];
#pragma unroll
        for (int j = 0; j < U; j++)
            n[j] = (e + j < en) ? (fit ? lcsr[e + j - st0] : gcsr[e + j]) : -1;
        uint4 u[U];
#pragma unroll
        for (int j = 0; j < U; j++)
            u[j] = (n[j] >= 0) ? *(const uint4*)(pool + n[j] * rs + coff)
                               : make_uint4(0u, 0u, 0u, 0u);
#pragma unroll
        for (int j = 0; j < U; j++) accp(a, u[j]);
    }
    float inv = (en > st) ? 1.f / (float)(en - st) : 0.f;
    return packp(a, inv);
}

// ---------------- k_pre: weights transpose | x->bf16 | bucket histogram ----------------
__global__ void k_pre(const float* __restrict__ W0_hf_l, const float* __restrict__ W0_hf_r,
                      const float* __restrict__ W0_fh_l, const float* __restrict__ W0_fh_r,
                      const float* __restrict__ W1_l, const float* __restrict__ W1_r,
                      const float* __restrict__ Wout,
                      u16* __restrict__ WT0_hf, u16* __restrict__ WT0_fh,
                      u16* __restrict__ WT1_l, u16* __restrict__ WT1_r,
                      u16* __restrict__ WTo,
                      const float* __restrict__ xf, const float* __restrict__ xh,
                      u16* __restrict__ xfb, u16* __restrict__ xhb,
                      const int* __restrict__ dst_hf, const int* __restrict__ dst_fh,
                      int* __restrict__ bcnt) {
    int b = blockIdx.x, t = threadIdx.x;
    if (b < 34) {
        u16 tmp[8];
        if (b < 32) {
            int e = (b & 7) * 2048 + t * 8;
            int n = e >> 7, k0 = e & 127;
            if (b < 8) {
#pragma unroll
                for (int j = 0; j < 8; j++) {
                    int k = k0 + j;
                    tmp[j] = fbh(k < 64 ? W0_hf_l[k * D_H + n] : W0_hf_r[(k - 64) * D_H + n]);
                }
                *(uint4*)(WT0_hf + n * 128 + k0) = *(uint4*)tmp;
            } else if (b < 16) {
#pragma unroll
                for (int j = 0; j < 8; j++) {
                    int k = k0 + j;
                    tmp[j] = fbh(k < 64 ? W0_fh_l[k * D_H + n] : W0_fh_r[(k - 64) * D_H + n]);
                }
                *(uint4*)(WT0_fh + n * 128 + k0) = *(uint4*)tmp;
            } else if (b < 24) {
#pragma unroll
                for (int j = 0; j < 8; j++) tmp[j] = fbh(W1_l[(k0 + j) * D_H + n]);
                *(uint4*)(WT1_l + n * 128 + k0) = *(uint4*)tmp;
            } else {
#pragma unroll
                for (int j = 0; j < 8; j++) tmp[j] = fbh(W1_r[(k0 + j) * D_H + n]);
                *(uint4*)(WT1_r + n * 128 + k0) = *(uint4*)tmp;
            }
        } else {
            int e = (b - 32) * 2048 + t * 8;
            int n = e >> 7, k0 = e & 127;
#pragma unroll
            for (int j = 0; j < 8; j++) tmp[j] = fbh(Wout[(k0 + j) * D_OUT + n]);
            *(uint4*)(WTo + n * 128 + k0) = *(uint4*)tmp;
        }
    } else if (b < 34 + 6875) {
        int q = (b - 34) * 256 + t;       // 8 floats per thread
        const int TF = (N_FLOW * D_IN) / 8;
        const int TT = TF + (N_HOST * D_IN) / 8;
        if (q >= TT) return;
        const float* src; u16* dst; int base;
        if (q < TF) { src = xf; dst = xfb; base = q * 8; }
        else        { src = xh; dst = xhb; base = (q - TF) * 8; }
        float4 f0 = *(const float4*)(src + base);
        float4 f1 = *(const float4*)(src + base + 4);
        uint4 o;
        o.x = packbf(f0.x, f0.y); o.y = packbf(f0.z, f0.w);
        o.z = packbf(f1.x, f1.y); o.w = packbf(f1.z, f1.w);
        *(uint4*)(dst + base) = o;
    } else {
        __shared__ int h[NBKT];
        for (int j = t; j < NBKT; j += 256) h[j] = 0;
        __syncthreads();
        int base = (b - 34 - 6875) * 2048;
#pragma unroll
        for (int i = 0; i < 8; i++) {
            int e = base + t + i * 256;
            if (e < 2 * NEDGE) {
                int bkt = (e < NEDGE) ? (dst_hf[e] >> 10)
                                      : (NBKT_F + (dst_fh[e - NEDGE] >> 8));
                atomicAdd(&h[bkt], 1);
            }
        }
        __syncthreads();
        for (int j = t; j < NBKT; j += 256)
            if (h[j]) atomicAdd(&bcnt[j], h[j]);
    }
}

// ---------------- kb2: bin scatter (in-block prefix of bcnt) ----------------
__global__ void kb2(const int* __restrict__ src_hf, const int* __restrict__ dst_hf,
                    const int* __restrict__ src_fh, const int* __restrict__ dst_fh,
                    const int* __restrict__ bcnt, int* __restrict__ bcur,
                    int2* __restrict__ binE) {
    __shared__ int sp[512];    // becomes exclusive bucket base
    __shared__ int lh[NBKT];
    __shared__ int lb[NBKT];
    int t = threadIdx.x;
    int o1 = (t < NBKT) ? bcnt[t] : 0;
    int o2 = (t + 256 < NBKT) ? bcnt[t + 256] : 0;
    sp[t] = o1; sp[t + 256] = o2;
    for (int j = t; j < NBKT; j += 256) lh[j] = 0;
    __syncthreads();
    for (int d = 1; d < 512; d <<= 1) {
        int a0 = (t >= d) ? sp[t - d] : 0;
        int a1 = sp[t + 256 - d];
        __syncthreads();
        sp[t] += a0; sp[t + 256] += a1;
        __syncthreads();
    }
    sp[t] -= o1; sp[t + 256] -= o2;   // exclusive
    __syncthreads();
    int base = blockIdx.x * 2048;
    int mybkt[8], myrank[8], mysrc[8], mydst[8];
#pragma unroll
    for (int i = 0; i < 8; i++) {
        int e = base + t + i * 256;
        mybkt[i] = -1;
        if (e < 2 * NEDGE) {
            int s, d;
            if (e < NEDGE) { s = src_hf[e]; d = dst_hf[e]; }
            else           { s = src_fh[e - NEDGE]; d = dst_fh[e - NEDGE] + N_FLOW; }
            int bkt = (d < N_FLOW) ? (d >> 10) : (NBKT_F + ((d - N_FLOW) >> 8));
            mybkt[i] = bkt; mysrc[i] = s; mydst[i] = d;
            myrank[i] = atomicAdd(&lh[bkt], 1);
        }
    }
    __syncthreads();
    for (int j = t; j < NBKT; j += 256)
        lb[j] = lh[j] ? atomicAdd(&bcur[j], lh[j]) : 0;
    __syncthreads();
#pragma unroll
    for (int i = 0; i < 8; i++) {
        if (mybkt[i] >= 0) {
            int pos = sp[mybkt[i]] + lb[mybkt[i]] + myrank[i];
            binE[pos] = make_int2(mysrc[i], mydst[i]);
        }
    }
}

// -------- kb3: per-SUB-bucket CSR build (4x split of every bucket, 1100 blocks) --------
// Sub-block scans its parent bucket's binE window, filters dst to its node sub-range;
// 'below' (# parent edges with dst < nbase) gives the csr base => layout identical to
// the old monolithic kb3.
__global__ __launch_bounds__(256) void kb3(const int2* __restrict__ binE,
                                           const int* __restrict__ bcnt,
                                           int* __restrict__ off, int* __restrict__ csr) {
    __shared__ int sp[512];
    __shared__ int deg[256];
    __shared__ int ts[256];
    __shared__ int below;
    int b = blockIdx.x, t = threadIdx.x;
    sp[t] = (t < NBKT) ? bcnt[t] : 0;
    sp[t + 256] = (t + 256 < NBKT) ? bcnt[t + 256] : 0;
    __syncthreads();
    for (int d = 1; d < 512; d <<= 1) {
        int a0 = (t >= d) ? sp[t - d] : 0;
        int a1 = sp[t + 256 - d];
        __syncthreads();
        sp[t] += a0; sp[t + 256] += a1;
        __syncthreads();
    }
    int pbg, nbase, span, ncnt;
    if (b < KB3_NF) {
        pbg = b >> 2;                                  // flow bucket 0..195
        nbase = (pbg << 10) + ((b & 3) << 8);          // 256-node sub-range
        span = 256;
        ncnt = min(256, N_FLOW - nbase);               // may be <=0 (tail subs)
    } else {
        int hb = b - KB3_NF;
        pbg = NBKT_F + (hb >> 2);                      // host bucket
        nbase = N_FLOW + ((hb >> 2) << 8) + ((hb & 3) << 6);  // 64-node sub-range
        span = 64;
        ncnt = min(64, NSEG - nbase);
    }
    int e0p = (pbg == 0) ? 0 : sp[pbg - 1];
    int e1p = sp[pbg];
    deg[t] = 0;
    if (t == 0) below = 0;
    __syncthreads();
    for (int e = e0p + t; e < e1p; e += 256) {
        int2 p = binE[e];
        int d = p.y - nbase;
        if (d < 0) atomicAdd(&below, 1);
        else if (d < span) atomicAdd(&deg[d], 1);
    }
    __syncthreads();
    int myd = (t < span) ? deg[t] : 0;
    ts[t] = myd;
    __syncthreads();
    for (int d = 1; d < 256; d <<= 1) {
        int x = (t >= d) ? ts[t - d] : 0;
        __syncthreads();
        ts[t] += x;
        __syncthreads();
    }
    int base = e0p + below;
    __syncthreads();               // deg reads done before reuse as cur
    if (t < span) {
        int stt = base + ts[t] - myd;
        deg[t] = stt;                                  // cur = segment start
        if (t < ncnt) off[nbase + t] = stt + myd;      // segment END
    }
    __syncthreads();
    for (int e = e0p + t; e < e1p; e += 256) {
        int2 p = binE[e];
        int d = p.y - nbase;
        if (d >= 0 && d < span) {
            int r = atomicAdd(&deg[d], 1);
            csr[r] = p.x;
        }
    }
}

// ---------------- k_host: G2+G3 fused (M=20000), 512 thr, col-split waves ----------------
__global__ __launch_bounds__(512, 4) void k_host(
    const u16* __restrict__ xfb, const u16* __restrict__ xhb,
    const int* __restrict__ off, const int* __restrict__ csr,
    const u16* __restrict__ WT0, const float* __restrict__ b0,
    const u16* __restrict__ WT1l, u16* __restrict__ hT, int M) {
    __shared__ __align__(16) u16 sA[64 * 136];
    __shared__ int sOff[72];
    __shared__ int sCsr[2560];
    const int t = threadIdx.x;
    const int m0 = blockIdx.x * 64;
    if (t < 65) {
        int idx = N_FLOW + m0 - 1 + t;
        sOff[t] = off[min(idx, NSEG - 1)];
    }
    // direct half: xhb row, k in [64,128)  — 512 chunks, 1/thread
    {
        int r = t >> 3, c = t & 7;
        int row = m0 + r;
        uint4 v = make_uint4(0u, 0u, 0u, 0u);
        if (row < M) v = *(const uint4*)(xhb + row * 64 + c * 8);
        *(uint4*)(&sA[r * 136 + 64 + c * 8]) = v;
    }
    __syncthreads();
    int st0 = sOff[0];
    int win = sOff[64] - st0;
    bool fit = (win <= 2560);
    if (fit) for (int e = t; e < win; e += 512) sCsr[e] = csr[st0 + e];
    __syncthreads();
    // gather half: mean(xfb nbrs), k in [0,64) — deg~30, batch 8 loads/round
    {
        int r = t >> 3, c = t & 7;
        int row = m0 + r;
        uint4 o = make_uint4(0u, 0u, 0u, 0u);
        if (row < M) o = gmean<8>(xfb, 64, c * 8, csr, sCsr, st0, fit, sOff[r], sOff[r + 1]);
        *(uint4*)(&sA[r * 136 + c * 8]) = o;
    }
    __syncthreads();
    const int w = t >> 6, wr = w >> 1, wc = w & 1;
    const int ln = t & 63, l15 = ln & 15, quad = ln >> 4;
    const u16* pA = sA + (wr * 16 + l15) * 136 + quad * 8;
    const u16* pB0 = WT0 + wc * 8192 + l15 * 128 + quad * 8;
    f32x4 acc[4];
#pragma unroll
    for (int tt = 0; tt < 4; tt++) acc[tt] = (f32x4){0.f, 0.f, 0.f, 0.f};
#pragma unroll
    for (int s = 0; s < 4; s++) {
        bf16x8 a = *(const bf16x8*)(pA + s * 32);
#pragma unroll
        for (int tt = 0; tt < 4; tt++) {
            bf16x8 b = *(const bf16x8*)(pB0 + tt * 2048 + s * 32);
            acc[tt] = __builtin_amdgcn_mfma_f32_16x16x32_bf16(a, b, acc[tt], 0, 0, 0);
        }
    }
    __syncthreads();   // all phase-A reads of sA done before h overwrites it
#pragma unroll
    for (int tt = 0; tt < 4; tt++) {
        int col = wc * 64 + tt * 16 + l15;
        float bv = b0[col];
#pragma unroll
        for (int i = 0; i < 4; i++) {
            int rl = wr * 16 + quad * 4 + i;
            float v = acc[tt][i] + bv;
            v = v > 0.f ? v : 0.01f * v;
            sA[rl * 136 + col] = fbh(v);
        }
    }
    __syncthreads();   // h complete (both col-half waves) before phase B reads
    const u16* pB1 = WT1l + wc * 8192 + l15 * 128 + quad * 8;
    f32x4 accB[4];
#pragma unroll
    for (int tt = 0; tt < 4; tt++) accB[tt] = (f32x4){0.f, 0.f, 0.f, 0.f};
#pragma unroll
    for (int s = 0; s < 4; s++) {
        bf16x8 a = *(const bf16x8*)(pA + s * 32);
#pragma unroll
        for (int tt = 0; tt < 4; tt++) {
            bf16x8 b = *(const bf16x8*)(pB1 + tt * 2048 + s * 32);
            accB[tt] = __builtin_amdgcn_mfma_f32_16x16x32_bf16(a, b, accB[tt], 0, 0, 0);
        }
    }
#pragma unroll
    for (int tt = 0; tt < 4; tt++) {
        int col = wc * 64 + tt * 16 + l15;
#pragma unroll
        for (int i = 0; i < 4; i++) {
            int row = m0 + wr * 16 + quad * 4 + i;
            if (row < M) hT[row * D_H + col] = fbh(accB[tt][i]);
        }
    }
}

// ---------- k_mega: G1+G4 fused, 512 thr — launched in 2 offset slices ----------
__global__ __launch_bounds__(512, 8) void k_mega(
    const u16* __restrict__ xfb, const u16* __restrict__ xhb,
    const int* __restrict__ off, const int* __restrict__ csr,
    const u16* __restrict__ hT,
    const u16* __restrict__ WT0, const float* __restrict__ b0,
    const u16* __restrict__ WT1r, const float* __restrict__ b1,
    const u16* __restrict__ WTo, const float* __restrict__ bout,
    float* __restrict__ OUT, int moff) {
    __shared__ __align__(16) u16 sA[64 * 136];    // A0 tile -> h band
    __shared__ __align__(16) u16 sAg[64 * 136];   // gathered mean(hT) tile -> g band
    __shared__ int sOff[72];
    __shared__ int sCsr[1024];
    const int t = threadIdx.x;
    const int m0 = (blockIdx.x + moff) * 64;
    if (t < 65) {
        int idx = m0 - 1 + t;
        sOff[t] = (idx < 0) ? 0 : off[idx];
    }
    // direct half: xfb row, k in [64,128) — 512 chunks, 1/thread
    {
        int r = t >> 3, c = t & 7;
        uint4 v = *(const uint4*)(xfb + (m0 + r) * 64 + c * 8);
        *(uint4*)(&sA[r * 136 + 64 + c * 8]) = v;
    }
    __syncthreads();
    int st0 = sOff[0];
    int win = sOff[64] - st0;
    bool fit = (win <= 1024);
    if (fit) for (int e = t; e < win; e += 512) sCsr[e] = csr[st0 + e];
    __syncthreads();
    // A0 gather half: mean(xhb nbrs), k in [0,64) — 512 tasks
    {
        int r = t >> 3, c = t & 7;
        uint4 o = gmean<4>(xhb, 64, c * 8, csr, sCsr, st0, fit, sOff[r], sOff[r + 1]);
        *(uint4*)(&sA[r * 136 + c * 8]) = o;
    }
    // agg tile: mean(hT nbrs), 128d — 1024 tasks, 2/thread
#pragma unroll
    for (int i = 0; i < 2; i++) {
        int q = t + i * 512;
        int r = q >> 4, c = q & 15;
        uint4 o = gmean<4>(hT, 128, c * 8, csr, sCsr, st0, fit, sOff[r], sOff[r + 1]);
        *(uint4*)(&sAg[r * 136 + c * 8]) = o;
    }
    __syncthreads();
    const int w = t >> 6, wr = w >> 1, wc = w & 1;   // wave = (row-band, col-half)
    const int ln = t & 63, l15 = ln & 15, quad = ln >> 4;
    const u16* pA = sA + (wr * 16 + l15) * 136 + quad * 8;
    const u16* pB0 = WT0 + wc * 8192 + l15 * 128 + quad * 8;
    f32x4 acc[4];
#pragma unroll
    for (int tt = 0; tt < 4; tt++) acc[tt] = (f32x4){0.f, 0.f, 0.f, 0.f};
#pragma unroll
    for (int s = 0; s < 4; s++) {
        bf16x8 av = *(const bf16x8*)(pA + s * 32);
#pragma unroll
        for (int tt = 0; tt < 4; tt++) {
            bf16x8 b = *(const bf16x8*)(pB0 + tt * 2048 + s * 32);
            acc[tt] = __builtin_amdgcn_mfma_f32_16x16x32_bf16(av, b, acc[tt], 0, 0, 0);
        }
    }
    __syncthreads();   // all phase-A reads of sA done before h overwrites it
    // epilogue1: h = lrelu(acc + b0) -> sA band (cols wc*64 ..)
#pragma unroll
    for (int tt = 0; tt < 4; tt++) {
        int col = wc * 64 + tt * 16 + l15;
        float bv = b0[col];
#pragma unroll
        for (int i = 0; i < 4; i++) {
            int rl = wr * 16 + quad * 4 + i;
            float v = acc[tt][i] + bv;
            v = v > 0.f ? v : 0.01f * v;
            sA[rl * 136 + col] = fbh(v);
        }
    }
    __syncthreads();   // h complete before phase B reads full rows
    // phase B: h @ WT1r^T
    const u16* pB1 = WT1r + wc * 8192 + l15 * 128 + quad * 8;
    f32x4 accB[4];
#pragma unroll
    for (int tt = 0; tt < 4; tt++) accB[tt] = (f32x4){0.f, 0.f, 0.f, 0.f};
#pragma unroll
    for (int s = 0; s < 4; s++) {
        bf16x8 av = *(const bf16x8*)(pA + s * 32);
#pragma unroll
        for (int tt = 0; tt < 4; tt++) {
            bf16x8 b = *(const bf16x8*)(pB1 + tt * 2048 + s * 32);
            accB[tt] = __builtin_amdgcn_mfma_f32_16x16x32_bf16(av, b, accB[tt], 0, 0, 0);
        }
    }
    // epilogue2: g = lrelu(accB + agg + b1) -> in-place over sAg
#pragma unroll
    for (int tt = 0; tt < 4; tt++) {
        int col = wc * 64 + tt * 16 + l15;
        float bv = b1[col];
#pragma unroll
        for (int i = 0; i < 4; i++) {
            int rl = wr * 16 + quad * 4 + i;
            float v = accB[tt][i] + bfh(sAg[rl * 136 + col]) + bv;
            v = v > 0.f ? v : 0.01f * v;
            sAg[rl * 136 + col] = fbh(v);
        }
    }
    __syncthreads();   // g complete before phase C reads full rows
    // phase C: out = g @ WTo^T + bout  (each wave: 16-row band x 16-col tile wc)
    const u16* pG = sAg + (wr * 16 + l15) * 136 + quad * 8;
    const u16* pBo = WTo + wc * 2048 + l15 * 128 + quad * 8;
    f32x4 acc2 = (f32x4){0.f, 0.f, 0.f, 0.f};
#pragma unroll
    for (int s = 0; s < 4; s++) {
        bf16x8 g = *(const bf16x8*)(pG + s * 32);
        bf16x8 b = *(const bf16x8*)(pBo + s * 32);
        acc2 = __builtin_amdgcn_mfma_f32_16x16x32_bf16(g, b, acc2, 0, 0, 0);
    }
    {
        int col = wc * 16 + l15;
        float bv = bout[col];
#pragma unroll
        for (int i = 0; i < 4; i++) {
            int row = m0 + wr * 16 + quad * 4 + i;
            OUT[row * D_OUT + col] = acc2[i] + bv;
        }
    }
}

extern "C" void kernel_launch(void* const* d_in, const int* in_sizes, int n_in,
                              void* d_out, int out_size, void* d_ws, size_t ws_size,
                              hipStream_t stream) {
    const float* x_host  = (const float*)d_in[0];
    const float* x_flow  = (const float*)d_in[1];
    const int* src_hf  = (const int*)d_in[2];
    const int* dst_hf  = (const int*)d_in[3];
    const int* src_fh  = (const int*)d_in[4];
    const int* dst_fh  = (const int*)d_in[5];
    const float* W0_hf_l = (const float*)d_in[6];
    const float* W0_hf_r = (const float*)d_in[7];
    const float* b0_hf   = (const float*)d_in[8];
    const float* W0_fh_l = (const float*)d_in[9];
    const float* W0_fh_r = (const float*)d_in[10];
    const float* b0_fh   = (const float*)d_in[11];
    const float* W1_hf_l = (const float*)d_in[12];
    const float* W1_hf_r = (const float*)d_in[13];
    const float* b1_hf   = (const float*)d_in[14];
    const float* W_out   = (const float*)d_in[18];
    const float* b_out   = (const float*)d_in[19];
    float* out = (float*)d_out;

    // workspace layout (bytes), all disjoint, total ~48.7 MB
    char* ws = (char*)d_ws;
    int*  off    = (int*)(ws + 0);             //   880,000
    int*  csr    = (int*)(ws + 880000);        // 4,800,000
    u16*  hT     = (u16*)(ws + 5680000);       //  5,120,000
    u16*  xfb    = (u16*)(ws + 10800000);      // 25,600,000
    u16*  xhb    = (u16*)(ws + 36400000);      //  2,560,000
    int2* binE   = (int2*)(ws + 38960000);     //  9,600,000
    int*  bcnt   = (int*)(ws + 48560000);      //  1,280
    int*  bcur   = (int*)(ws + 48561280);      //  1,280
    u16*  WT0_hf = (u16*)(ws + 48562560);      //  32,768
    u16*  WT0_fh = (u16*)(ws + 48595328);      //  32,768
    u16*  WT1_l  = (u16*)(ws + 48628096);      //  32,768
    u16*  WT1_r  = (u16*)(ws + 48660864);      //  32,768
    u16*  WTo    = (u16*)(ws + 48693632);      //   8,192

    hipMemsetAsync(bcnt, 0, 2560, stream);     // bcnt + bcur
    k_pre<<<34 + 6875 + NEB, 256, 0, stream>>>(
        W0_hf_l, W0_hf_r, W0_fh_l, W0_fh_r, W1_hf_l, W1_hf_r, W_out,
        WT0_hf, WT0_fh, WT1_l, WT1_r, WTo,
        x_flow, x_host, xfb, xhb, dst_hf, dst_fh, bcnt);
    kb2<<<NEB, 256, 0, stream>>>(src_hf, dst_hf, src_fh, dst_fh, bcnt, bcur, binE);
    kb3<<<KB3_NF + KB3_NH, 256, 0, stream>>>(binE, bcnt, off, csr);
    k_host<<<313, 512, 0, stream>>>(xfb, xhb, off, csr, WT0_fh, b0_fh, WT1_l, hT, N_HOST);
    // 2 slices: both >1024 blocks (machine stays full); top-5 = 2 mega halves + 3
    // largest prep kernels with counters.
    k_mega<<<1563, 512, 0, stream>>>(xfb, xhb, off, csr, hT, WT0_hf, b0_hf,
                                     WT1_r, b1_hf, WTo, b_out, out, 0);
    k_mega<<<1562, 512, 0, stream>>>(xfb, xhb, off, csr, hT, WT0_hf, b0_hf,
                                     WT1_r, b1_hf, WTo, b_out, out, 1563);
}

// Round 9
// 352.624 us; speedup vs baseline: 1.2271x; 1.0477x over previous
//
#include <hip/hip_runtime.h>

// HeteroGNN on MI355X. Inputs/weights/output fp32 (per reference); intermediates bf16.
// Round 17 = Round 16 resubmit (bench infra "container failed twice" — same as R3,
// where identical resubmit then passed; source re-audited: merged-gather body is
// functionally identical to R10's HW-passing version, only launch_bounds differs).
// Merged-gather k_mega:
//  - k_mega's 3 serial gmean calls (xhb, hT-lo, hT-hi) expose gather latency 3x/wave.
//    Merge into ONE loop over the shared neighbor list: 12 loads in flight, 1 exposure.
//  - R10 proved structure correct but spilled under launch_bounds(512,8)=64-VGPR cap
//    (WRITE 25->102MB). Now (512,4)=128 cap: room for ~100 VGPR of accumulators+loads.
//    Occupancy ~50% — acceptable: R8->R9 measured occ 39->81% bought only 8us.
//  - WRITE_SIZE == 25MB is the spill sentinel.
//   k_pre  : weights->bf16 WT[n][k] | x->bf16 pools | bucket histogram
//   kb2    : bin scatter (in-block 275-prefix)  kb3: per-bucket CSR build
//   k_host : h=lrelu([mean(xfb nbrs)|xhb]@WT0_fh^T+b0); hT=h@WT1_l^T        (M=20000)
//   k_mega : h=lrelu([mean(xhb nbrs)|xfb]@WT0_hf^T+b0);
//            g=lrelu(h@WT1_r^T+mean(hT nbrs)+b1); out=g@WTo^T+bout          (M=200000)
// g_host dead in reference -> W1_fh_* unused.

#define N_HOST 20000
#define N_FLOW 200000
#define NEDGE  600000
#define D_IN   64
#define D_H    128
#define D_OUT  32
#define NSEG   (N_FLOW + N_HOST)
#define NBKT_F 196
#define NBKT_H 79
#define NBKT   (NBKT_F + NBKT_H)   // 275
#define NEB    586                 // ceil(1200000/2048)

typedef unsigned short u16;
typedef unsigned int   u32;
typedef short bf16x8 __attribute__((ext_vector_type(8)));
typedef float f32x4  __attribute__((ext_vector_type(4)));
typedef float fx2    __attribute__((ext_vector_type(2)));

__device__ __forceinline__ float bfh(u16 h) { return __uint_as_float(((u32)h) << 16); }
__device__ __forceinline__ u16 fbh(float f) {
    u32 u = __float_as_uint(f);
    return (u16)((u + 0x7fffu + ((u >> 16) & 1u)) >> 16);   // RNE
}
__device__ __forceinline__ u32 packbf(float x, float y) {
    return (u32)fbh(x) | ((u32)fbh(y) << 16);
}
// packed bf16 unpack+accumulate (v_pk_add_f32)
__device__ __forceinline__ void accp(fx2* a, uint4 u) {
    fx2 p;
    p.x = __uint_as_float(u.x << 16); p.y = __uint_as_float(u.x & 0xffff0000u); a[0] += p;
    p.x = __uint_as_float(u.y << 16); p.y = __uint_as_float(u.y & 0xffff0000u); a[1] += p;
    p.x = __uint_as_float(u.z << 16); p.y = __uint_as_float(u.z & 0xffff0000u); a[2] += p;
    p.x = __uint_as_float(u.w << 16); p.y = __uint_as_float(u.w & 0xffff0000u); a[3] += p;
}
__device__ __forceinline__ uint4 packp(const fx2* a, float inv) {
    uint4 o;
    o.x = packbf(a[0].x * inv, a[0].y * inv);
    o.y = packbf(a[1].x * inv, a[1].y * inv);
    o.z = packbf(a[2].x * inv, a[2].y * inv);
    o.w = packbf(a[3].x * inv, a[3].y * inv);
    return o;
}

// gather-mean of 16B chunks; neighbor indices from LDS window (fit) or global fallback.
template <int U>
__device__ __forceinline__ uint4 gmean(const u16* __restrict__ pool, int rs, int coff,
                                       const int* __restrict__ gcsr,
                                       const int* __restrict__ lcsr, int st0, bool fit,
                                       int st, int en) {
    fx2 a[4] = {};
    for (int e = st; e < en; e += U) {
        int n[U];
#pragma unroll
        for (int j = 0; j < U; j++)
            n[j] = (e + j < en) ? (fit ? lcsr[e + j - st0] : gcsr[e + j]) : -1;
        uint4 u[U];
#pragma unroll
        for (int j = 0; j < U; j++)
            u[j] = (n[j] >= 0) ? *(const uint4*)(pool + n[j] * rs + coff)
                               : make_uint4(0u, 0u, 0u, 0u);
#pragma unroll
        for (int j = 0; j < U; j++) accp(a, u[j]);
    }
    float inv = (en > st) ? 1.f / (float)(en - st) : 0.f;
    return packp(a, inv);
}

// ---------------- k_pre: weights transpose | x->bf16 | bucket histogram ----------------
__global__ void k_pre(const float* __restrict__ W0_hf_l, const float* __restrict__ W0_hf_r,
                      const float* __restrict__ W0_fh_l, const float* __restrict__ W0_fh_r,
                      const float* __restrict__ W1_l, const float* __restrict__ W1_r,
                      const float* __restrict__ Wout,
                      u16* __restrict__ WT0_hf, u16* __restrict__ WT0_fh,
                      u16* __restrict__ WT1_l, u16* __restrict__ WT1_r,
                      u16* __restrict__ WTo,
                      const float* __restrict__ xf, const float* __restrict__ xh,
                      u16* __restrict__ xfb, u16* __restrict__ xhb,
                      const int* __restrict__ dst_hf, const int* __restrict__ dst_fh,
                      int* __restrict__ bcnt) {
    int b = blockIdx.x, t = threadIdx.x;
    if (b < 34) {
        u16 tmp[8];
        if (b < 32) {
            int e = (b & 7) * 2048 + t * 8;
            int n = e >> 7, k0 = e & 127;
            if (b < 8) {
#pragma unroll
                for (int j = 0; j < 8; j++) {
                    int k = k0 + j;
                    tmp[j] = fbh(k < 64 ? W0_hf_l[k * D_H + n] : W0_hf_r[(k - 64) * D_H + n]);
                }
                *(uint4*)(WT0_hf + n * 128 + k0) = *(uint4*)tmp;
            } else if (b < 16) {
#pragma unroll
                for (int j = 0; j < 8; j++) {
                    int k = k0 + j;
                    tmp[j] = fbh(k < 64 ? W0_fh_l[k * D_H + n] : W0_fh_r[(k - 64) * D_H + n]);
                }
                *(uint4*)(WT0_fh + n * 128 + k0) = *(uint4*)tmp;
            } else if (b < 24) {
#pragma unroll
                for (int j = 0; j < 8; j++) tmp[j] = fbh(W1_l[(k0 + j) * D_H + n]);
                *(uint4*)(WT1_l + n * 128 + k0) = *(uint4*)tmp;
            } else {
#pragma unroll
                for (int j = 0; j < 8; j++) tmp[j] = fbh(W1_r[(k0 + j) * D_H + n]);
                *(uint4*)(WT1_r + n * 128 + k0) = *(uint4*)tmp;
            }
        } else {
            int e = (b - 32) * 2048 + t * 8;
            int n = e >> 7, k0 = e & 127;
#pragma unroll
            for (int j = 0; j < 8; j++) tmp[j] = fbh(Wout[(k0 + j) * D_OUT + n]);
            *(uint4*)(WTo + n * 128 + k0) = *(uint4*)tmp;
        }
    } else if (b < 34 + 6875) {
        int q = (b - 34) * 256 + t;       // 8 floats per thread
        const int TF = (N_FLOW * D_IN) / 8;
        const int TT = TF + (N_HOST * D_IN) / 8;
        if (q >= TT) return;
        const float* src; u16* dst; int base;
        if (q < TF) { src = xf; dst = xfb; base = q * 8; }
        else        { src = xh; dst = xhb; base = (q - TF) * 8; }
        float4 f0 = *(const float4*)(src + base);
        float4 f1 = *(const float4*)(src + base + 4);
        uint4 o;
        o.x = packbf(f0.x, f0.y); o.y = packbf(f0.z, f0.w);
        o.z = packbf(f1.x, f1.y); o.w = packbf(f1.z, f1.w);
        *(uint4*)(dst + base) = o;
    } else {
        __shared__ int h[NBKT];
        for (int j = t; j < NBKT; j += 256) h[j] = 0;
        __syncthreads();
        int base = (b - 34 - 6875) * 2048;
#pragma unroll
        for (int i = 0; i < 8; i++) {
            int e = base + t + i * 256;
            if (e < 2 * NEDGE) {
                int bkt = (e < NEDGE) ? (dst_hf[e] >> 10)
                                      : (NBKT_F + (dst_fh[e - NEDGE] >> 8));
                atomicAdd(&h[bkt], 1);
            }
        }
        __syncthreads();
        for (int j = t; j < NBKT; j += 256)
            if (h[j]) atomicAdd(&bcnt[j], h[j]);
    }
}

// ---------------- kb2: bin scatter (in-block prefix of bcnt) ----------------
__global__ void kb2(const int* __restrict__ src_hf, const int* __restrict__ dst_hf,
                    const int* __restrict__ src_fh, const int* __restrict__ dst_fh,
                    const int* __restrict__ bcnt, int* __restrict__ bcur,
                    int2* __restrict__ binE) {
    __shared__ int sp[512];    // becomes exclusive bucket base
    __shared__ int lh[NBKT];
    __shared__ int lb[NBKT];
    int t = threadIdx.x;
    int o1 = (t < NBKT) ? bcnt[t] : 0;
    int o2 = (t + 256 < NBKT) ? bcnt[t + 256] : 0;
    sp[t] = o1; sp[t + 256] = o2;
    for (int j = t; j < NBKT; j += 256) lh[j] = 0;
    __syncthreads();
    for (int d = 1; d < 512; d <<= 1) {
        int a0 = (t >= d) ? sp[t - d] : 0;
        int a1 = sp[t + 256 - d];
        __syncthreads();
        sp[t] += a0; sp[t + 256] += a1;
        __syncthreads();
    }
    sp[t] -= o1; sp[t + 256] -= o2;   // exclusive
    __syncthreads();
    int base = blockIdx.x * 2048;
    int mybkt[8], myrank[8], mysrc[8], mydst[8];
#pragma unroll
    for (int i = 0; i < 8; i++) {
        int e = base + t + i * 256;
        mybkt[i] = -1;
        if (e < 2 * NEDGE) {
            int s, d;
            if (e < NEDGE) { s = src_hf[e]; d = dst_hf[e]; }
            else           { s = src_fh[e - NEDGE]; d = dst_fh[e - NEDGE] + N_FLOW; }
            int bkt = (d < N_FLOW) ? (d >> 10) : (NBKT_F + ((d - N_FLOW) >> 8));
            mybkt[i] = bkt; mysrc[i] = s; mydst[i] = d;
            myrank[i] = atomicAdd(&lh[bkt], 1);
        }
    }
    __syncthreads();
    for (int j = t; j < NBKT; j += 256)
        lb[j] = lh[j] ? atomicAdd(&bcur[j], lh[j]) : 0;
    __syncthreads();
#pragma unroll
    for (int i = 0; i < 8; i++) {
        if (mybkt[i] >= 0) {
            int pos = sp[mybkt[i]] + lb[mybkt[i]] + myrank[i];
            binE[pos] = make_int2(mysrc[i], mydst[i]);
        }
    }
}

// ---------------- kb3: per-bucket CSR (in-block prefix of bcnt) ----------------
__global__ __launch_bounds__(256) void kb3(const int2* __restrict__ binE,
                                           const int* __restrict__ bcnt,
                                           int* __restrict__ off, int* __restrict__ csr) {
    __shared__ int sp[512];
    __shared__ int deg[1024];
    __shared__ int ts[256];
    int b = blockIdx.x, t = threadIdx.x;
    sp[t] = (t < NBKT) ? bcnt[t] : 0;
    sp[t + 256] = (t + 256 < NBKT) ? bcnt[t + 256] : 0;
    __syncthreads();
    for (int d = 1; d < 512; d <<= 1) {
        int a0 = (t >= d) ? sp[t - d] : 0;
        int a1 = sp[t + 256 - d];
        __syncthreads();
        sp[t] += a0; sp[t + 256] += a1;
        __syncthreads();
    }
    int e0 = (b == 0) ? 0 : sp[b - 1];
    int e1 = sp[b];
    int nbase, ncnt;
    if (b < NBKT_F) { nbase = b << 10; ncnt = min(1024, N_FLOW - nbase); }
    else { nbase = N_FLOW + ((b - NBKT_F) << 8); ncnt = min(256, NSEG - nbase); }
    for (int i = t; i < 1024; i += 256) deg[i] = 0;
    __syncthreads();
    for (int e = e0 + t; e < e1; e += 256) {
        int2 p = binE[e];
        atomicAdd(&deg[p.y - nbase], 1);
    }
    __syncthreads();
    int loc[4]; int s = 0;
#pragma unroll
    for (int j = 0; j < 4; j++) { loc[j] = s; s += deg[t * 4 + j]; }
    ts[t] = s;
    __syncthreads();
    for (int d = 1; d < 256; d <<= 1) {
        int x = (t >= d) ? ts[t - d] : 0;
        __syncthreads();
        ts[t] += x;
        __syncthreads();
    }
    int base2 = e0 + ts[t] - s;
    int dsave[4];
#pragma unroll
    for (int j = 0; j < 4; j++) dsave[j] = deg[t * 4 + j];
    __syncthreads();
#pragma unroll
    for (int j = 0; j < 4; j++) {
        int idx = t * 4 + j;
        int st = base2 + loc[j];
        deg[idx] = st;
        if (idx < ncnt) off[nbase + idx] = st + dsave[j];   // segment END
    }
    __syncthreads();
    for (int e = e0 + t; e < e1; e += 256) {
        int2 p = binE[e];
        int r = atomicAdd(&deg[p.y - nbase], 1);
        csr[r] = p.x;
    }
}

// ---------------- k_host: G2+G3 fused (M=20000), 512 thr, col-split waves ----------------
__global__ __launch_bounds__(512, 4) void k_host(
    const u16* __restrict__ xfb, const u16* __restrict__ xhb,
    const int* __restrict__ off, const int* __restrict__ csr,
    const u16* __restrict__ WT0, const float* __restrict__ b0,
    const u16* __restrict__ WT1l, u16* __restrict__ hT, int M) {
    __shared__ __align__(16) u16 sA[64 * 136];
    __shared__ int sOff[72];
    __shared__ int sCsr[2560];
    const int t = threadIdx.x;
    const int m0 = blockIdx.x * 64;
    if (t < 65) {
        int idx = N_FLOW + m0 - 1 + t;
        sOff[t] = off[min(idx, NSEG - 1)];
    }
    // direct half: xhb row, k in [64,128)  — 512 chunks, 1/thread
    {
        int r = t >> 3, c = t & 7;
        int row = m0 + r;
        uint4 v = make_uint4(0u, 0u, 0u, 0u);
        if (row < M) v = *(const uint4*)(xhb + row * 64 + c * 8);
        *(uint4*)(&sA[r * 136 + 64 + c * 8]) = v;
    }
    __syncthreads();
    int st0 = sOff[0];
    int win = sOff[64] - st0;
    bool fit = (win <= 2560);
    if (fit) for (int e = t; e < win; e += 512) sCsr[e] = csr[st0 + e];
    __syncthreads();
    // gather half: mean(xfb nbrs), k in [0,64) — deg~30, batch 8 loads/round
    {
        int r = t >> 3, c = t & 7;
        int row = m0 + r;
        uint4 o = make_uint4(0u, 0u, 0u, 0u);
        if (row < M) o = gmean<8>(xfb, 64, c * 8, csr, sCsr, st0, fit, sOff[r], sOff[r + 1]);
        *(uint4*)(&sA[r * 136 + c * 8]) = o;
    }
    __syncthreads();
    const int w = t >> 6, wr = w >> 1, wc = w & 1;
    const int ln = t & 63, l15 = ln & 15, quad = ln >> 4;
    const u16* pA = sA + (wr * 16 + l15) * 136 + quad * 8;
    const u16* pB0 = WT0 + wc * 8192 + l15 * 128 + quad * 8;
    f32x4 acc[4];
#pragma unroll
    for (int tt = 0; tt < 4; tt++) acc[tt] = (f32x4){0.f, 0.f, 0.f, 0.f};
#pragma unroll
    for (int s = 0; s < 4; s++) {
        bf16x8 a = *(const bf16x8*)(pA + s * 32);
#pragma unroll
        for (int tt = 0; tt < 4; tt++) {
            bf16x8 b = *(const bf16x8*)(pB0 + tt * 2048 + s * 32);
            acc[tt] = __builtin_amdgcn_mfma_f32_16x16x32_bf16(a, b, acc[tt], 0, 0, 0);
        }
    }
    __syncthreads();   // all phase-A reads of sA done before h overwrites it
#pragma unroll
    for (int tt = 0; tt < 4; tt++) {
        int col = wc * 64 + tt * 16 + l15;
        float bv = b0[col];
#pragma unroll
        for (int i = 0; i < 4; i++) {
            int rl = wr * 16 + quad * 4 + i;
            float v = acc[tt][i] + bv;
            v = v > 0.f ? v : 0.01f * v;
            sA[rl * 136 + col] = fbh(v);
        }
    }
    __syncthreads();   // h complete (both col-half waves) before phase B reads
    const u16* pB1 = WT1l + wc * 8192 + l15 * 128 + quad * 8;
    f32x4 accB[4];
#pragma unroll
    for (int tt = 0; tt < 4; tt++) accB[tt] = (f32x4){0.f, 0.f, 0.f, 0.f};
#pragma unroll
    for (int s = 0; s < 4; s++) {
        bf16x8 a = *(const bf16x8*)(pA + s * 32);
#pragma unroll
        for (int tt = 0; tt < 4; tt++) {
            bf16x8 b = *(const bf16x8*)(pB1 + tt * 2048 + s * 32);
            accB[tt] = __builtin_amdgcn_mfma_f32_16x16x32_bf16(a, b, accB[tt], 0, 0, 0);
        }
    }
#pragma unroll
    for (int tt = 0; tt < 4; tt++) {
        int col = wc * 64 + tt * 16 + l15;
#pragma unroll
        for (int i = 0; i < 4; i++) {
            int row = m0 + wr * 16 + quad * 4 + i;
            if (row < M) hT[row * D_H + col] = fbh(accB[tt][i]);
        }
    }
}

// ------- k_mega: G1+G4 fused (M=200000), merged gather, 128-VGPR budget -------
__global__ __launch_bounds__(512, 4) void k_mega(
    const u16* __restrict__ xfb, const u16* __restrict__ xhb,
    const int* __restrict__ off, const int* __restrict__ csr,
    const u16* __restrict__ hT,
    const u16* __restrict__ WT0, const float* __restrict__ b0,
    const u16* __restrict__ WT1r, const float* __restrict__ b1,
    const u16* __restrict__ WTo, const float* __restrict__ bout,
    float* __restrict__ OUT) {
    __shared__ __align__(16) u16 sA[64 * 136];    // A0 tile -> h band
    __shared__ __align__(16) u16 sAg[64 * 136];   // gathered mean(hT) tile -> g band
    __shared__ int sOff[72];
    __shared__ int sCsr[1024];
    const int t = threadIdx.x;
    const int m0 = blockIdx.x * 64;
    if (t < 65) {
        int idx = m0 - 1 + t;
        sOff[t] = (idx < 0) ? 0 : off[idx];
    }
    // direct half: xfb row, k in [64,128) — 512 chunks, 1/thread
    {
        int r = t >> 3, c = t & 7;
        uint4 v = *(const uint4*)(xfb + (m0 + r) * 64 + c * 8);
        *(uint4*)(&sA[r * 136 + 64 + c * 8]) = v;
    }
    __syncthreads();
    int st0 = sOff[0];
    int win = sOff[64] - st0;
    bool fit = (win <= 1024);
    if (fit) for (int e = t; e < win; e += 512) sCsr[e] = csr[st0 + e];
    __syncthreads();
    // merged gather: per (r,c) accumulate xhb 16B chunk + hT 32B chunk over SAME nbrs.
    // flow deg ~3 -> typically ONE round of 12 loads in flight (1 latency exposure
    // instead of 3 serial gmean calls). Needs ~100 VGPR -> launch_bounds(512,4).
    {
        const int r = t >> 3, c = t & 7;
        const int st = sOff[r], en = sOff[r + 1];
        fx2 a0[4] = {}, a1[4] = {}, a2[4] = {};
        for (int e = st; e < en; e += 4) {
            int n[4];
#pragma unroll
            for (int j = 0; j < 4; j++)
                n[j] = (e + j < en) ? (fit ? sCsr[e + j - st0] : csr[e + j]) : -1;
            uint4 ux[4], ua[4], ub[4];
#pragma unroll
            for (int j = 0; j < 4; j++) {
                if (n[j] >= 0) {
                    const u16* px = xhb + n[j] * 64 + c * 8;
                    const u16* ph = hT + n[j] * 128 + c * 16;
                    ux[j] = *(const uint4*)px;
                    ua[j] = *(const uint4*)ph;
                    ub[j] = *(const uint4*)(ph + 8);
                } else {
                    ux[j] = make_uint4(0u, 0u, 0u, 0u);
                    ua[j] = make_uint4(0u, 0u, 0u, 0u);
                    ub[j] = make_uint4(0u, 0u, 0u, 0u);
                }
            }
#pragma unroll
            for (int j = 0; j < 4; j++) {
                accp(a0, ux[j]); accp(a1, ua[j]); accp(a2, ub[j]);
            }
        }
        float inv = (en > st) ? 1.f / (float)(en - st) : 0.f;
        *(uint4*)(&sA[r * 136 + c * 8]) = packp(a0, inv);
        *(uint4*)(&sAg[r * 136 + c * 16]) = packp(a1, inv);
        *(uint4*)(&sAg[r * 136 + c * 16 + 8]) = packp(a2, inv);
    }
    __syncthreads();
    const int w = t >> 6, wr = w >> 1, wc = w & 1;   // wave = (row-band, col-half)
    const int ln = t & 63, l15 = ln & 15, quad = ln >> 4;
    const u16* pA = sA + (wr * 16 + l15) * 136 + quad * 8;
    const u16* pB0 = WT0 + wc * 8192 + l15 * 128 + quad * 8;
    f32x4 acc[4];
#pragma unroll
    for (int tt = 0; tt < 4; tt++) acc[tt] = (f32x4){0.f, 0.f, 0.f, 0.f};
#pragma unroll
    for (int s = 0; s < 4; s++) {
        bf16x8 av = *(const bf16x8*)(pA + s * 32);
#pragma unroll
        for (int tt = 0; tt < 4; tt++) {
            bf16x8 b = *(const bf16x8*)(pB0 + tt * 2048 + s * 32);
            acc[tt] = __builtin_amdgcn_mfma_f32_16x16x32_bf16(av, b, acc[tt], 0, 0, 0);
        }
    }
    __syncthreads();   // all phase-A reads of sA done before h overwrites it
    // epilogue1: h = lrelu(acc + b0) -> sA band (cols wc*64 ..)
#pragma unroll
    for (int tt = 0; tt < 4; tt++) {
        int col = wc * 64 + tt * 16 + l15;
        float bv = b0[col];
#pragma unroll
        for (int i = 0; i < 4; i++) {
            int rl = wr * 16 + quad * 4 + i;
            float v = acc[tt][i] + bv;
            v = v > 0.f ? v : 0.01f * v;
            sA[rl * 136 + col] = fbh(v);
        }
    }
    __syncthreads();   // h complete before phase B reads full rows
    // phase B: h @ WT1r^T
    const u16* pB1 = WT1r + wc * 8192 + l15 * 128 + quad * 8;
    f32x4 accB[4];
#pragma unroll
    for (int tt = 0; tt < 4; tt++) accB[tt] = (f32x4){0.f, 0.f, 0.f, 0.f};
#pragma unroll
    for (int s = 0; s < 4; s++) {
        bf16x8 av = *(const bf16x8*)(pA + s * 32);
#pragma unroll
        for (int tt = 0; tt < 4; tt++) {
            bf16x8 b = *(const bf16x8*)(pB1 + tt * 2048 + s * 32);
            accB[tt] = __builtin_amdgcn_mfma_f32_16x16x32_bf16(av, b, accB[tt], 0, 0, 0);
        }
    }
    // epilogue2: g = lrelu(accB + agg + b1) -> in-place over sAg
#pragma unroll
    for (int tt = 0; tt < 4; tt++) {
        int col = wc * 64 + tt * 16 + l15;
        float bv = b1[col];
#pragma unroll
        for (int i = 0; i < 4; i++) {
            int rl = wr * 16 + quad * 4 + i;
            float v = accB[tt][i] + bfh(sAg[rl * 136 + col]) + bv;
            v = v > 0.f ? v : 0.01f * v;
            sAg[rl * 136 + col] = fbh(v);
        }
    }
    __syncthreads();   // g complete before phase C reads full rows
    // phase C: out = g @ WTo^T + bout  (each wave: 16-row band x 16-col tile wc)
    const u16* pG = sAg + (wr * 16 + l15) * 136 + quad * 8;
    const u16* pBo = WTo + wc * 2048 + l15 * 128 + quad * 8;
    f32x4 acc2 = (f32x4){0.f, 0.f, 0.f, 0.f};
#pragma unroll
    for (int s = 0; s < 4; s++) {
        bf16x8 g = *(const bf16x8*)(pG + s * 32);
        bf16x8 b = *(const bf16x8*)(pBo + s * 32);
        acc2 = __builtin_amdgcn_mfma_f32_16x16x32_bf16(g, b, acc2, 0, 0, 0);
    }
    {
        int col = wc * 16 + l15;
        float bv = bout[col];
#pragma unroll
        for (int i = 0; i < 4; i++) {
            int row = m0 + wr * 16 + quad * 4 + i;
            OUT[row * D_OUT + col] = acc2[i] + bv;
        }
    }
}

extern "C" void kernel_launch(void* const* d_in, const int* in_sizes, int n_in,
                              void* d_out, int out_size, void* d_ws, size_t ws_size,
                              hipStream_t stream) {
    const float* x_host  = (const float*)d_in[0];
    const float* x_flow  = (const float*)d_in[1];
    const int* src_hf  = (const int*)d_in[2];
    const int* dst_hf  = (const int*)d_in[3];
    const int* src_fh  = (const int*)d_in[4];
    const int* dst_fh  = (const int*)d_in[5];
    const float* W0_hf_l = (const float*)d_in[6];
    const float* W0_hf_r = (const float*)d_in[7];
    const float* b0_hf   = (const float*)d_in[8];
    const float* W0_fh_l = (const float*)d_in[9];
    const float* W0_fh_r = (const float*)d_in[10];
    const float* b0_fh   = (const float*)d_in[11];
    const float* W1_hf_l = (const float*)d_in[12];
    const float* W1_hf_r = (const float*)d_in[13];
    const float* b1_hf   = (const float*)d_in[14];
    const float* W_out   = (const float*)d_in[18];
    const float* b_out   = (const float*)d_in[19];
    float* out = (float*)d_out;

    // workspace layout (bytes), all disjoint, total ~48.7 MB
    char* ws = (char*)d_ws;
    int*  off    = (int*)(ws + 0);             //   880,000
    int*  csr    = (int*)(ws + 880000);        // 4,800,000
    u16*  hT     = (u16*)(ws + 5680000);       //  5,120,000
    u16*  xfb    = (u16*)(ws + 10800000);      // 25,600,000
    u16*  xhb    = (u16*)(ws + 36400000);      //  2,560,000
    int2* binE   = (int2*)(ws + 38960000);     //  9,600,000
    int*  bcnt   = (int*)(ws + 48560000);      //  1,280
    int*  bcur   = (int*)(ws + 48561280);      //  1,280
    u16*  WT0_hf = (u16*)(ws + 48562560);      //  32,768
    u16*  WT0_fh = (u16*)(ws + 48595328);      //  32,768
    u16*  WT1_l  = (u16*)(ws + 48628096);      //  32,768
    u16*  WT1_r  = (u16*)(ws + 48660864);      //  32,768
    u16*  WTo    = (u16*)(ws + 48693632);      //   8,192

    hipMemsetAsync(bcnt, 0, 2560, stream);     // bcnt + bcur
    k_pre<<<34 + 6875 + NEB, 256, 0, stream>>>(
        W0_hf_l, W0_hf_r, W0_fh_l, W0_fh_r, W1_hf_l, W1_hf_r, W_out,
        WT0_hf, WT0_fh, WT1_l, WT1_r, WTo,
        x_flow, x_host, xfb, xhb, dst_hf, dst_fh, bcnt);
    kb2<<<NEB, 256, 0, stream>>>(src_hf, dst_hf, src_fh, dst_fh, bcnt, bcur, binE);
    kb3<<<NBKT, 256, 0, stream>>>(binE, bcnt, off, csr);
    k_host<<<313, 512, 0, stream>>>(xfb, xhb, off, csr, WT0_fh, b0_fh, WT1_l, hT, N_HOST);
    k_mega<<<3125, 512, 0, stream>>>(xfb, xhb, off, csr, hT, WT0_hf, b0_hf,
                                     WT1_r, b1_hf, WTo, b_out, out);
}

// Round 11
// 342.596 us; speedup vs baseline: 1.2630x; 1.0293x over previous
//
#include <hip/hip_runtime.h>

// HeteroGNN on MI355X. Inputs/weights/output fp32 (per reference); intermediates bf16.
// Round 19 = Round 18 with the compile fix: __builtin_nontemporal_load requires a
// scalar/clang-ext-vector pointer, not HIP_vector_type (uint4). Use u32x4 ext-vector.
//  - R17 post-mortem: merged gather clean (no spill, VGPR 48) but SLOWER (145.6 vs
//    137.5; occ 41 vs 81). Compiler serialized the 12 loads. Merged gather dead.
//  - Evidence: k_mega insensitive to TLP (+42pp occ -> -8us), VALU cut (neutral),
//    ILP (merged: worse). All utils <30% => miss-throughput-bound: gather set
//    xhb(2.5M)+hT(5M)=7.7MB > 4MB/XCD L2, AND xfb streams 25.6MB through L2 each
//    dispatch evicting gather-hot lines. Fix: nt-bit hints on streaming traffic
//    (xfb direct load, csr staging, OUT store). Prediction: FETCH 81.6->~70MB,
//    k_mega ~120-128us. If null (+-3us): L2-thrash dead, structural floor.
//   k_pre  : weights->bf16 WT[n][k] | x->bf16 pools | bucket histogram
//   kb2    : bin scatter (in-block 275-prefix)  kb3: per-bucket CSR build
//   k_host : h=lrelu([mean(xfb nbrs)|xhb]@WT0_fh^T+b0); hT=h@WT1_l^T        (M=20000)
//   k_mega : h=lrelu([mean(xhb nbrs)|xfb]@WT0_hf^T+b0);
//            g=lrelu(h@WT1_r^T+mean(hT nbrs)+b1); out=g@WTo^T+bout          (M=200000)
// g_host dead in reference -> W1_fh_* unused.

#define N_HOST 20000
#define N_FLOW 200000
#define NEDGE  600000
#define D_IN   64
#define D_H    128
#define D_OUT  32
#define NSEG   (N_FLOW + N_HOST)
#define NBKT_F 196
#define NBKT_H 79
#define NBKT   (NBKT_F + NBKT_H)   // 275
#define NEB    586                 // ceil(1200000/2048)

typedef unsigned short u16;
typedef unsigned int   u32;
typedef short bf16x8 __attribute__((ext_vector_type(8)));
typedef float f32x4  __attribute__((ext_vector_type(4)));
typedef float fx2    __attribute__((ext_vector_type(2)));
typedef unsigned int u32x4 __attribute__((ext_vector_type(4)));   // for nontemporal ld

__device__ __forceinline__ float bfh(u16 h) { return __uint_as_float(((u32)h) << 16); }
__device__ __forceinline__ u16 fbh(float f) {
    u32 u = __float_as_uint(f);
    return (u16)((u + 0x7fffu + ((u >> 16) & 1u)) >> 16);   // RNE
}
__device__ __forceinline__ u32 packbf(float x, float y) {
    return (u32)fbh(x) | ((u32)fbh(y) << 16);
}
// packed bf16 unpack+accumulate (v_pk_add_f32)
__device__ __forceinline__ void accp(fx2* a, uint4 u) {
    fx2 p;
    p.x = __uint_as_float(u.x << 16); p.y = __uint_as_float(u.x & 0xffff0000u); a[0] += p;
    p.x = __uint_as_float(u.y << 16); p.y = __uint_as_float(u.y & 0xffff0000u); a[1] += p;
    p.x = __uint_as_float(u.z << 16); p.y = __uint_as_float(u.z & 0xffff0000u); a[2] += p;
    p.x = __uint_as_float(u.w << 16); p.y = __uint_as_float(u.w & 0xffff0000u); a[3] += p;
}
__device__ __forceinline__ uint4 packp(const fx2* a, float inv) {
    uint4 o;
    o.x = packbf(a[0].x * inv, a[0].y * inv);
    o.y = packbf(a[1].x * inv, a[1].y * inv);
    o.z = packbf(a[2].x * inv, a[2].y * inv);
    o.w = packbf(a[3].x * inv, a[3].y * inv);
    return o;
}

// gather-mean of 16B chunks; neighbor indices from LDS window (fit) or global fallback.
template <int U>
__device__ __forceinline__ uint4 gmean(const u16* __restrict__ pool, int rs, int coff,
                                       const int* __restrict__ gcsr,
                                       const int* __restrict__ lcsr, int st0, bool fit,
                                       int st, int en) {
    fx2 a[4] = {};
    for (int e = st; e < en; e += U) {
        int n[U];
#pragma unroll
        for (int j = 0; j < U; j++)
            n[j] = (e + j < en) ? (fit ? lcsr[e + j - st0] : gcsr[e + j]) : -1;
        uint4 u[U];
#pragma unroll
        for (int j = 0; j < U; j++)
            u[j] = (n[j] >= 0) ? *(const uint4*)(pool + n[j] * rs + coff)
                               : make_uint4(0u, 0u, 0u, 0u);
#pragma unroll
        for (int j = 0; j < U; j++) accp(a, u[j]);
    }
    float inv = (en > st) ? 1.f / (float)(en - st) : 0.f;
    return packp(a, inv);
}

// ---------------- k_pre: weights transpose | x->bf16 | bucket histogram ----------------
__global__ void k_pre(const float* __restrict__ W0_hf_l, const float* __restrict__ W0_hf_r,
                      const float* __restrict__ W0_fh_l, const float* __restrict__ W0_fh_r,
                      const float* __restrict__ W1_l, const float* __restrict__ W1_r,
                      const float* __restrict__ Wout,
                      u16* __restrict__ WT0_hf, u16* __restrict__ WT0_fh,
                      u16* __restrict__ WT1_l, u16* __restrict__ WT1_r,
                      u16* __restrict__ WTo,
                      const float* __restrict__ xf, const float* __restrict__ xh,
                      u16* __restrict__ xfb, u16* __restrict__ xhb,
                      const int* __restrict__ dst_hf, const int* __restrict__ dst_fh,
                      int* __restrict__ bcnt) {
    int b = blockIdx.x, t = threadIdx.x;
    if (b < 34) {
        u16 tmp[8];
        if (b < 32) {
            int e = (b & 7) * 2048 + t * 8;
            int n = e >> 7, k0 = e & 127;
            if (b < 8) {
#pragma unroll
                for (int j = 0; j < 8; j++) {
                    int k = k0 + j;
                    tmp[j] = fbh(k < 64 ? W0_hf_l[k * D_H + n] : W0_hf_r[(k - 64) * D_H + n]);
                }
                *(uint4*)(WT0_hf + n * 128 + k0) = *(uint4*)tmp;
            } else if (b < 16) {
#pragma unroll
                for (int j = 0; j < 8; j++) {
                    int k = k0 + j;
                    tmp[j] = fbh(k < 64 ? W0_fh_l[k * D_H + n] : W0_fh_r[(k - 64) * D_H + n]);
                }
                *(uint4*)(WT0_fh + n * 128 + k0) = *(uint4*)tmp;
            } else if (b < 24) {
#pragma unroll
                for (int j = 0; j < 8; j++) tmp[j] = fbh(W1_l[(k0 + j) * D_H + n]);
                *(uint4*)(WT1_l + n * 128 + k0) = *(uint4*)tmp;
            } else {
#pragma unroll
                for (int j = 0; j < 8; j++) tmp[j] = fbh(W1_r[(k0 + j) * D_H + n]);
                *(uint4*)(WT1_r + n * 128 + k0) = *(uint4*)tmp;
            }
        } else {
            int e = (b - 32) * 2048 + t * 8;
            int n = e >> 7, k0 = e & 127;
#pragma unroll
            for (int j = 0; j < 8; j++) tmp[j] = fbh(Wout[(k0 + j) * D_OUT + n]);
            *(uint4*)(WTo + n * 128 + k0) = *(uint4*)tmp;
        }
    } else if (b < 34 + 6875) {
        int q = (b - 34) * 256 + t;       // 8 floats per thread
        const int TF = (N_FLOW * D_IN) / 8;
        const int TT = TF + (N_HOST * D_IN) / 8;
        if (q >= TT) return;
        const float* src; u16* dst; int base;
        if (q < TF) { src = xf; dst = xfb; base = q * 8; }
        else        { src = xh; dst = xhb; base = (q - TF) * 8; }
        float4 f0 = *(const float4*)(src + base);
        float4 f1 = *(const float4*)(src + base + 4);
        uint4 o;
        o.x = packbf(f0.x, f0.y); o.y = packbf(f0.z, f0.w);
        o.z = packbf(f1.x, f1.y); o.w = packbf(f1.z, f1.w);
        *(uint4*)(dst + base) = o;
    } else {
        __shared__ int h[NBKT];
        for (int j = t; j < NBKT; j += 256) h[j] = 0;
        __syncthreads();
        int base = (b - 34 - 6875) * 2048;
#pragma unroll
        for (int i = 0; i < 8; i++) {
            int e = base + t + i * 256;
            if (e < 2 * NEDGE) {
                int bkt = (e < NEDGE) ? (dst_hf[e] >> 10)
                                      : (NBKT_F + (dst_fh[e - NEDGE] >> 8));
                atomicAdd(&h[bkt], 1);
            }
        }
        __syncthreads();
        for (int j = t; j < NBKT; j += 256)
            if (h[j]) atomicAdd(&bcnt[j], h[j]);
    }
}

// ---------------- kb2: bin scatter (in-block prefix of bcnt) ----------------
__global__ void kb2(const int* __restrict__ src_hf, const int* __restrict__ dst_hf,
                    const int* __restrict__ src_fh, const int* __restrict__ dst_fh,
                    const int* __restrict__ bcnt, int* __restrict__ bcur,
                    int2* __restrict__ binE) {
    __shared__ int sp[512];    // becomes exclusive bucket base
    __shared__ int lh[NBKT];
    __shared__ int lb[NBKT];
    int t = threadIdx.x;
    int o1 = (t < NBKT) ? bcnt[t] : 0;
    int o2 = (t + 256 < NBKT) ? bcnt[t + 256] : 0;
    sp[t] = o1; sp[t + 256] = o2;
    for (int j = t; j < NBKT; j += 256) lh[j] = 0;
    __syncthreads();
    for (int d = 1; d < 512; d <<= 1) {
        int a0 = (t >= d) ? sp[t - d] : 0;
        int a1 = sp[t + 256 - d];
        __syncthreads();
        sp[t] += a0; sp[t + 256] += a1;
        __syncthreads();
    }
    sp[t] -= o1; sp[t + 256] -= o2;   // exclusive
    __syncthreads();
    int base = blockIdx.x * 2048;
    int mybkt[8], myrank[8], mysrc[8], mydst[8];
#pragma unroll
    for (int i = 0; i < 8; i++) {
        int e = base + t + i * 256;
        mybkt[i] = -1;
        if (e < 2 * NEDGE) {
            int s, d;
            if (e < NEDGE) { s = src_hf[e]; d = dst_hf[e]; }
            else           { s = src_fh[e - NEDGE]; d = dst_fh[e - NEDGE] + N_FLOW; }
            int bkt = (d < N_FLOW) ? (d >> 10) : (NBKT_F + ((d - N_FLOW) >> 8));
            mybkt[i] = bkt; mysrc[i] = s; mydst[i] = d;
            myrank[i] = atomicAdd(&lh[bkt], 1);
        }
    }
    __syncthreads();
    for (int j = t; j < NBKT; j += 256)
        lb[j] = lh[j] ? atomicAdd(&bcur[j], lh[j]) : 0;
    __syncthreads();
#pragma unroll
    for (int i = 0; i < 8; i++) {
        if (mybkt[i] >= 0) {
            int pos = sp[mybkt[i]] + lb[mybkt[i]] + myrank[i];
            binE[pos] = make_int2(mysrc[i], mydst[i]);
        }
    }
}

// ---------------- kb3: per-bucket CSR (in-block prefix of bcnt) ----------------
__global__ __launch_bounds__(256) void kb3(const int2* __restrict__ binE,
                                           const int* __restrict__ bcnt,
                                           int* __restrict__ off, int* __restrict__ csr) {
    __shared__ int sp[512];
    __shared__ int deg[1024];
    __shared__ int ts[256];
    int b = blockIdx.x, t = threadIdx.x;
    sp[t] = (t < NBKT) ? bcnt[t] : 0;
    sp[t + 256] = (t + 256 < NBKT) ? bcnt[t + 256] : 0;
    __syncthreads();
    for (int d = 1; d < 512; d <<= 1) {
        int a0 = (t >= d) ? sp[t - d] : 0;
        int a1 = sp[t + 256 - d];
        __syncthreads();
        sp[t] += a0; sp[t + 256] += a1;
        __syncthreads();
    }
    int e0 = (b == 0) ? 0 : sp[b - 1];
    int e1 = sp[b];
    int nbase, ncnt;
    if (b < NBKT_F) { nbase = b << 10; ncnt = min(1024, N_FLOW - nbase); }
    else { nbase = N_FLOW + ((b - NBKT_F) << 8); ncnt = min(256, NSEG - nbase); }
    for (int i = t; i < 1024; i += 256) deg[i] = 0;
    __syncthreads();
    for (int e = e0 + t; e < e1; e += 256) {
        int2 p = binE[e];
        atomicAdd(&deg[p.y - nbase], 1);
    }
    __syncthreads();
    int loc[4]; int s = 0;
#pragma unroll
    for (int j = 0; j < 4; j++) { loc[j] = s; s += deg[t * 4 + j]; }
    ts[t] = s;
    __syncthreads();
    for (int d = 1; d < 256; d <<= 1) {
        int x = (t >= d) ? ts[t - d] : 0;
        __syncthreads();
        ts[t] += x;
        __syncthreads();
    }
    int base2 = e0 + ts[t] - s;
    int dsave[4];
#pragma unroll
    for (int j = 0; j < 4; j++) dsave[j] = deg[t * 4 + j];
    __syncthreads();
#pragma unroll
    for (int j = 0; j < 4; j++) {
        int idx = t * 4 + j;
        int st = base2 + loc[j];
        deg[idx] = st;
        if (idx < ncnt) off[nbase + idx] = st + dsave[j];   // segment END
    }
    __syncthreads();
    for (int e = e0 + t; e < e1; e += 256) {
        int2 p = binE[e];
        int r = atomicAdd(&deg[p.y - nbase], 1);
        csr[r] = p.x;
    }
}

// ---------------- k_host: G2+G3 fused (M=20000), 512 thr, col-split waves ----------------
__global__ __launch_bounds__(512, 4) void k_host(
    const u16* __restrict__ xfb, const u16* __restrict__ xhb,
    const int* __restrict__ off, const int* __restrict__ csr,
    const u16* __restrict__ WT0, const float* __restrict__ b0,
    const u16* __restrict__ WT1l, u16* __restrict__ hT, int M) {
    __shared__ __align__(16) u16 sA[64 * 136];
    __shared__ int sOff[72];
    __shared__ int sCsr[2560];
    const int t = threadIdx.x;
    const int m0 = blockIdx.x * 64;
    if (t < 65) {
        int idx = N_FLOW + m0 - 1 + t;
        sOff[t] = off[min(idx, NSEG - 1)];
    }
    // direct half: xhb row, k in [64,128)  — 512 chunks, 1/thread
    {
        int r = t >> 3, c = t & 7;
        int row = m0 + r;
        uint4 v = make_uint4(0u, 0u, 0u, 0u);
        if (row < M) v = *(const uint4*)(xhb + row * 64 + c * 8);
        *(uint4*)(&sA[r * 136 + 64 + c * 8]) = v;
    }
    __syncthreads();
    int st0 = sOff[0];
    int win = sOff[64] - st0;
    bool fit = (win <= 2560);
    if (fit) for (int e = t; e < win; e += 512) sCsr[e] = csr[st0 + e];
    __syncthreads();
    // gather half: mean(xfb nbrs), k in [0,64) — deg~30, batch 8 loads/round
    {
        int r = t >> 3, c = t & 7;
        int row = m0 + r;
        uint4 o = make_uint4(0u, 0u, 0u, 0u);
        if (row < M) o = gmean<8>(xfb, 64, c * 8, csr, sCsr, st0, fit, sOff[r], sOff[r + 1]);
        *(uint4*)(&sA[r * 136 + c * 8]) = o;
    }
    __syncthreads();
    const int w = t >> 6, wr = w >> 1, wc = w & 1;
    const int ln = t & 63, l15 = ln & 15, quad = ln >> 4;
    const u16* pA = sA + (wr * 16 + l15) * 136 + quad * 8;
    const u16* pB0 = WT0 + wc * 8192 + l15 * 128 + quad * 8;
    f32x4 acc[4];
#pragma unroll
    for (int tt = 0; tt < 4; tt++) acc[tt] = (f32x4){0.f, 0.f, 0.f, 0.f};
#pragma unroll
    for (int s = 0; s < 4; s++) {
        bf16x8 a = *(const bf16x8*)(pA + s * 32);
#pragma unroll
        for (int tt = 0; tt < 4; tt++) {
            bf16x8 b = *(const bf16x8*)(pB0 + tt * 2048 + s * 32);
            acc[tt] = __builtin_amdgcn_mfma_f32_16x16x32_bf16(a, b, acc[tt], 0, 0, 0);
        }
    }
    __syncthreads();   // all phase-A reads of sA done before h overwrites it
#pragma unroll
    for (int tt = 0; tt < 4; tt++) {
        int col = wc * 64 + tt * 16 + l15;
        float bv = b0[col];
#pragma unroll
        for (int i = 0; i < 4; i++) {
            int rl = wr * 16 + quad * 4 + i;
            float v = acc[tt][i] + bv;
            v = v > 0.f ? v : 0.01f * v;
            sA[rl * 136 + col] = fbh(v);
        }
    }
    __syncthreads();   // h complete (both col-half waves) before phase B reads
    const u16* pB1 = WT1l + wc * 8192 + l15 * 128 + quad * 8;
    f32x4 accB[4];
#pragma unroll
    for (int tt = 0; tt < 4; tt++) accB[tt] = (f32x4){0.f, 0.f, 0.f, 0.f};
#pragma unroll
    for (int s = 0; s < 4; s++) {
        bf16x8 a = *(const bf16x8*)(pA + s * 32);
#pragma unroll
        for (int tt = 0; tt < 4; tt++) {
            bf16x8 b = *(const bf16x8*)(pB1 + tt * 2048 + s * 32);
            accB[tt] = __builtin_amdgcn_mfma_f32_16x16x32_bf16(a, b, accB[tt], 0, 0, 0);
        }
    }
#pragma unroll
    for (int tt = 0; tt < 4; tt++) {
        int col = wc * 64 + tt * 16 + l15;
#pragma unroll
        for (int i = 0; i < 4; i++) {
            int row = m0 + wr * 16 + quad * 4 + i;
            if (row < M) hT[row * D_H + col] = fbh(accB[tt][i]);
        }
    }
}

// ---- k_mega: G1+G4 fused (M=200000) — R9 structure + non-temporal streaming ----
__global__ __launch_bounds__(512, 8) void k_mega(
    const u16* __restrict__ xfb, const u16* __restrict__ xhb,
    const int* __restrict__ off, const int* __restrict__ csr,
    const u16* __restrict__ hT,
    const u16* __restrict__ WT0, const float* __restrict__ b0,
    const u16* __restrict__ WT1r, const float* __restrict__ b1,
    const u16* __restrict__ WTo, const float* __restrict__ bout,
    float* __restrict__ OUT) {
    __shared__ __align__(16) u16 sA[64 * 136];    // A0 tile -> h band
    __shared__ __align__(16) u16 sAg[64 * 136];   // gathered mean(hT) tile -> g band
    __shared__ int sOff[72];
    __shared__ int sCsr[1024];
    const int t = threadIdx.x;
    const int m0 = blockIdx.x * 64;
    if (t < 65) {
        int idx = m0 - 1 + t;
        sOff[t] = (idx < 0) ? 0 : off[idx];
    }
    // direct half: xfb row, k in [64,128) — streaming (read-once): non-temporal, keeps
    // L2 capacity for the gather-hot xhb/hT working set.
    {
        int r = t >> 3, c = t & 7;
        const u32x4* p = (const u32x4*)(xfb + (m0 + r) * 64 + c * 8);
        u32x4 v = __builtin_nontemporal_load(p);
        *(u32x4*)(&sA[r * 136 + 64 + c * 8]) = v;
    }
    __syncthreads();
    int st0 = sOff[0];
    int win = sOff[64] - st0;
    bool fit = (win <= 1024);
    if (fit) for (int e = t; e < win; e += 512)
        sCsr[e] = __builtin_nontemporal_load(csr + st0 + e);   // read-once stream
    __syncthreads();
    // A0 gather half: mean(xhb nbrs), k in [0,64) — 512 tasks
    {
        int r = t >> 3, c = t & 7;
        uint4 o = gmean<4>(xhb, 64, c * 8, csr, sCsr, st0, fit, sOff[r], sOff[r + 1]);
        *(uint4*)(&sA[r * 136 + c * 8]) = o;
    }
    // agg tile: mean(hT nbrs), 128d — 1024 tasks, 2/thread
#pragma unroll
    for (int i = 0; i < 2; i++) {
        int q = t + i * 512;
        int r = q >> 4, c = q & 15;
        uint4 o = gmean<4>(hT, 128, c * 8, csr, sCsr, st0, fit, sOff[r], sOff[r + 1]);
        *(uint4*)(&sAg[r * 136 + c * 8]) = o;
    }
    __syncthreads();
    const int w = t >> 6, wr = w >> 1, wc = w & 1;   // wave = (row-band, col-half)
    const int ln = t & 63, l15 = ln & 15, quad = ln >> 4;
    const u16* pA = sA + (wr * 16 + l15) * 136 + quad * 8;
    const u16* pB0 = WT0 + wc * 8192 + l15 * 128 + quad * 8;
    f32x4 acc[4];
#pragma unroll
    for (int tt = 0; tt < 4; tt++) acc[tt] = (f32x4){0.f, 0.f, 0.f, 0.f};
#pragma unroll
    for (int s = 0; s < 4; s++) {
        bf16x8 av = *(const bf16x8*)(pA + s * 32);
#pragma unroll
        for (int tt = 0; tt < 4; tt++) {
            bf16x8 b = *(const bf16x8*)(pB0 + tt * 2048 + s * 32);
            acc[tt] = __builtin_amdgcn_mfma_f32_16x16x32_bf16(av, b, acc[tt], 0, 0, 0);
        }
    }
    __syncthreads();   // all phase-A reads of sA done before h overwrites it
    // epilogue1: h = lrelu(acc + b0) -> sA band (cols wc*64 ..)
#pragma unroll
    for (int tt = 0; tt < 4; tt++) {
        int col = wc * 64 + tt * 16 + l15;
        float bv = b0[col];
#pragma unroll
        for (int i = 0; i < 4; i++) {
            int rl = wr * 16 + quad * 4 + i;
            float v = acc[tt][i] + bv;
            v = v > 0.f ? v : 0.01f * v;
            sA[rl * 136 + col] = fbh(v);
        }
    }
    __syncthreads();   // h complete before phase B reads full rows
    // phase B: h @ WT1r^T
    const u16* pB1 = WT1r + wc * 8192 + l15 * 128 + quad * 8;
    f32x4 accB[4];
#pragma unroll
    for (int tt = 0; tt < 4; tt++) accB[tt] = (f32x4){0.f, 0.f, 0.f, 0.f};
#pragma unroll
    for (int s = 0; s < 4; s++) {
        bf16x8 av = *(const bf16x8*)(pA + s * 32);
#pragma unroll
        for (int tt = 0; tt < 4; tt++) {
            bf16x8 b = *(const bf16x8*)(pB1 + tt * 2048 + s * 32);
            accB[tt] = __builtin_amdgcn_mfma_f32_16x16x32_bf16(av, b, accB[tt], 0, 0, 0);
        }
    }
    // epilogue2: g = lrelu(accB + agg + b1) -> in-place over sAg
#pragma unroll
    for (int tt = 0; tt < 4; tt++) {
        int col = wc * 64 + tt * 16 + l15;
        float bv = b1[col];
#pragma unroll
        for (int i = 0; i < 4; i++) {
            int rl = wr * 16 + quad * 4 + i;
            float v = accB[tt][i] + bfh(sAg[rl * 136 + col]) + bv;
            v = v > 0.f ? v : 0.01f * v;
            sAg[rl * 136 + col] = fbh(v);
        }
    }
    __syncthreads();   // g complete before phase C reads full rows
    // phase C: out = g @ WTo^T + bout  (each wave: 16-row band x 16-col tile wc)
    const u16* pG = sAg + (wr * 16 + l15) * 136 + quad * 8;
    const u16* pBo = WTo + wc * 2048 + l15 * 128 + quad * 8;
    f32x4 acc2 = (f32x4){0.f, 0.f, 0.f, 0.f};
#pragma unroll
    for (int s = 0; s < 4; s++) {
        bf16x8 g = *(const bf16x8*)(pG + s * 32);
        bf16x8 b = *(const bf16x8*)(pBo + s * 32);
        acc2 = __builtin_amdgcn_mfma_f32_16x16x32_bf16(g, b, acc2, 0, 0, 0);
    }
    {
        int col = wc * 16 + l15;
        float bv = bout[col];
#pragma unroll
        for (int i = 0; i < 4; i++) {
            int row = m0 + wr * 16 + quad * 4 + i;
            __builtin_nontemporal_store(acc2[i] + bv, &OUT[row * D_OUT + col]);
        }
    }
}

extern "C" void kernel_launch(void* const* d_in, const int* in_sizes, int n_in,
                              void* d_out, int out_size, void* d_ws, size_t ws_size,
                              hipStream_t stream) {
    const float* x_host  = (const float*)d_in[0];
    const float* x_flow  = (const float*)d_in[1];
    const int* src_hf  = (const int*)d_in[2];
    const int* dst_hf  = (const int*)d_in[3];
    const int* src_fh  = (const int*)d_in[4];
    const int* dst_fh  = (const int*)d_in[5];
    const float* W0_hf_l = (const float*)d_in[6];
    const float* W0_hf_r = (const float*)d_in[7];
    const float* b0_hf   = (const float*)d_in[8];
    const float* W0_fh_l = (const float*)d_in[9];
    const float* W0_fh_r = (const float*)d_in[10];
    const float* b0_fh   = (const float*)d_in[11];
    const float* W1_hf_l = (const float*)d_in[12];
    const float* W1_hf_r = (const float*)d_in[13];
    const float* b1_hf   = (const float*)d_in[14];
    const float* W_out   = (const float*)d_in[18];
    const float* b_out   = (const float*)d_in[19];
    float* out = (float*)d_out;

    // workspace layout (bytes), all disjoint, total ~48.7 MB
    char* ws = (char*)d_ws;
    int*  off    = (int*)(ws + 0);             //   880,000
    int*  csr    = (int*)(ws + 880000);        // 4,800,000
    u16*  hT     = (u16*)(ws + 5680000);       //  5,120,000
    u16*  xfb    = (u16*)(ws + 10800000);      // 25,600,000
    u16*  xhb    = (u16*)(ws + 36400000);      //  2,560,000
    int2* binE   = (int2*)(ws + 38960000);     //  9,600,000
    int*  bcnt   = (int*)(ws + 48560000);      //  1,280
    int*  bcur   = (int*)(ws + 48561280);      //  1,280
    u16*  WT0_hf = (u16*)(ws + 48562560);      //  32,768
    u16*  WT0_fh = (u16*)(ws + 48595328);      //  32,768
    u16*  WT1_l  = (u16*)(ws + 48628096);      //  32,768
    u16*  WT1_r  = (u16*)(ws + 48660864);      //  32,768
    u16*  WTo    = (u16*)(ws + 48693632);      //   8,192

    (void)hipMemsetAsync(bcnt, 0, 2560, stream);     // bcnt + bcur
    k_pre<<<34 + 6875 + NEB, 256, 0, stream>>>(
        W0_hf_l, W0_hf_r, W0_fh_l, W0_fh_r, W1_hf_l, W1_hf_r, W_out,
        WT0_hf, WT0_fh, WT1_l, WT1_r, WTo,
        x_flow, x_host, xfb, xhb, dst_hf, dst_fh, bcnt);
    kb2<<<NEB, 256, 0, stream>>>(src_hf, dst_hf, src_fh, dst_fh, bcnt, bcur, binE);
    kb3<<<NBKT, 256, 0, stream>>>(binE, bcnt, off, csr);
    k_host<<<313, 512, 0, stream>>>(xfb, xhb, off, csr, WT0_fh, b0_fh, WT1_l, hT, N_HOST);
    k_mega<<<3125, 512, 0, stream>>>(xfb, xhb, off, csr, hT, WT0_hf, b0_hf,
                                     WT1_r, b1_hf, WTo, b_out, out);
}

// Round 12
// 336.300 us; speedup vs baseline: 1.2866x; 1.0187x over previous
//
#include <hip/hip_runtime.h>

// HeteroGNN on MI355X. Inputs/weights/output fp32 (per reference); intermediates bf16.
// Round 20: fine-grained bucketing (275 -> 1095 buckets).
//  - R19 verdict: nt-hints cut FETCH 81.6->73.7MB but k_mega time unchanged ->
//    L2-thrash dead; k_mega at structural floor (~136us, latency-bound gather,
//    insensitive to TLP/VALU/ILP/L2). Keep nt-hints, stop touching k_mega.
//  - Rest (~206us): kb3 at 275 blocks = 1.07/CU is the one structural defect fixable
//    WITHOUT adding work (R15's post-hoc sub-split rescanned 4x = wash). Fix: bucket
//    finer at the SOURCE: flow 256-node (782) + host 64-node (313) = 1095 buckets.
//    kb2 cost unchanged (same edges, less per-bucket atomic contention); kb3 gets
//    4.3 blocks/CU, 4x smaller windows, 256-entry LDS prefix (was 1024), zero
//    redundant reads. 1095-wide bucket prefixes: in-block 5-per-thread 2-level scan.
//  - bcnt/bcur (8.8KB) alias hT region (dead until k_host) -> ws footprint unchanged.
//   k_pre  : weights->bf16 WT[n][k] | x->bf16 pools | bucket histogram
//   kb2    : bin scatter (in-block 1095-prefix)  kb3: per-bucket CSR build
//   k_host : h=lrelu([mean(xfb nbrs)|xhb]@WT0_fh^T+b0); hT=h@WT1_l^T        (M=20000)
//   k_mega : h=lrelu([mean(xhb nbrs)|xfb]@WT0_hf^T+b0);
//            g=lrelu(h@WT1_r^T+mean(hT nbrs)+b1); out=g@WTo^T+bout          (M=200000)
// g_host dead in reference -> W1_fh_* unused.

#define N_HOST 20000
#define N_FLOW 200000
#define NEDGE  600000
#define D_IN   64
#define D_H    128
#define D_OUT  32
#define NSEG   (N_FLOW + N_HOST)
#define NBKT_F 782                 // 256-node flow buckets (200000 -> 781*256+64)
#define NBKT_H 313                 // 64-node host buckets  (20000  -> 312*64+32)
#define NBKT   (NBKT_F + NBKT_H)   // 1095
#define NBKT_PAD 1100              // 5*220, scan padding
#define NEB    586                 // ceil(1200000/2048)

typedef unsigned short u16;
typedef unsigned int   u32;
typedef short bf16x8 __attribute__((ext_vector_type(8)));
typedef float f32x4  __attribute__((ext_vector_type(4)));
typedef float fx2    __attribute__((ext_vector_type(2)));
typedef unsigned int u32x4 __attribute__((ext_vector_type(4)));   // for nontemporal ld

__device__ __forceinline__ float bfh(u16 h) { return __uint_as_float(((u32)h) << 16); }
__device__ __forceinline__ u16 fbh(float f) {
    u32 u = __float_as_uint(f);
    return (u16)((u + 0x7fffu + ((u >> 16) & 1u)) >> 16);   // RNE
}
__device__ __forceinline__ u32 packbf(float x, float y) {
    return (u32)fbh(x) | ((u32)fbh(y) << 16);
}
// packed bf16 unpack+accumulate (v_pk_add_f32)
__device__ __forceinline__ void accp(fx2* a, uint4 u) {
    fx2 p;
    p.x = __uint_as_float(u.x << 16); p.y = __uint_as_float(u.x & 0xffff0000u); a[0] += p;
    p.x = __uint_as_float(u.y << 16); p.y = __uint_as_float(u.y & 0xffff0000u); a[1] += p;
    p.x = __uint_as_float(u.z << 16); p.y = __uint_as_float(u.z & 0xffff0000u); a[2] += p;
    p.x = __uint_as_float(u.w << 16); p.y = __uint_as_float(u.w & 0xffff0000u); a[3] += p;
}
__device__ __forceinline__ uint4 packp(const fx2* a, float inv) {
    uint4 o;
    o.x = packbf(a[0].x * inv, a[0].y * inv);
    o.y = packbf(a[1].x * inv, a[1].y * inv);
    o.z = packbf(a[2].x * inv, a[2].y * inv);
    o.w = packbf(a[3].x * inv, a[3].y * inv);
    return o;
}

// gather-mean of 16B chunks; neighbor indices from LDS window (fit) or global fallback.
template <int U>
__device__ __forceinline__ uint4 gmean(const u16* __restrict__ pool, int rs, int coff,
                                       const int* __restrict__ gcsr,
                                       const int* __restrict__ lcsr, int st0, bool fit,
                                       int st, int en) {
    fx2 a[4] = {};
    for (int e = st; e < en; e += U) {
        int n[U];
#pragma unroll
        for (int j = 0; j < U; j++)
            n[j] = (e + j < en) ? (fit ? lcsr[e + j - st0] : gcsr[e + j]) : -1;
        uint4 u[U];
#pragma unroll
        for (int j = 0; j < U; j++)
            u[j] = (n[j] >= 0) ? *(const uint4*)(pool + n[j] * rs + coff)
                               : make_uint4(0u, 0u, 0u, 0u);
#pragma unroll
        for (int j = 0; j < U; j++) accp(a, u[j]);
    }
    float inv = (en > st) ? 1.f / (float)(en - st) : 0.f;
    return packp(a, inv);
}

// ---------------- k_pre: weights transpose | x->bf16 | bucket histogram ----------------
__global__ void k_pre(const float* __restrict__ W0_hf_l, const float* __restrict__ W0_hf_r,
                      const float* __restrict__ W0_fh_l, const float* __restrict__ W0_fh_r,
                      const float* __restrict__ W1_l, const float* __restrict__ W1_r,
                      const float* __restrict__ Wout,
                      u16* __restrict__ WT0_hf, u16* __restrict__ WT0_fh,
                      u16* __restrict__ WT1_l, u16* __restrict__ WT1_r,
                      u16* __restrict__ WTo,
                      const float* __restrict__ xf, const float* __restrict__ xh,
                      u16* __restrict__ xfb, u16* __restrict__ xhb,
                      const int* __restrict__ dst_hf, const int* __restrict__ dst_fh,
                      int* __restrict__ bcnt) {
    int b = blockIdx.x, t = threadIdx.x;
    if (b < 34) {
        u16 tmp[8];
        if (b < 32) {
            int e = (b & 7) * 2048 + t * 8;
            int n = e >> 7, k0 = e & 127;
            if (b < 8) {
#pragma unroll
                for (int j = 0; j < 8; j++) {
                    int k = k0 + j;
                    tmp[j] = fbh(k < 64 ? W0_hf_l[k * D_H + n] : W0_hf_r[(k - 64) * D_H + n]);
                }
                *(uint4*)(WT0_hf + n * 128 + k0) = *(uint4*)tmp;
            } else if (b < 16) {
#pragma unroll
                for (int j = 0; j < 8; j++) {
                    int k = k0 + j;
                    tmp[j] = fbh(k < 64 ? W0_fh_l[k * D_H + n] : W0_fh_r[(k - 64) * D_H + n]);
                }
                *(uint4*)(WT0_fh + n * 128 + k0) = *(uint4*)tmp;
            } else if (b < 24) {
#pragma unroll
                for (int j = 0; j < 8; j++) tmp[j] = fbh(W1_l[(k0 + j) * D_H + n]);
                *(uint4*)(WT1_l + n * 128 + k0) = *(uint4*)tmp;
            } else {
#pragma unroll
                for (int j = 0; j < 8; j++) tmp[j] = fbh(W1_r[(k0 + j) * D_H + n]);
                *(uint4*)(WT1_r + n * 128 + k0) = *(uint4*)tmp;
            }
        } else {
            int e = (b - 32) * 2048 + t * 8;
            int n = e >> 7, k0 = e & 127;
#pragma unroll
            for (int j = 0; j < 8; j++) tmp[j] = fbh(Wout[(k0 + j) * D_OUT + n]);
            *(uint4*)(WTo + n * 128 + k0) = *(uint4*)tmp;
        }
    } else if (b < 34 + 6875) {
        int q = (b - 34) * 256 + t;       // 8 floats per thread
        const int TF = (N_FLOW * D_IN) / 8;
        const int TT = TF + (N_HOST * D_IN) / 8;
        if (q >= TT) return;
        const float* src; u16* dst; int base;
        if (q < TF) { src = xf; dst = xfb; base = q * 8; }
        else        { src = xh; dst = xhb; base = (q - TF) * 8; }
        float4 f0 = *(const float4*)(src + base);
        float4 f1 = *(const float4*)(src + base + 4);
        uint4 o;
        o.x = packbf(f0.x, f0.y); o.y = packbf(f0.z, f0.w);
        o.z = packbf(f1.x, f1.y); o.w = packbf(f1.z, f1.w);
        *(uint4*)(dst + base) = o;
    } else {
        __shared__ int h[NBKT];
        for (int j = t; j < NBKT; j += 256) h[j] = 0;
        __syncthreads();
        int base = (b - 34 - 6875) * 2048;
#pragma unroll
        for (int i = 0; i < 8; i++) {
            int e = base + t + i * 256;
            if (e < 2 * NEDGE) {
                int bkt = (e < NEDGE) ? (dst_hf[e] >> 8)
                                      : (NBKT_F + (dst_fh[e - NEDGE] >> 6));
                atomicAdd(&h[bkt], 1);
            }
        }
        __syncthreads();
        for (int j = t; j < NBKT; j += 256)
            if (h[j]) atomicAdd(&bcnt[j], h[j]);
    }
}

// ---------------- kb2: bin scatter (in-block 1095-prefix of bcnt) ----------------
__global__ __launch_bounds__(256) void kb2(
    const int* __restrict__ src_hf, const int* __restrict__ dst_hf,
    const int* __restrict__ src_fh, const int* __restrict__ dst_fh,
    const int* __restrict__ bcnt, int* __restrict__ bcur,
    int2* __restrict__ binE) {
    __shared__ int spx[NBKT_PAD];   // exclusive bucket base
    __shared__ int ts[256];
    __shared__ int lh[NBKT];
    __shared__ int lb[NBKT];
    int t = threadIdx.x;
    // 5-per-thread 2-level exclusive scan of bcnt[0..NBKT)
    int v[5], loc[5];
    int b5 = t * 5, s = 0;
#pragma unroll
    for (int j = 0; j < 5; j++) {
        int idx = b5 + j;
        v[j] = (idx < NBKT) ? bcnt[idx] : 0;
        loc[j] = s; s += v[j];
    }
    ts[t] = s;
    for (int j = t; j < NBKT; j += 256) lh[j] = 0;
    __syncthreads();
    for (int d = 1; d < 256; d <<= 1) {
        int x = (t >= d) ? ts[t - d] : 0;
        __syncthreads();
        ts[t] += x;
        __syncthreads();
    }
    int ex = ts[t] - s;
#pragma unroll
    for (int j = 0; j < 5; j++) {
        int idx = b5 + j;
        if (idx < NBKT_PAD) spx[idx] = ex + loc[j];
    }
    __syncthreads();
    int base = blockIdx.x * 2048;
    int mybkt[8], myrank[8], mysrc[8], mydst[8];
#pragma unroll
    for (int i = 0; i < 8; i++) {
        int e = base + t + i * 256;
        mybkt[i] = -1;
        if (e < 2 * NEDGE) {
            int sv, d;
            if (e < NEDGE) { sv = src_hf[e]; d = dst_hf[e]; }
            else           { sv = src_fh[e - NEDGE]; d = dst_fh[e - NEDGE] + N_FLOW; }
            int bkt = (d < N_FLOW) ? (d >> 8) : (NBKT_F + ((d - N_FLOW) >> 6));
            mybkt[i] = bkt; mysrc[i] = sv; mydst[i] = d;
            myrank[i] = atomicAdd(&lh[bkt], 1);
        }
    }
    __syncthreads();
    for (int j = t; j < NBKT; j += 256)
        lb[j] = lh[j] ? atomicAdd(&bcur[j], lh[j]) : 0;
    __syncthreads();
#pragma unroll
    for (int i = 0; i < 8; i++) {
        if (mybkt[i] >= 0) {
            int pos = spx[mybkt[i]] + lb[mybkt[i]] + myrank[i];
            binE[pos] = make_int2(mysrc[i], mydst[i]);
        }
    }
}

// ------- kb3: per-bucket CSR build (1095 blocks, 256/64-node buckets) -------
__global__ __launch_bounds__(256) void kb3(const int2* __restrict__ binE,
                                           const int* __restrict__ bcnt,
                                           int* __restrict__ off, int* __restrict__ csr) {
    __shared__ int sinc[NBKT_PAD];   // inclusive bucket prefix
    __shared__ int ts[256];
    __shared__ int deg[256];
    int b = blockIdx.x, t = threadIdx.x;
    // 5-per-thread 2-level inclusive scan of bcnt
    int v[5], iv[5];
    int b5 = t * 5, s = 0;
#pragma unroll
    for (int j = 0; j < 5; j++) {
        int idx = b5 + j;
        v[j] = (idx < NBKT) ? bcnt[idx] : 0;
        s += v[j]; iv[j] = s;
    }
    ts[t] = s;
    __syncthreads();
    for (int d = 1; d < 256; d <<= 1) {
        int x = (t >= d) ? ts[t - d] : 0;
        __syncthreads();
        ts[t] += x;
        __syncthreads();
    }
    int ex = ts[t] - s;
#pragma unroll
    for (int j = 0; j < 5; j++) {
        int idx = b5 + j;
        if (idx < NBKT_PAD) sinc[idx] = ex + iv[j];
    }
    deg[t] = 0;
    __syncthreads();
    int e0 = (b == 0) ? 0 : sinc[b - 1];
    int e1 = sinc[b];
    int nbase, ncnt;
    if (b < NBKT_F) { nbase = b << 8; ncnt = min(256, N_FLOW - nbase); }
    else { int hb = b - NBKT_F; nbase = N_FLOW + (hb << 6); ncnt = min(64, NSEG - nbase); }
    for (int e = e0 + t; e < e1; e += 256) {
        int2 p = binE[e];
        atomicAdd(&deg[p.y - nbase], 1);
    }
    __syncthreads();
    int myd = deg[t];
    ts[t] = myd;
    __syncthreads();
    for (int d = 1; d < 256; d <<= 1) {
        int x = (t >= d) ? ts[t - d] : 0;
        __syncthreads();
        ts[t] += x;
        __syncthreads();
    }
    int st_ = e0 + ts[t] - myd;   // segment start
    __syncthreads();
    deg[t] = st_;                 // cur
    if (t < ncnt) off[nbase + t] = st_ + myd;   // segment END
    __syncthreads();
    for (int e = e0 + t; e < e1; e += 256) {
        int2 p = binE[e];
        int r = atomicAdd(&deg[p.y - nbase], 1);
        csr[r] = p.x;
    }
}

// ---------------- k_host: G2+G3 fused (M=20000), 512 thr, col-split waves ----------------
__global__ __launch_bounds__(512, 4) void k_host(
    const u16* __restrict__ xfb, const u16* __restrict__ xhb,
    const int* __restrict__ off, const int* __restrict__ csr,
    const u16* __restrict__ WT0, const float* __restrict__ b0,
    const u16* __restrict__ WT1l, u16* __restrict__ hT, int M) {
    __shared__ __align__(16) u16 sA[64 * 136];
    __shared__ int sOff[72];
    __shared__ int sCsr[2560];
    const int t = threadIdx.x;
    const int m0 = blockIdx.x * 64;
    if (t < 65) {
        int idx = N_FLOW + m0 - 1 + t;
        sOff[t] = off[min(idx, NSEG - 1)];
    }
    // direct half: xhb row, k in [64,128)  — 512 chunks, 1/thread
    {
        int r = t >> 3, c = t & 7;
        int row = m0 + r;
        uint4 v = make_uint4(0u, 0u, 0u, 0u);
        if (row < M) v = *(const uint4*)(xhb + row * 64 + c * 8);
        *(uint4*)(&sA[r * 136 + 64 + c * 8]) = v;
    }
    __syncthreads();
    int st0 = sOff[0];
    int win = sOff[64] - st0;
    bool fit = (win <= 2560);
    if (fit) for (int e = t; e < win; e += 512) sCsr[e] = csr[st0 + e];
    __syncthreads();
    // gather half: mean(xfb nbrs), k in [0,64) — deg~30, batch 8 loads/round
    {
        int r = t >> 3, c = t & 7;
        int row = m0 + r;
        uint4 o = make_uint4(0u, 0u, 0u, 0u);
        if (row < M) o = gmean<8>(xfb, 64, c * 8, csr, sCsr, st0, fit, sOff[r], sOff[r + 1]);
        *(uint4*)(&sA[r * 136 + c * 8]) = o;
    }
    __syncthreads();
    const int w = t >> 6, wr = w >> 1, wc = w & 1;
    const int ln = t & 63, l15 = ln & 15, quad = ln >> 4;
    const u16* pA = sA + (wr * 16 + l15) * 136 + quad * 8;
    const u16* pB0 = WT0 + wc * 8192 + l15 * 128 + quad * 8;
    f32x4 acc[4];
#pragma unroll
    for (int tt = 0; tt < 4; tt++) acc[tt] = (f32x4){0.f, 0.f, 0.f, 0.f};
#pragma unroll
    for (int s = 0; s < 4; s++) {
        bf16x8 a = *(const bf16x8*)(pA + s * 32);
#pragma unroll
        for (int tt = 0; tt < 4; tt++) {
            bf16x8 b = *(const bf16x8*)(pB0 + tt * 2048 + s * 32);
            acc[tt] = __builtin_amdgcn_mfma_f32_16x16x32_bf16(a, b, acc[tt], 0, 0, 0);
        }
    }
    __syncthreads();   // all phase-A reads of sA done before h overwrites it
#pragma unroll
    for (int tt = 0; tt < 4; tt++) {
        int col = wc * 64 + tt * 16 + l15;
        float bv = b0[col];
#pragma unroll
        for (int i = 0; i < 4; i++) {
            int rl = wr * 16 + quad * 4 + i;
            float v = acc[tt][i] + bv;
            v = v > 0.f ? v : 0.01f * v;
            sA[rl * 136 + col] = fbh(v);
        }
    }
    __syncthreads();   // h complete (both col-half waves) before phase B reads
    const u16* pB1 = WT1l + wc * 8192 + l15 * 128 + quad * 8;
    f32x4 accB[4];
#pragma unroll
    for (int tt = 0; tt < 4; tt++) accB[tt] = (f32x4){0.f, 0.f, 0.f, 0.f};
#pragma unroll
    for (int s = 0; s < 4; s++) {
        bf16x8 a = *(const bf16x8*)(pA + s * 32);
#pragma unroll
        for (int tt = 0; tt < 4; tt++) {
            bf16x8 b = *(const bf16x8*)(pB1 + tt * 2048 + s * 32);
            accB[tt] = __builtin_amdgcn_mfma_f32_16x16x32_bf16(a, b, accB[tt], 0, 0, 0);
        }
    }
#pragma unroll
    for (int tt = 0; tt < 4; tt++) {
        int col = wc * 64 + tt * 16 + l15;
#pragma unroll
        for (int i = 0; i < 4; i++) {
            int row = m0 + wr * 16 + quad * 4 + i;
            if (row < M) hT[row * D_H + col] = fbh(accB[tt][i]);
        }
    }
}

// ---- k_mega: G1+G4 fused (M=200000) — R9 structure + non-temporal streaming ----
__global__ __launch_bounds__(512, 8) void k_mega(
    const u16* __restrict__ xfb, const u16* __restrict__ xhb,
    const int* __restrict__ off, const int* __restrict__ csr,
    const u16* __restrict__ hT,
    const u16* __restrict__ WT0, const float* __restrict__ b0,
    const u16* __restrict__ WT1r, const float* __restrict__ b1,
    const u16* __restrict__ WTo, const float* __restrict__ bout,
    float* __restrict__ OUT) {
    __shared__ __align__(16) u16 sA[64 * 136];    // A0 tile -> h band
    __shared__ __align__(16) u16 sAg[64 * 136];   // gathered mean(hT) tile -> g band
    __shared__ int sOff[72];
    __shared__ int sCsr[1024];
    const int t = threadIdx.x;
    const int m0 = blockIdx.x * 64;
    if (t < 65) {
        int idx = m0 - 1 + t;
        sOff[t] = (idx < 0) ? 0 : off[idx];
    }
    // direct half: xfb row, k in [64,128) — streaming (read-once): non-temporal
    {
        int r = t >> 3, c = t & 7;
        const u32x4* p = (const u32x4*)(xfb + (m0 + r) * 64 + c * 8);
        u32x4 v = __builtin_nontemporal_load(p);
        *(u32x4*)(&sA[r * 136 + 64 + c * 8]) = v;
    }
    __syncthreads();
    int st0 = sOff[0];
    int win = sOff[64] - st0;
    bool fit = (win <= 1024);
    if (fit) for (int e = t; e < win; e += 512)
        sCsr[e] = __builtin_nontemporal_load(csr + st0 + e);   // read-once stream
    __syncthreads();
    // A0 gather half: mean(xhb nbrs), k in [0,64) — 512 tasks
    {
        int r = t >> 3, c = t & 7;
        uint4 o = gmean<4>(xhb, 64, c * 8, csr, sCsr, st0, fit, sOff[r], sOff[r + 1]);
        *(uint4*)(&sA[r * 136 + c * 8]) = o;
    }
    // agg tile: mean(hT nbrs), 128d — 1024 tasks, 2/thread
#pragma unroll
    for (int i = 0; i < 2; i++) {
        int q = t + i * 512;
        int r = q >> 4, c = q & 15;
        uint4 o = gmean<4>(hT, 128, c * 8, csr, sCsr, st0, fit, sOff[r], sOff[r + 1]);
        *(uint4*)(&sAg[r * 136 + c * 8]) = o;
    }
    __syncthreads();
    const int w = t >> 6, wr = w >> 1, wc = w & 1;   // wave = (row-band, col-half)
    const int ln = t & 63, l15 = ln & 15, quad = ln >> 4;
    const u16* pA = sA + (wr * 16 + l15) * 136 + quad * 8;
    const u16* pB0 = WT0 + wc * 8192 + l15 * 128 + quad * 8;
    f32x4 acc[4];
#pragma unroll
    for (int tt = 0; tt < 4; tt++) acc[tt] = (f32x4){0.f, 0.f, 0.f, 0.f};
#pragma unroll
    for (int s = 0; s < 4; s++) {
        bf16x8 av = *(const bf16x8*)(pA + s * 32);
#pragma unroll
        for (int tt = 0; tt < 4; tt++) {
            bf16x8 b = *(const bf16x8*)(pB0 + tt * 2048 + s * 32);
            acc[tt] = __builtin_amdgcn_mfma_f32_16x16x32_bf16(av, b, acc[tt], 0, 0, 0);
        }
    }
    __syncthreads();   // all phase-A reads of sA done before h overwrites it
    // epilogue1: h = lrelu(acc + b0) -> sA band (cols wc*64 ..)
#pragma unroll
    for (int tt = 0; tt < 4; tt++) {
        int col = wc * 64 + tt * 16 + l15;
        float bv = b0[col];
#pragma unroll
        for (int i = 0; i < 4; i++) {
            int rl = wr * 16 + quad * 4 + i;
            float v = acc[tt][i] + bv;
            v = v > 0.f ? v : 0.01f * v;
            sA[rl * 136 + col] = fbh(v);
        }
    }
    __syncthreads();   // h complete before phase B reads full rows
    // phase B: h @ WT1r^T
    const u16* pB1 = WT1r + wc * 8192 + l15 * 128 + quad * 8;
    f32x4 accB[4];
#pragma unroll
    for (int tt = 0; tt < 4; tt++) accB[tt] = (f32x4){0.f, 0.f, 0.f, 0.f};
#pragma unroll
    for (int s = 0; s < 4; s++) {
        bf16x8 av = *(const bf16x8*)(pA + s * 32);
#pragma unroll
        for (int tt = 0; tt < 4; tt++) {
            bf16x8 b = *(const bf16x8*)(pB1 + tt * 2048 + s * 32);
            accB[tt] = __builtin_amdgcn_mfma_f32_16x16x32_bf16(av, b, accB[tt], 0, 0, 0);
        }
    }
    // epilogue2: g = lrelu(accB + agg + b1) -> in-place over sAg
#pragma unroll
    for (int tt = 0; tt < 4; tt++) {
        int col = wc * 64 + tt * 16 + l15;
        float bv = b1[col];
#pragma unroll
        for (int i = 0; i < 4; i++) {
            int rl = wr * 16 + quad * 4 + i;
            float v = accB[tt][i] + bfh(sAg[rl * 136 + col]) + bv;
            v = v > 0.f ? v : 0.01f * v;
            sAg[rl * 136 + col] = fbh(v);
        }
    }
    __syncthreads();   // g complete before phase C reads full rows
    // phase C: out = g @ WTo^T + bout  (each wave: 16-row band x 16-col tile wc)
    const u16* pG = sAg + (wr * 16 + l15) * 136 + quad * 8;
    const u16* pBo = WTo + wc * 2048 + l15 * 128 + quad * 8;
    f32x4 acc2 = (f32x4){0.f, 0.f, 0.f, 0.f};
#pragma unroll
    for (int s = 0; s < 4; s++) {
        bf16x8 g = *(const bf16x8*)(pG + s * 32);
        bf16x8 b = *(const bf16x8*)(pBo + s * 32);
        acc2 = __builtin_amdgcn_mfma_f32_16x16x32_bf16(g, b, acc2, 0, 0, 0);
    }
    {
        int col = wc * 16 + l15;
        float bv = bout[col];
#pragma unroll
        for (int i = 0; i < 4; i++) {
            int row = m0 + wr * 16 + quad * 4 + i;
            __builtin_nontemporal_store(acc2[i] + bv, &OUT[row * D_OUT + col]);
        }
    }
}

extern "C" void kernel_launch(void* const* d_in, const int* in_sizes, int n_in,
                              void* d_out, int out_size, void* d_ws, size_t ws_size,
                              hipStream_t stream) {
    const float* x_host  = (const float*)d_in[0];
    const float* x_flow  = (const float*)d_in[1];
    const int* src_hf  = (const int*)d_in[2];
    const int* dst_hf  = (const int*)d_in[3];
    const int* src_fh  = (const int*)d_in[4];
    const int* dst_fh  = (const int*)d_in[5];
    const float* W0_hf_l = (const float*)d_in[6];
    const float* W0_hf_r = (const float*)d_in[7];
    const float* b0_hf   = (const float*)d_in[8];
    const float* W0_fh_l = (const float*)d_in[9];
    const float* W0_fh_r = (const float*)d_in[10];
    const float* b0_fh   = (const float*)d_in[11];
    const float* W1_hf_l = (const float*)d_in[12];
    const float* W1_hf_r = (const float*)d_in[13];
    const float* b1_hf   = (const float*)d_in[14];
    const float* W_out   = (const float*)d_in[18];
    const float* b_out   = (const float*)d_in[19];
    float* out = (float*)d_out;

    // workspace layout (bytes), total ~48.7 MB (unchanged footprint)
    char* ws = (char*)d_ws;
    int*  off    = (int*)(ws + 0);             //   880,000
    int*  csr    = (int*)(ws + 880000);        // 4,800,000
    u16*  hT     = (u16*)(ws + 5680000);       // 5,120,000  (written by k_host)
    int*  bcnt   = (int*)(ws + 5680000);       //     4,380 } alias hT region:
    int*  bcur   = (int*)(ws + 5684380);       //     4,380 } dead before k_host
    u16*  xfb    = (u16*)(ws + 10800000);      // 25,600,000
    u16*  xhb    = (u16*)(ws + 36400000);      //  2,560,000
    int2* binE   = (int2*)(ws + 38960000);     //  9,600,000
    u16*  WT0_hf = (u16*)(ws + 48562560);      //  32,768
    u16*  WT0_fh = (u16*)(ws + 48595328);      //  32,768
    u16*  WT1_l  = (u16*)(ws + 48628096);      //  32,768
    u16*  WT1_r  = (u16*)(ws + 48660864);      //  32,768
    u16*  WTo    = (u16*)(ws + 48693632);      //   8,192

    (void)hipMemsetAsync(bcnt, 0, 8760, stream);     // bcnt + bcur (contiguous)
    k_pre<<<34 + 6875 + NEB, 256, 0, stream>>>(
        W0_hf_l, W0_hf_r, W0_fh_l, W0_fh_r, W1_hf_l, W1_hf_r, W_out,
        WT0_hf, WT0_fh, WT1_l, WT1_r, WTo,
        x_flow, x_host, xfb, xhb, dst_hf, dst_fh, bcnt);
    kb2<<<NEB, 256, 0, stream>>>(src_hf, dst_hf, src_fh, dst_fh, bcnt, bcur, binE);
    kb3<<<NBKT, 256, 0, stream>>>(binE, bcnt, off, csr);
    k_host<<<313, 512, 0, stream>>>(xfb, xhb, off, csr, WT0_fh, b0_fh, WT1_l, hT, N_HOST);
    k_mega<<<3125, 512, 0, stream>>>(xfb, xhb, off, csr, hT, WT0_hf, b0_hf,
                                     WT1_r, b1_hf, WTo, b_out, out);
}